// Round 8
// baseline (409.481 us; speedup 1.0000x reference)
//
#include <hip/hip_runtime.h>
#include <hip/hip_bf16.h>

// ---------------------------------------------------------------------------
// CleanDITBlock: adaLN-modulated DiT block (self-attn w/ RoPE, cross-attn, MLP)
// B=2, L=2048, S=512, D=1024, H=16, HD=64, CTX=1024, HID=4096
// ---------------------------------------------------------------------------

typedef short short8 __attribute__((ext_vector_type(8)));
typedef float f32x4 __attribute__((ext_vector_type(4)));
typedef float f32x16 __attribute__((ext_vector_type(16)));

#define DEV __device__ __forceinline__

DEV unsigned short f2b(float f) {
  __hip_bfloat16 h = __float2bfloat16(f);
  return *reinterpret_cast<unsigned short*>(&h);
}
DEV float b2f(unsigned short u) {
  unsigned int x = ((unsigned int)u) << 16;
  return __builtin_bit_cast(float, x);
}
// single-instruction packed f32->bf16 pair (T12): D[15:0]=bf16(lo), D[31:16]=bf16(hi)
DEV unsigned int pk2(float lo, float hi) {
  unsigned int r;
  asm("v_cvt_pk_bf16_f32 %0, %1, %2" : "=v"(r) : "v"(lo), "v"(hi));
  return r;
}
// lane[i]<->lane[i+32] half-swap (VALU, no LDS)
DEV void vpsw(unsigned int& a, unsigned int& b) {
  asm("v_permlane32_swap_b32 %0, %1" : "+v"(a), "+v"(b));
}
// 3-input max (T17)
DEV float max3f(float a, float b, float c) {
  float r;
  asm("v_max3_f32 %0, %1, %2, %3" : "=v"(r) : "v"(a), "v"(b), "v"(c));
  return r;
}

#define GLB(p) ((const __attribute__((address_space(1))) void*)(p))
#define LDSP(p) ((__attribute__((address_space(3))) void*)(p))

// ---------------------------------------------------------------------------
// prep: ALL preprocessing in one launch (flattened grid, range decode).
//   [0,24)            mods = te @ wmod + bmod, computed DIRECTLY from f32 wmod
//   [24,8216)         8 square 1024^2 transposes (wq/wk/wv/wo self+cross)
//   [8216,12312)      w1 transpose (1024x4096 -> 4096x1024)
//   [12312,16408)     w2 transpose (4096x1024 -> 1024x4096)
//   [16408,18456)     ctx f32->bf16 cast, 2 elems/thread (packed cvt)
//   [18456,18968)     rope (cos,sin) table (131072 elems)
// ---------------------------------------------------------------------------
struct TCB { const float* in; unsigned short* out; float scale; };
struct PrepArgs {
  const float* wmod; const float* te; const float* bmod; float* mods;
  TCB sq[8];
  const float* w1; unsigned short* w1T;
  const float* w2; unsigned short* w2T;
  const float* ctx; unsigned short* ctxb;
  const float* rope; float2* cs;
};

__global__ __launch_bounds__(256) void prep(PrepArgs a) {
  __shared__ float t32[32][33];
  __shared__ float tes[2048];
  const int blk = blockIdx.x;
  const int tid = threadIdx.x;
  const int tx = tid & 31, ty = tid >> 5;
  if (blk < 24) {
    // ---- mods: j-chunk of 256 columns, both batches ----
    const int j = blk * 256 + tid;
    for (int u = tid; u < 2048; u += 256) tes[u] = a.te[u];
    __syncthreads();
    float a0 = 0.f, b0 = 0.f, a1 = 0.f, b1 = 0.f;
#pragma unroll 8
    for (int k = 0; k < 1024; k += 2) {
      float v0 = a.wmod[(size_t)k * 6144 + j];
      float v1 = a.wmod[(size_t)(k + 1) * 6144 + j];
      a0 += tes[k] * v0;
      b0 += tes[k + 1] * v1;
      a1 += tes[1024 + k] * v0;
      b1 += tes[1024 + k + 1] * v1;
    }
    float bm = a.bmod[j];
    a.mods[j] = a0 + b0 + bm;
    a.mods[6144 + j] = a1 + b1 + bm;
  } else if (blk < 16408) {
    const float* in;
    unsigned short* out;
    int R, C, gx, tile;
    float scale;
    if (blk < 8216) {
      int j = (blk - 24) >> 10;
      tile = (blk - 24) & 1023;
      in = a.sq[j].in; out = a.sq[j].out; scale = a.sq[j].scale;
      R = 1024; C = 1024; gx = 32;
    } else if (blk < 12312) {
      tile = blk - 8216;
      in = a.w1; out = a.w1T; R = 1024; C = 4096; gx = 128; scale = 1.f;
    } else {
      tile = blk - 12312;
      in = a.w2; out = a.w2T; R = 4096; C = 1024; gx = 32; scale = 1.f;
    }
    int bx = (tile % gx) * 32, by = (tile / gx) * 32;
#pragma unroll
    for (int i = ty; i < 32; i += 8)
      t32[i][tx] = in[(size_t)(by + i) * C + bx + tx];
    __syncthreads();
#pragma unroll
    for (int i = ty; i < 32; i += 8)
      out[(size_t)(bx + i) * R + by + tx] = f2b(t32[tx][i] * scale);
  } else if (blk < 18456) {
    int i = (blk - 16408) * 512 + tid * 2;
    float2 v = *(const float2*)&a.ctx[i];
    *(unsigned int*)&a.ctxb[i] = pk2(v.x, v.y);
  } else {
    int i = (blk - 18456) * 256 + tid;
    float v = a.rope[i];
    a.cs[i] = make_float2(cosf(v), sinf(v));
  }
}

// ---------------------------------------------------------------------------
__global__ __launch_bounds__(256) void ln_mod(
    const float* __restrict__ x, const float* __restrict__ mods,
    unsigned short* __restrict__ out, int scale_ofs, int shift_ofs) {
  int row = blockIdx.x;
  int b = row >> 11;
  int tid = threadIdx.x;
  const float* xr = x + (size_t)row * 1024;
  float4 v = ((const float4*)xr)[tid];
  float s = v.x + v.y + v.z + v.w;
  float ss = v.x * v.x + v.y * v.y + v.z * v.z + v.w * v.w;
#pragma unroll
  for (int off = 32; off >= 1; off >>= 1) {
    s += __shfl_down(s, off);
    ss += __shfl_down(ss, off);
  }
  __shared__ float red[8];
  int wave = tid >> 6, lane = tid & 63;
  if (lane == 0) { red[wave] = s; red[4 + wave] = ss; }
  __syncthreads();
  if (tid == 0) {
    float S = red[0] + red[1] + red[2] + red[3];
    float SS = red[4] + red[5] + red[6] + red[7];
    float mu = S * (1.f / 1024.f);
    red[0] = mu;
    red[1] = SS * (1.f / 1024.f) - mu * mu;
  }
  __syncthreads();
  float mu = red[0];
  float rs = rsqrtf(red[1] + 1e-6f);
  float vv[4] = {v.x, v.y, v.z, v.w};
  unsigned short o[4];
#pragma unroll
  for (int c = 0; c < 4; ++c) {
    int col = tid * 4 + c;
    float nv = (vv[c] - mu) * rs;
    if (scale_ofs >= 0)
      nv = nv * (1.f + mods[(size_t)b * 6144 + scale_ofs + col]) +
           mods[(size_t)b * 6144 + shift_ofs + col];
    o[c] = f2b(nv);
  }
  *(ushort4*)(&out[(size_t)row * 1024 + tid * 4]) = *(const ushort4*)o;
}

// ---------------------------------------------------------------------------
// Shared GEMM epilogue.  EPI: 0 bf16; 1 bias+GELU bf16; 2 f32 residual
// src + gate*(acc+bias); 3 bf16 split-store (buffer = col>>10, row stride 1024,
// buffer stride 4096*1024).
// ---------------------------------------------------------------------------
template <int EPI, int MI, int NJ>
DEV void gemm_epilogue(f32x4 (&acc)[MI][NJ], void* Cout, const float* bias,
                       const float* mods, int gate_ofs, const float* src,
                       int N, int rowsPerB, int m0, int n0, int wm, int wn,
                       int g, int r) {
#pragma unroll
  for (int i = 0; i < MI; ++i) {
#pragma unroll
    for (int j = 0; j < NJ; ++j) {
#pragma unroll
      for (int q = 0; q < 4; ++q) {
        size_t grow = (size_t)(m0 + wm + i * 16 + g * 4 + q);
        size_t gcol = (size_t)(n0 + wn + j * 16 + r);
        float v = acc[i][j][q];
        if constexpr (EPI == 0) {
          ((unsigned short*)Cout)[grow * N + gcol] = f2b(v);
        } else if constexpr (EPI == 1) {
          v += bias[gcol];
          float ge = 0.5f * v * (1.0f + erff(v * 0.70710678f));
          ((unsigned short*)Cout)[grow * N + gcol] = f2b(ge);
        } else if constexpr (EPI == 3) {
          size_t buf = gcol >> 10;
          ((unsigned short*)Cout)[buf * (4096ull * 1024) + grow * 1024 + (gcol & 1023)] = f2b(v);
        } else {
          v += bias[gcol];
          float gate = 1.0f;
          if (gate_ofs >= 0)
            gate = mods[(grow / rowsPerB) * 6144 + gate_ofs + gcol];
          ((float*)Cout)[grow * N + gcol] = src[grow * N + gcol] + gate * v;
        }
      }
    }
  }
}

// ---------------------------------------------------------------------------
// QKV epilogue with fused RoPE (EPI 4).  j-tiles are head-aligned: d=j*16+r,
// rotation pair (d,d+32) = (acc[i][j], acc[i][j+2]) in the SAME lane.  Applies
// rope to buffers 0 (q) and 1 (k); buffer 2 (v) stored plain.  cs = interleaved
// (cos,sin)[l][d].
// ---------------------------------------------------------------------------
DEV void qkv_rope_epilogue(f32x4 (&acc)[4][4], unsigned short* Cout,
                           const float2* cs, int m0, int n0, int wm, int wn,
                           int g, int r) {
  const int buf = (n0 + wn) >> 10;      // wave-uniform
  const int colbase = (n0 + wn) & 1023;
  unsigned short* base = Cout + (size_t)buf * (4096ull * 1024);
#pragma unroll
  for (int i = 0; i < 4; ++i) {
#pragma unroll
    for (int q = 0; q < 4; ++q) {
      size_t grow = (size_t)(m0 + wm + i * 16 + g * 4 + q);
      unsigned short* orow = base + grow * 1024 + colbase + r;
      if (buf < 2) {
        int l = (int)(grow & 2047);
#pragma unroll
        for (int j = 0; j < 2; ++j) {
          int d = j * 16 + r;
          float2 a = cs[l * 64 + d];
          float2 bb = cs[l * 64 + d + 32];
          float x1 = acc[i][j][q], x2 = acc[i][j + 2][q];
          orow[j * 16] = f2b(x1 * a.x - x2 * a.y);
          orow[(j + 2) * 16] = f2b(x2 * bb.x + x1 * bb.y);
        }
      } else {
#pragma unroll
        for (int j = 0; j < 4; ++j) orow[j * 16] = f2b(acc[i][j][q]);
      }
    }
  }
}

// ---------------------------------------------------------------------------
// GEMM (m97): 128x128, BK=32, implicit overlap.  For >=4 blocks/CU (mlp1).
// ---------------------------------------------------------------------------
template <int EPI>
__global__ __launch_bounds__(256, 2) void gemm_bt(
    const unsigned short* __restrict__ A, const unsigned short* __restrict__ Bt,
    void* __restrict__ Cout, const float* __restrict__ bias,
    const float* __restrict__ mods, int gate_ofs, const float* __restrict__ src,
    int M, int N, int K, int rowsPerB) {
  __shared__ unsigned short As[128 * 32];
  __shared__ unsigned short Bs[128 * 32];
  const int tid = threadIdx.x;
  const int wave = tid >> 6, lane = tid & 63;
  const int g = lane >> 4, r = lane & 15;
  const int m0 = blockIdx.y * 128, n0 = blockIdx.x * 128;
  const int wm = (wave >> 1) * 64, wn = (wave & 1) * 64;
  const int srow = lane >> 2;
  const int scol = (lane & 3) * 8;

  f32x4 acc[4][4] = {};

  for (int k0 = 0; k0 < K; k0 += 32) {
    __syncthreads();
#pragma unroll
    for (int cc = 0; cc < 4; ++cc) {
      int c = wave * 4 + cc;
      int isB = c >> 3;
      int cl = c & 7;
      int row = cl * 16 + srow;
      const unsigned short* gsrc =
          isB ? (Bt + (size_t)(n0 + row) * K + k0 + scol)
              : (A + (size_t)(m0 + row) * K + k0 + scol);
      unsigned short* ldst = (isB ? Bs : As) + cl * 512;
      __builtin_amdgcn_global_load_lds(GLB(gsrc), LDSP(ldst), 16, 0, 0);
    }
    __syncthreads();

    short8 bfr[4];
#pragma unroll
    for (int j = 0; j < 4; ++j)
      bfr[j] = *(const short8*)(&Bs[(wn + j * 16 + r) * 32 + g * 8]);
#pragma unroll
    for (int i = 0; i < 4; ++i) {
      short8 af = *(const short8*)(&As[(wm + i * 16 + r) * 32 + g * 8]);
#pragma unroll
      for (int j = 0; j < 4; ++j)
        acc[i][j] = __builtin_amdgcn_mfma_f32_16x16x32_bf16(af, bfr[j], acc[i][j], 0, 0, 0);
    }
  }
  gemm_epilogue<EPI, 4, 4>(acc, Cout, bias, mods, gate_ofs, src, N, rowsPerB,
                           m0, n0, wm, wn, g, r);
}

// ---------------------------------------------------------------------------
// GEMM (pipelined 128x128): BK=64, 4 LDS bufs, depth-3, counted vmcnt.
// 1 block/CU (128KB LDS).  XCD-grouped decode via mshift.
// EPI==4: fused-RoPE QKV epilogue (cs table passed via `bias`).
// Now also used for wo_s / wo_c / mlp2 (grid 256 = exactly 1 block/CU).
// ---------------------------------------------------------------------------
template <int EPI>
__global__ __launch_bounds__(256) void gemm_pipe(
    const unsigned short* __restrict__ A, const unsigned short* __restrict__ Bt,
    void* __restrict__ Cout, const float* __restrict__ bias,
    const float* __restrict__ mods, int gate_ofs, const float* __restrict__ src,
    int M, int N, int K, int rowsPerB, int mshift) {
  __shared__ unsigned short lds[4 * 16384];
  const int tid = threadIdx.x;
  const int wave = tid >> 6, lane = tid & 63;
  const int g = lane >> 4, r = lane & 15;
  const int flat = blockIdx.x;
  const int xcd = flat & 7, idx = flat >> 3;
  const int mt = xcd * (1 << mshift) + (idx & ((1 << mshift) - 1));
  const int nt = idx >> mshift;
  const int m0 = mt * 128, n0 = nt * 128;
  const int wm = (wave >> 1) * 64, wn = (wave & 1) * 64;
  const int srow8 = lane >> 3;
  const int sck = (lane & 7) ^ srow8;

  f32x4 acc[4][4] = {};

  auto stage = [&](int t, int bufi) {
    const int k0 = t * 64;
#pragma unroll
    for (int i = 0; i < 8; ++i) {
      int u = wave * 8 + i;
      int isB = u >> 4;
      int uu = u & 15;
      int rl = uu * 8 + srow8;
      const unsigned short* gsrc =
          (isB ? (Bt + (size_t)(n0 + rl) * K) : (A + (size_t)(m0 + rl) * K)) +
          k0 + sck * 8;
      unsigned short* dst = (unsigned short*)lds + bufi * 16384 + isB * 8192 + uu * 512;
      __builtin_amdgcn_global_load_lds(GLB(gsrc), LDSP(dst), 16, 0, 0);
    }
  };

  const int nt_k = K / 64;
  stage(0, 0);
  stage(1, 1);
  stage(2, 2);

  for (int t = 0; t < nt_k; ++t) {
    int rem = nt_k - t;
    if (rem >= 3) {
      asm volatile("s_waitcnt vmcnt(16)" ::: "memory");
    } else if (rem == 2) {
      asm volatile("s_waitcnt vmcnt(8)" ::: "memory");
    } else {
      asm volatile("s_waitcnt vmcnt(0)" ::: "memory");
    }
    __builtin_amdgcn_sched_barrier(0);
    __builtin_amdgcn_s_barrier();
    __builtin_amdgcn_sched_barrier(0);
    if (t + 3 < nt_k) stage(t + 3, (t + 3) & 3);

    const unsigned short* Ab = (const unsigned short*)lds + (t & 3) * 16384;
    const unsigned short* Bb = Ab + 8192;
#pragma unroll
    for (int ks = 0; ks < 2; ++ks) {
      short8 bfr[4];
#pragma unroll
      for (int j = 0; j < 4; ++j) {
        int row = wn + j * 16 + r;
        bfr[j] = *(const short8*)&Bb[row * 64 + ((g + ks * 4) ^ (r & 7)) * 8];
      }
#pragma unroll
      for (int i = 0; i < 4; ++i) {
        int row = wm + i * 16 + r;
        short8 af = *(const short8*)&Ab[row * 64 + ((g + ks * 4) ^ (r & 7)) * 8];
#pragma unroll
        for (int j = 0; j < 4; ++j)
          acc[i][j] = __builtin_amdgcn_mfma_f32_16x16x32_bf16(af, bfr[j], acc[i][j], 0, 0, 0);
      }
    }
  }
  if constexpr (EPI == 4) {
    qkv_rope_epilogue(acc, (unsigned short*)Cout, (const float2*)bias,
                      m0, n0, wm, wn, g, r);
  } else {
    gemm_epilogue<EPI, 4, 4>(acc, Cout, bias, mods, gate_ofs, src, N, rowsPerB,
                             m0, n0, wm, wn, g, r);
  }
}

// ---------------------------------------------------------------------------
// GEMM (64x128 tile): 4 waves of 32x64, BK=64, 3 LDS bufs (72KB),
// depth-2 counted vmcnt(6).  Retained for gemm_cross's kv half (M=1024).
// ---------------------------------------------------------------------------
template <int EPI>
__global__ __launch_bounds__(256) void gemm_p2(
    const unsigned short* __restrict__ A, const unsigned short* __restrict__ Bt,
    void* __restrict__ Cout, const float* __restrict__ bias,
    const float* __restrict__ mods, int gate_ofs, const float* __restrict__ src,
    int M, int N, int K, int rowsPerB, int ntn) {
  __shared__ unsigned short lds[3 * 12288];  // per buf: A 64x64 (8KB) | B 128x64 (16KB)
  const int tid = threadIdx.x;
  const int wave = tid >> 6, lane = tid & 63;
  const int g = lane >> 4, r = lane & 15;
  const int flat = blockIdx.x;
  const int nt = flat % ntn, mt = flat / ntn;
  const int m0 = mt * 64, n0 = nt * 128;
  const int wm = (wave >> 1) * 32, wn = (wave & 1) * 64;
  const int srow8 = lane >> 3;
  const int sck = (lane & 7) ^ srow8;

  f32x4 acc[2][4] = {};

  auto stage = [&](int t, int bufi) {
    const int k0 = t * 64;
    unsigned short* base = (unsigned short*)lds + bufi * 12288;
#pragma unroll
    for (int i = 0; i < 2; ++i) {  // A units: 8 of 64 rows
      int u = wave * 2 + i;
      int rl = u * 8 + srow8;
      const unsigned short* gsrc = A + (size_t)(m0 + rl) * K + k0 + sck * 8;
      __builtin_amdgcn_global_load_lds(GLB(gsrc), LDSP(base + u * 512), 16, 0, 0);
    }
#pragma unroll
    for (int i = 0; i < 4; ++i) {  // B units: 16 of 128 rows
      int u = wave * 4 + i;
      int rl = u * 8 + srow8;
      const unsigned short* gsrc = Bt + (size_t)(n0 + rl) * K + k0 + sck * 8;
      __builtin_amdgcn_global_load_lds(GLB(gsrc), LDSP(base + 4096 + u * 512), 16, 0, 0);
    }
  };

  const int ntk = K / 64;
  stage(0, 0);
  stage(1, 1);
  int cbuf = 0, sbuf = 2;

  for (int t = 0; t < ntk; ++t) {
    if (t < ntk - 1) {
      asm volatile("s_waitcnt vmcnt(6)" ::: "memory");
    } else {
      asm volatile("s_waitcnt vmcnt(0)" ::: "memory");
    }
    __builtin_amdgcn_sched_barrier(0);
    __builtin_amdgcn_s_barrier();
    __builtin_amdgcn_sched_barrier(0);
    if (t + 2 < ntk) {
      stage(t + 2, sbuf);
      sbuf = (sbuf == 2) ? 0 : sbuf + 1;
    }

    const unsigned short* Ab = (const unsigned short*)lds + cbuf * 12288;
    const unsigned short* Bb = Ab + 4096;
#pragma unroll
    for (int ks = 0; ks < 2; ++ks) {
      short8 bfr[4];
#pragma unroll
      for (int j = 0; j < 4; ++j) {
        int row = wn + j * 16 + r;
        bfr[j] = *(const short8*)&Bb[row * 64 + ((g + ks * 4) ^ (r & 7)) * 8];
      }
#pragma unroll
      for (int i = 0; i < 2; ++i) {
        int row = wm + i * 16 + r;
        short8 af = *(const short8*)&Ab[row * 64 + ((g + ks * 4) ^ (r & 7)) * 8];
#pragma unroll
        for (int j = 0; j < 4; ++j)
          acc[i][j] = __builtin_amdgcn_mfma_f32_16x16x32_bf16(af, bfr[j], acc[i][j], 0, 0, 0);
      }
    }
    cbuf = (cbuf == 2) ? 0 : cbuf + 1;
  }
  gemm_epilogue<EPI, 2, 4>(acc, Cout, bias, mods, gate_ofs, src, N, rowsPerB,
                           m0, n0, wm, wn, g, r);
}

// ---------------------------------------------------------------------------
// gemm_cross: fused cross-attention Q-proj + KV-proj in ONE launch (768 blk).
//   blocks [0,512):   q = nx(4096x1024) @ wqcT,  N=1024, ntn=8  -> qb (bf16)
//   blocks [512,768): kv = ctxb(1024x1024) @ wkcT(+wvcT adj), N=2048, ntn=16
//                     -> kb/vb split-store (EPI3 layout)
// ---------------------------------------------------------------------------
__global__ __launch_bounds__(256) void gemm_cross(
    const unsigned short* __restrict__ Anx, const unsigned short* __restrict__ Bq,
    unsigned short* __restrict__ Oq,
    const unsigned short* __restrict__ Actx, const unsigned short* __restrict__ Bkv,
    unsigned short* __restrict__ Okv) {
  __shared__ unsigned short lds[3 * 12288];
  const int tid = threadIdx.x;
  const int wave = tid >> 6, lane = tid & 63;
  const int g = lane >> 4, r = lane & 15;
  const bool iskv = blockIdx.x >= 512;
  const int flat = iskv ? (blockIdx.x - 512) : blockIdx.x;
  const int ntn = iskv ? 16 : 8;
  const unsigned short* A = iskv ? Actx : Anx;
  const unsigned short* Bt = iskv ? Bkv : Bq;
  const int nt = flat % ntn, mt = flat / ntn;
  const int m0 = mt * 64, n0 = nt * 128;
  const int K = 1024;
  const int wm = (wave >> 1) * 32, wn = (wave & 1) * 64;
  const int srow8 = lane >> 3;
  const int sck = (lane & 7) ^ srow8;

  f32x4 acc[2][4] = {};

  auto stage = [&](int t, int bufi) {
    const int k0 = t * 64;
    unsigned short* base = (unsigned short*)lds + bufi * 12288;
#pragma unroll
    for (int i = 0; i < 2; ++i) {
      int u = wave * 2 + i;
      int rl = u * 8 + srow8;
      const unsigned short* gsrc = A + (size_t)(m0 + rl) * K + k0 + sck * 8;
      __builtin_amdgcn_global_load_lds(GLB(gsrc), LDSP(base + u * 512), 16, 0, 0);
    }
#pragma unroll
    for (int i = 0; i < 4; ++i) {
      int u = wave * 4 + i;
      int rl = u * 8 + srow8;
      const unsigned short* gsrc = Bt + (size_t)(n0 + rl) * K + k0 + sck * 8;
      __builtin_amdgcn_global_load_lds(GLB(gsrc), LDSP(base + 4096 + u * 512), 16, 0, 0);
    }
  };

  const int ntk = K / 64;
  stage(0, 0);
  stage(1, 1);
  int cbuf = 0, sbuf = 2;

  for (int t = 0; t < ntk; ++t) {
    if (t < ntk - 1) {
      asm volatile("s_waitcnt vmcnt(6)" ::: "memory");
    } else {
      asm volatile("s_waitcnt vmcnt(0)" ::: "memory");
    }
    __builtin_amdgcn_sched_barrier(0);
    __builtin_amdgcn_s_barrier();
    __builtin_amdgcn_sched_barrier(0);
    if (t + 2 < ntk) {
      stage(t + 2, sbuf);
      sbuf = (sbuf == 2) ? 0 : sbuf + 1;
    }

    const unsigned short* Ab = (const unsigned short*)lds + cbuf * 12288;
    const unsigned short* Bb = Ab + 4096;
#pragma unroll
    for (int ks = 0; ks < 2; ++ks) {
      short8 bfr[4];
#pragma unroll
      for (int j = 0; j < 4; ++j) {
        int row = wn + j * 16 + r;
        bfr[j] = *(const short8*)&Bb[row * 64 + ((g + ks * 4) ^ (r & 7)) * 8];
      }
#pragma unroll
      for (int i = 0; i < 2; ++i) {
        int row = wm + i * 16 + r;
        short8 af = *(const short8*)&Ab[row * 64 + ((g + ks * 4) ^ (r & 7)) * 8];
#pragma unroll
        for (int j = 0; j < 4; ++j)
          acc[i][j] = __builtin_amdgcn_mfma_f32_16x16x32_bf16(af, bfr[j], acc[i][j], 0, 0, 0);
      }
    }
    cbuf = (cbuf == 2) ? 0 : cbuf + 1;
  }

#pragma unroll
  for (int i = 0; i < 2; ++i) {
#pragma unroll
    for (int j = 0; j < 4; ++j) {
#pragma unroll
      for (int q = 0; q < 4; ++q) {
        size_t grow = (size_t)(m0 + wm + i * 16 + g * 4 + q);
        size_t gcol = (size_t)(n0 + wn + j * 16 + r);
        float v = acc[i][j][q];
        if (iskv) {
          size_t buf = gcol >> 10;
          Okv[buf * (4096ull * 1024) + grow * 1024 + (gcol & 1023)] = f2b(v);
        } else {
          Oq[grow * 1024 + gcol] = f2b(v);
        }
      }
    }
  }
}

// ---------------------------------------------------------------------------
// Flash attention v9 (converged): 128 q/block, T15 pipeline, cvt_pk, max3,
// fused-scale, perm V-pack, setprio(PV).  Blind VALU edits exhausted — frozen.
// ---------------------------------------------------------------------------
__global__ __launch_bounds__(256, 2) void flash2(
    const unsigned short* __restrict__ Q, const unsigned short* __restrict__ Kv,
    const unsigned short* __restrict__ Vv, unsigned short* __restrict__ O,
    int Lk) {
  __shared__ unsigned short lds[20480];  // 40KB: K 3x8KB @0 | V^T 2x8KB @12288
  const int tid = threadIdx.x, wave = tid >> 6, lane = tid & 63;
  const int hi = lane >> 5, lq = lane & 31;
  const int flat = blockIdx.x;
  const int xcd = flat & 7, rr = flat >> 3;
  const int gl = rr >> 4, qt = rr & 15;
  const int g = xcd * 4 + gl;
  const int h = g & 15, b = g >> 4;
  const int Lq = 2048, D = 1024;

  const unsigned short* Qbase =
      Q + ((size_t)b * Lq + qt * 128 + wave * 32 + lq) * D + h * 64;
  const unsigned short* Kbase = Kv + (size_t)b * Lk * D + h * 64;
  const unsigned short* Vbase = Vv + (size_t)b * Lk * D + h * 64;

  short8 qf[4];
#pragma unroll
  for (int kb = 0; kb < 4; ++kb)
    qf[kb] = *(const short8*)(Qbase + kb * 16 + hi * 8);

  const short8 ones = {0x3F80, 0x3F80, 0x3F80, 0x3F80, 0x3F80, 0x3F80, 0x3F80, 0x3F80};
  const f32x16 z16 = {};  // persistent zero C-operand

  const int kr0 = tid >> 3, kc0 = tid & 7;   // K stage: row, chunk
  const int kvp = tid >> 3, db = tid & 7;    // V stage: kv-pair, d-block
  const int kch0 = (kc0 ^ (kr0 & 7) ^ (kr0 >> 3)) & 7;
  const int kch1 = kch0 ^ 4;
  const int f0 = (lq & 7) ^ (lq >> 3);
  const int swz0 = f0 << 4, swz1 = swz0 ^ 64;

  // kt-invariant V^T write byte-offsets (per-thread constants, reg-resident)
  int vby[8];
#pragma unroll
  for (int e = 0; e < 8; ++e) {
    int d = db * 8 + e;
    vby[e] = d * 128 + ((kvp * 4) ^ (((e ^ db) & 7) << 4));
  }

  float m_run = -3.0e38f;
  f32x16 o0 = {}, o1 = {}, lacc = {};
  short8 vr0, vr1;
  short8 pbf[4];

  auto stageK = [&](int t, int bi) {
    const unsigned short* s0 = Kbase + (size_t)(t * 64 + kr0) * D + kch0 * 8;
    const unsigned short* s1 = Kbase + (size_t)(t * 64 + kr0 + 32) * D + kch1 * 8;
    __builtin_amdgcn_global_load_lds(GLB(s0), LDSP(&lds[bi * 4096 + wave * 512]), 16, 0, 0);
    __builtin_amdgcn_global_load_lds(GLB(s1), LDSP(&lds[bi * 4096 + 2048 + wave * 512]), 16, 0, 0);
  };
  auto loadV = [&](int t) {
    const unsigned short* v0 = Vbase + (size_t)(t * 64 + 2 * kvp) * D + db * 8;
    vr0 = *(const short8*)v0;
    vr1 = *(const short8*)(v0 + D);
  };
  auto writeV = [&](int t) {
    char* vt = (char*)&lds[12288 + (t & 1) * 4096];
    union { short8 s; unsigned int u[4]; } a, c;
    a.s = vr0; c.s = vr1;
#pragma unroll
    for (int k = 0; k < 4; ++k) {
      *(unsigned int*)(vt + vby[2 * k]) =
          __builtin_amdgcn_perm(c.u[k], a.u[k], 0x05040100u);
      *(unsigned int*)(vt + vby[2 * k + 1]) =
          __builtin_amdgcn_perm(c.u[k], a.u[k], 0x07060302u);
    }
  };
  auto qk = [&](int bi, f32x16& sa0, f32x16& sa1) {
    const unsigned short* K0 = &lds[bi * 4096];
    {
      int lo = hi * 16;
      short8 a0 = *(const short8*)&K0[lq * 64 + ((lo ^ swz0) >> 1)];
      short8 a1 = *(const short8*)&K0[(32 + lq) * 64 + ((lo ^ swz1) >> 1)];
      sa0 = __builtin_amdgcn_mfma_f32_32x32x16_bf16(a0, qf[0], z16, 0, 0, 0);
      sa1 = __builtin_amdgcn_mfma_f32_32x32x16_bf16(a1, qf[0], z16, 0, 0, 0);
    }
#pragma unroll
    for (int ks = 1; ks < 4; ++ks) {
      int lo = ks * 32 + hi * 16;
      short8 a0 = *(const short8*)&K0[lq * 64 + ((lo ^ swz0) >> 1)];
      short8 a1 = *(const short8*)&K0[(32 + lq) * 64 + ((lo ^ swz1) >> 1)];
      sa0 = __builtin_amdgcn_mfma_f32_32x32x16_bf16(a0, qf[ks], sa0, 0, 0, 0);
      sa1 = __builtin_amdgcn_mfma_f32_32x32x16_bf16(a1, qf[ks], sa1, 0, 0, 0);
    }
  };
  auto finish = [&](f32x16& s0a, f32x16& s1a) {
    float tm[8];
#pragma unroll
    for (int i = 0; i < 8; ++i)
      tm[i] = fmaxf(max3f(s0a[i], s0a[i + 8], s1a[i]), s1a[i + 8]);
    float x = max3f(tm[0], tm[1], tm[2]);
    float y = max3f(tm[3], tm[4], tm[5]);
    float pm = fmaxf(max3f(tm[6], tm[7], x), y);
    {
      unsigned int ua = __builtin_bit_cast(unsigned int, pm), ub = ua;
      vpsw(ua, ub);
      pm = fmaxf(__builtin_bit_cast(float, ua), __builtin_bit_cast(float, ub));
    }
    if (__any(pm - m_run > 8.0f)) {
      float mnew = fmaxf(m_run, pm);
      float alpha = exp2f(m_run - mnew);
      lacc[0] *= alpha;
#pragma unroll
      for (int i = 0; i < 16; ++i) { o0[i] *= alpha; o1[i] *= alpha; }
      m_run = mnew;
    }
    float mc = m_run;
#pragma unroll
    for (int i = 0; i < 16; ++i) s0a[i] = exp2f(s0a[i] - mc);
#pragma unroll
    for (int i = 0; i < 16; ++i) s1a[i] = exp2f(s1a[i] - mc);
#pragma unroll
    for (int kb = 0; kb < 4; ++kb) {
      int bb = (kb & 1) * 8;
      float p0, p1, p2, p3, p4, p5, p6, p7;
      if (kb < 2) {
        p0 = s0a[bb + 0]; p1 = s0a[bb + 1]; p2 = s0a[bb + 2]; p3 = s0a[bb + 3];
        p4 = s0a[bb + 4]; p5 = s0a[bb + 5]; p6 = s0a[bb + 6]; p7 = s0a[bb + 7];
      } else {
        p0 = s1a[bb + 0]; p1 = s1a[bb + 1]; p2 = s1a[bb + 2]; p3 = s1a[bb + 3];
        p4 = s1a[bb + 4]; p5 = s1a[bb + 5]; p6 = s1a[bb + 6]; p7 = s1a[bb + 7];
      }
      unsigned int u0 = pk2(p0, p1), u1 = pk2(p2, p3);
      unsigned int u2 = pk2(p4, p5), u3 = pk2(p6, p7);
      vpsw(u0, u2);
      vpsw(u1, u3);
      union { unsigned int u[4]; short8 s; } fr;
      fr.u[0] = u0; fr.u[1] = u1; fr.u[2] = u2; fr.u[3] = u3;
      pbf[kb] = fr.s;
    }
  };
  auto pv = [&](int t) {
    const unsigned short* V0 = &lds[12288 + (t & 1) * 4096];
    __builtin_amdgcn_s_setprio(1);
#pragma unroll
    for (int kb = 0; kb < 4; ++kb) {
      int lo = kb * 32 + hi * 16;
      short8 vf0 = *(const short8*)&V0[lq * 64 + ((lo ^ swz0) >> 1)];
      short8 vf1 = *(const short8*)&V0[(32 + lq) * 64 + ((lo ^ swz1) >> 1)];
      o0 = __builtin_amdgcn_mfma_f32_32x32x16_bf16(vf0, pbf[kb], o0, 0, 0, 0);
      o1 = __builtin_amdgcn_mfma_f32_32x32x16_bf16(vf1, pbf[kb], o1, 0, 0, 0);
      lacc = __builtin_amdgcn_mfma_f32_32x32x16_bf16(ones, pbf[kb], lacc, 0, 0, 0);
    }
    __builtin_amdgcn_s_setprio(0);
  };

  const int nkt = Lk / 64;  // even for both Lk=2048 (32) and Lk=512 (8)

  // prologue: K(0)->buf0, V(0)->Vbuf0, K(1)->buf1, then S(0)
  stageK(0, 0);
  loadV(0);
  writeV(0);
  stageK(1, 1);
  __syncthreads();

  f32x16 sA0, sA1, sB0, sB1;
  qk(0, sA0, sA1);

  // pipelined step: QK(t+1)->snew (MFMA) overlaps finish(sold) (VALU); PV(t)
  auto pstep = [&](int t, f32x16& n0, f32x16& n1, f32x16& p0, f32x16& p1) {
    const int tq = t + 1;
    if (tq < nkt) {
      loadV(tq);
      if (tq + 1 < nkt) stageK(tq + 1, (tq + 1) % 3);
      qk(tq % 3, n0, n1);
    }
    finish(p0, p1);
    if (tq < nkt) writeV(tq);
    pv(t);
    __syncthreads();
  };

  for (int t = 0; t < nkt; t += 2) {
    pstep(t, sB0, sB1, sA0, sA1);
    pstep(t + 1, sA0, sA1, sB0, sB1);
  }

  // ---- epilogue: normalize, bounce through LDS, coalesced store ----
  float rl = 1.0f / lacc[0];
  unsigned short* os = &lds[wave * 2048];
#pragma unroll
  for (int t = 0; t < 2; ++t) {
#pragma unroll
    for (int c = 0; c < 4; ++c) {
      int dbase = 32 * t + 8 * c + 4 * hi;
      float v0 = (t ? o1[4 * c + 0] : o0[4 * c + 0]) * rl;
      float v1 = (t ? o1[4 * c + 1] : o0[4 * c + 1]) * rl;
      float v2 = (t ? o1[4 * c + 2] : o0[4 * c + 2]) * rl;
      float v3 = (t ? o1[4 * c + 3] : o0[4 * c + 3]) * rl;
      int by0 = lq * 128 + ((dbase * 2) ^ ((lq & 7) << 4));
      int by1 = lq * 128 + (((dbase + 2) * 2) ^ ((lq & 7) << 4));
      *(unsigned int*)((char*)os + by0) = pk2(v0, v1);
      *(unsigned int*)((char*)os + by1) = pk2(v2, v3);
    }
  }
  int q2 = lane >> 1;
  unsigned short* orow =
      O + ((size_t)b * Lq + qt * 128 + wave * 32 + q2) * D + h * 64;
#pragma unroll
  for (int j = 0; j < 4; ++j) {
    int j2 = (lane & 1) * 4 + j;
    int byr = q2 * 128 + ((j2 * 16) ^ ((q2 & 7) << 4));
    short8 vv = *(const short8*)((char*)os + byr);
    *(short8*)(orow + j2 * 8) = vv;
  }
}

// ---------------------------------------------------------------------------
// Host orchestration
// ---------------------------------------------------------------------------
extern "C" void kernel_launch(void* const* d_in, const int* in_sizes, int n_in,
                              void* d_out, int out_size, void* d_ws, size_t ws_size,
                              hipStream_t stream) {
  (void)in_sizes; (void)n_in; (void)out_size; (void)ws_size;
  const float* x_in = (const float*)d_in[0];
  const float* te   = (const float*)d_in[1];
  const float* ctx  = (const float*)d_in[2];
  const float* rope = (const float*)d_in[3];
  const float* wmod = (const float*)d_in[4];
  const float* bmod = (const float*)d_in[5];
  const float* wqs  = (const float*)d_in[6];
  const float* wks  = (const float*)d_in[7];
  const float* wvs  = (const float*)d_in[8];
  const float* wos  = (const float*)d_in[9];
  const float* bos  = (const float*)d_in[10];
  const float* wqc  = (const float*)d_in[11];
  const float* wkc  = (const float*)d_in[12];
  const float* wvc  = (const float*)d_in[13];
  const float* woc  = (const float*)d_in[14];
  const float* boc  = (const float*)d_in[15];
  const float* w1   = (const float*)d_in[16];
  const float* b1   = (const float*)d_in[17];
  const float* w2   = (const float*)d_in[18];
  const float* b2   = (const float*)d_in[19];
  float* out = (float*)d_out;

  char* w = (char*)d_ws;
  size_t o = 0;
  auto alloc = [&](size_t bytes) {
    char* p = w + o;
    o = (o + bytes + 255) & ~(size_t)255;
    return p;
  };
  // wqsT/wksT/wvsT adjacent (fused QKV); wkcT/wvcT adjacent (fused cross-KV).
  unsigned short* wqsT  = (unsigned short*)alloc(1024ull * 1024 * 2);
  unsigned short* wksT  = (unsigned short*)alloc(1024ull * 1024 * 2);
  unsigned short* wvsT  = (unsigned short*)alloc(1024ull * 1024 * 2);
  unsigned short* wosT  = (unsigned short*)alloc(1024ull * 1024 * 2);
  unsigned short* wqcT  = (unsigned short*)alloc(1024ull * 1024 * 2);
  unsigned short* wkcT  = (unsigned short*)alloc(1024ull * 1024 * 2);
  unsigned short* wvcT  = (unsigned short*)alloc(1024ull * 1024 * 2);
  unsigned short* wocT  = (unsigned short*)alloc(1024ull * 1024 * 2);
  unsigned short* w1T   = (unsigned short*)alloc(4096ull * 1024 * 2);
  unsigned short* w2T   = (unsigned short*)alloc(1024ull * 4096 * 2);
  float* modsb = (float*)alloc(2ull * 6144 * 4);
  float2* csT  = (float2*)alloc(2048ull * 64 * 8);
  unsigned short* nx   = (unsigned short*)alloc(4096ull * 1024 * 2);
  unsigned short* ctxb = (unsigned short*)alloc(1024ull * 1024 * 2);
  // qb/kb/vb adjacent: EPI3/EPI4 buffer stride = 4096*1024 elems.
  unsigned short* qb = (unsigned short*)alloc(4096ull * 1024 * 2);
  unsigned short* kb = (unsigned short*)alloc(4096ull * 1024 * 2);
  unsigned short* vb = (unsigned short*)alloc(4096ull * 1024 * 2);
  unsigned short* ao = (unsigned short*)alloc(4096ull * 1024 * 2);
  float* xw = (float*)alloc(4096ull * 1024 * 4);
  unsigned short* hbuf = qb;  // reuse qb..ao contiguous 32MB for MLP hidden

  const float c1 = 0.125f * 1.4426950408889634f;  // scale * log2(e), folded into wqs/wkc

  PrepArgs pa;
  pa.wmod = wmod; pa.te = te; pa.bmod = bmod; pa.mods = modsb;
  pa.sq[0] = {wqs, wqsT, c1};
  pa.sq[1] = {wks, wksT, 1.0f};
  pa.sq[2] = {wvs, wvsT, 1.0f};
  pa.sq[3] = {wos, wosT, 1.0f};
  pa.sq[4] = {wqc, wqcT, 1.0f};
  pa.sq[5] = {wkc, wkcT, c1};
  pa.sq[6] = {wvc, wvcT, 1.0f};
  pa.sq[7] = {woc, wocT, 1.0f};
  pa.w1 = w1; pa.w1T = w1T;
  pa.w2 = w2; pa.w2T = w2T;
  pa.ctx = ctx; pa.ctxb = ctxb;
  pa.rope = rope; pa.cs = csT;
  prep<<<18968, 256, 0, stream>>>(pa);

  // --- self-attention (RoPE fused into QKV epilogue) ---
  ln_mod<<<4096, 256, 0, stream>>>(x_in, modsb, nx, 1024, 0);
  gemm_pipe<4><<<768, 256, 0, stream>>>(nx, wqsT, qb, (const float*)csT, nullptr, -1, nullptr, 4096, 3072, 1024, 2048, 2);
  flash2<<<512, 256, 0, stream>>>(qb, kb, vb, ao, 2048);
  gemm_pipe<2><<<256, 256, 0, stream>>>(ao, wosT, xw, bos, modsb, 2048, x_in, 4096, 1024, 1024, 2048, 2);

  // --- cross-attention (Q-proj + KV-proj fused in one launch) ---
  ln_mod<<<4096, 256, 0, stream>>>(xw, modsb, nx, -1, -1);
  gemm_cross<<<768, 256, 0, stream>>>(nx, wqcT, qb, ctxb, wkcT, kb);
  flash2<<<512, 256, 0, stream>>>(qb, kb, vb, ao, 512);
  gemm_pipe<2><<<256, 256, 0, stream>>>(ao, wocT, xw, boc, modsb, -1, xw, 4096, 1024, 1024, 2048, 2);

  // --- MLP ---
  ln_mod<<<4096, 256, 0, stream>>>(xw, modsb, nx, 4096, 3072);
  gemm_bt<1><<<dim3(32, 32), 256, 0, stream>>>(nx, w1T, hbuf, b1, nullptr, -1, nullptr, 4096, 4096, 1024, 2048);
  gemm_pipe<2><<<256, 256, 0, stream>>>(hbuf, w2T, out, b2, modsb, 5120, xw, 4096, 1024, 4096, 2048, 2);
}

// Round 9
// 388.261 us; speedup vs baseline: 1.0547x; 1.0547x over previous
//
#include <hip/hip_runtime.h>
#include <hip/hip_bf16.h>

// ---------------------------------------------------------------------------
// CleanDITBlock: adaLN-modulated DiT block (self-attn w/ RoPE, cross-attn, MLP)
// B=2, L=2048, S=512, D=1024, H=16, HD=64, CTX=1024, HID=4096
// ---------------------------------------------------------------------------

typedef short short8 __attribute__((ext_vector_type(8)));
typedef float f32x4 __attribute__((ext_vector_type(4)));
typedef float f32x16 __attribute__((ext_vector_type(16)));

#define DEV __device__ __forceinline__

DEV unsigned short f2b(float f) {
  __hip_bfloat16 h = __float2bfloat16(f);
  return *reinterpret_cast<unsigned short*>(&h);
}
DEV float b2f(unsigned short u) {
  unsigned int x = ((unsigned int)u) << 16;
  return __builtin_bit_cast(float, x);
}
// single-instruction packed f32->bf16 pair (T12): D[15:0]=bf16(lo), D[31:16]=bf16(hi)
DEV unsigned int pk2(float lo, float hi) {
  unsigned int r;
  asm("v_cvt_pk_bf16_f32 %0, %1, %2" : "=v"(r) : "v"(lo), "v"(hi));
  return r;
}
// lane[i]<->lane[i+32] half-swap (VALU, no LDS)
DEV void vpsw(unsigned int& a, unsigned int& b) {
  asm("v_permlane32_swap_b32 %0, %1" : "+v"(a), "+v"(b));
}
// 3-input max (T17)
DEV float max3f(float a, float b, float c) {
  float r;
  asm("v_max3_f32 %0, %1, %2, %3" : "=v"(r) : "v"(a), "v"(b), "v"(c));
  return r;
}

#define GLB(p) ((const __attribute__((address_space(1))) void*)(p))
#define LDSP(p) ((__attribute__((address_space(3))) void*)(p))

// ---------------------------------------------------------------------------
// prep: ALL preprocessing in one launch (flattened grid, range decode).
//   [0,24)            mods = te @ wmod + bmod, computed DIRECTLY from f32 wmod
//   [24,8216)         8 square 1024^2 transposes (wq/wk/wv/wo self+cross)
//   [8216,12312)      w1 transpose (1024x4096 -> 4096x1024)
//   [12312,16408)     w2 transpose (4096x1024 -> 1024x4096)
//   [16408,18456)     ctx f32->bf16 cast, 2 elems/thread (packed cvt)
//   [18456,18968)     rope (cos,sin) table (131072 elems)
// ---------------------------------------------------------------------------
struct TCB { const float* in; unsigned short* out; float scale; };
struct PrepArgs {
  const float* wmod; const float* te; const float* bmod; float* mods;
  TCB sq[8];
  const float* w1; unsigned short* w1T;
  const float* w2; unsigned short* w2T;
  const float* ctx; unsigned short* ctxb;
  const float* rope; float2* cs;
};

__global__ __launch_bounds__(256) void prep(PrepArgs a) {
  __shared__ float t32[32][33];
  __shared__ float tes[2048];
  const int blk = blockIdx.x;
  const int tid = threadIdx.x;
  const int tx = tid & 31, ty = tid >> 5;
  if (blk < 24) {
    // ---- mods: j-chunk of 256 columns, both batches ----
    const int j = blk * 256 + tid;
    for (int u = tid; u < 2048; u += 256) tes[u] = a.te[u];
    __syncthreads();
    float a0 = 0.f, b0 = 0.f, a1 = 0.f, b1 = 0.f;
#pragma unroll 8
    for (int k = 0; k < 1024; k += 2) {
      float v0 = a.wmod[(size_t)k * 6144 + j];
      float v1 = a.wmod[(size_t)(k + 1) * 6144 + j];
      a0 += tes[k] * v0;
      b0 += tes[k + 1] * v1;
      a1 += tes[1024 + k] * v0;
      b1 += tes[1024 + k + 1] * v1;
    }
    float bm = a.bmod[j];
    a.mods[j] = a0 + b0 + bm;
    a.mods[6144 + j] = a1 + b1 + bm;
  } else if (blk < 16408) {
    const float* in;
    unsigned short* out;
    int R, C, gx, tile;
    float scale;
    if (blk < 8216) {
      int j = (blk - 24) >> 10;
      tile = (blk - 24) & 1023;
      in = a.sq[j].in; out = a.sq[j].out; scale = a.sq[j].scale;
      R = 1024; C = 1024; gx = 32;
    } else if (blk < 12312) {
      tile = blk - 8216;
      in = a.w1; out = a.w1T; R = 1024; C = 4096; gx = 128; scale = 1.f;
    } else {
      tile = blk - 12312;
      in = a.w2; out = a.w2T; R = 4096; C = 1024; gx = 32; scale = 1.f;
    }
    int bx = (tile % gx) * 32, by = (tile / gx) * 32;
#pragma unroll
    for (int i = ty; i < 32; i += 8)
      t32[i][tx] = in[(size_t)(by + i) * C + bx + tx];
    __syncthreads();
#pragma unroll
    for (int i = ty; i < 32; i += 8)
      out[(size_t)(bx + i) * R + by + tx] = f2b(t32[tx][i] * scale);
  } else if (blk < 18456) {
    int i = (blk - 16408) * 512 + tid * 2;
    float2 v = *(const float2*)&a.ctx[i];
    *(unsigned int*)&a.ctxb[i] = pk2(v.x, v.y);
  } else {
    int i = (blk - 18456) * 256 + tid;
    float v = a.rope[i];
    a.cs[i] = make_float2(cosf(v), sinf(v));
  }
}

// ---------------------------------------------------------------------------
__global__ __launch_bounds__(256) void ln_mod(
    const float* __restrict__ x, const float* __restrict__ mods,
    unsigned short* __restrict__ out, int scale_ofs, int shift_ofs) {
  int row = blockIdx.x;
  int b = row >> 11;
  int tid = threadIdx.x;
  const float* xr = x + (size_t)row * 1024;
  float4 v = ((const float4*)xr)[tid];
  float s = v.x + v.y + v.z + v.w;
  float ss = v.x * v.x + v.y * v.y + v.z * v.z + v.w * v.w;
#pragma unroll
  for (int off = 32; off >= 1; off >>= 1) {
    s += __shfl_down(s, off);
    ss += __shfl_down(ss, off);
  }
  __shared__ float red[8];
  int wave = tid >> 6, lane = tid & 63;
  if (lane == 0) { red[wave] = s; red[4 + wave] = ss; }
  __syncthreads();
  if (tid == 0) {
    float S = red[0] + red[1] + red[2] + red[3];
    float SS = red[4] + red[5] + red[6] + red[7];
    float mu = S * (1.f / 1024.f);
    red[0] = mu;
    red[1] = SS * (1.f / 1024.f) - mu * mu;
  }
  __syncthreads();
  float mu = red[0];
  float rs = rsqrtf(red[1] + 1e-6f);
  float vv[4] = {v.x, v.y, v.z, v.w};
  unsigned short o[4];
#pragma unroll
  for (int c = 0; c < 4; ++c) {
    int col = tid * 4 + c;
    float nv = (vv[c] - mu) * rs;
    if (scale_ofs >= 0)
      nv = nv * (1.f + mods[(size_t)b * 6144 + scale_ofs + col]) +
           mods[(size_t)b * 6144 + shift_ofs + col];
    o[c] = f2b(nv);
  }
  *(ushort4*)(&out[(size_t)row * 1024 + tid * 4]) = *(const ushort4*)o;
}

// ---------------------------------------------------------------------------
// Shared GEMM epilogue.  EPI: 0 bf16; 1 bias+GELU bf16; 2 f32 residual
// src + gate*(acc+bias); 3 bf16 split-store (buffer = col>>10, row stride 1024,
// buffer stride 4096*1024).
// ---------------------------------------------------------------------------
template <int EPI, int MI, int NJ>
DEV void gemm_epilogue(f32x4 (&acc)[MI][NJ], void* Cout, const float* bias,
                       const float* mods, int gate_ofs, const float* src,
                       int N, int rowsPerB, int m0, int n0, int wm, int wn,
                       int g, int r) {
#pragma unroll
  for (int i = 0; i < MI; ++i) {
#pragma unroll
    for (int j = 0; j < NJ; ++j) {
#pragma unroll
      for (int q = 0; q < 4; ++q) {
        size_t grow = (size_t)(m0 + wm + i * 16 + g * 4 + q);
        size_t gcol = (size_t)(n0 + wn + j * 16 + r);
        float v = acc[i][j][q];
        if constexpr (EPI == 0) {
          ((unsigned short*)Cout)[grow * N + gcol] = f2b(v);
        } else if constexpr (EPI == 1) {
          v += bias[gcol];
          float ge = 0.5f * v * (1.0f + erff(v * 0.70710678f));
          ((unsigned short*)Cout)[grow * N + gcol] = f2b(ge);
        } else if constexpr (EPI == 3) {
          size_t buf = gcol >> 10;
          ((unsigned short*)Cout)[buf * (4096ull * 1024) + grow * 1024 + (gcol & 1023)] = f2b(v);
        } else {
          v += bias[gcol];
          float gate = 1.0f;
          if (gate_ofs >= 0)
            gate = mods[(grow / rowsPerB) * 6144 + gate_ofs + gcol];
          ((float*)Cout)[grow * N + gcol] = src[grow * N + gcol] + gate * v;
        }
      }
    }
  }
}

// ---------------------------------------------------------------------------
// QKV epilogue with fused RoPE (EPI 4).  j-tiles are head-aligned: d=j*16+r,
// rotation pair (d,d+32) = (acc[i][j], acc[i][j+2]) in the SAME lane.  Applies
// rope to buffers 0 (q) and 1 (k); buffer 2 (v) stored plain.  cs = interleaved
// (cos,sin)[l][d].
// ---------------------------------------------------------------------------
DEV void qkv_rope_epilogue(f32x4 (&acc)[4][4], unsigned short* Cout,
                           const float2* cs, int m0, int n0, int wm, int wn,
                           int g, int r) {
  const int buf = (n0 + wn) >> 10;      // wave-uniform
  const int colbase = (n0 + wn) & 1023;
  unsigned short* base = Cout + (size_t)buf * (4096ull * 1024);
#pragma unroll
  for (int i = 0; i < 4; ++i) {
#pragma unroll
    for (int q = 0; q < 4; ++q) {
      size_t grow = (size_t)(m0 + wm + i * 16 + g * 4 + q);
      unsigned short* orow = base + grow * 1024 + colbase + r;
      if (buf < 2) {
        int l = (int)(grow & 2047);
#pragma unroll
        for (int j = 0; j < 2; ++j) {
          int d = j * 16 + r;
          float2 a = cs[l * 64 + d];
          float2 bb = cs[l * 64 + d + 32];
          float x1 = acc[i][j][q], x2 = acc[i][j + 2][q];
          orow[j * 16] = f2b(x1 * a.x - x2 * a.y);
          orow[(j + 2) * 16] = f2b(x2 * bb.x + x1 * bb.y);
        }
      } else {
#pragma unroll
        for (int j = 0; j < 4; ++j) orow[j * 16] = f2b(acc[i][j][q]);
      }
    }
  }
}

// ---------------------------------------------------------------------------
// GEMM (m97): 128x128, BK=32, implicit overlap.  For >=4 blocks/CU (mlp1).
// ---------------------------------------------------------------------------
template <int EPI>
__global__ __launch_bounds__(256, 2) void gemm_bt(
    const unsigned short* __restrict__ A, const unsigned short* __restrict__ Bt,
    void* __restrict__ Cout, const float* __restrict__ bias,
    const float* __restrict__ mods, int gate_ofs, const float* __restrict__ src,
    int M, int N, int K, int rowsPerB) {
  __shared__ unsigned short As[128 * 32];
  __shared__ unsigned short Bs[128 * 32];
  const int tid = threadIdx.x;
  const int wave = tid >> 6, lane = tid & 63;
  const int g = lane >> 4, r = lane & 15;
  const int m0 = blockIdx.y * 128, n0 = blockIdx.x * 128;
  const int wm = (wave >> 1) * 64, wn = (wave & 1) * 64;
  const int srow = lane >> 2;
  const int scol = (lane & 3) * 8;

  f32x4 acc[4][4] = {};

  for (int k0 = 0; k0 < K; k0 += 32) {
    __syncthreads();
#pragma unroll
    for (int cc = 0; cc < 4; ++cc) {
      int c = wave * 4 + cc;
      int isB = c >> 3;
      int cl = c & 7;
      int row = cl * 16 + srow;
      const unsigned short* gsrc =
          isB ? (Bt + (size_t)(n0 + row) * K + k0 + scol)
              : (A + (size_t)(m0 + row) * K + k0 + scol);
      unsigned short* ldst = (isB ? Bs : As) + cl * 512;
      __builtin_amdgcn_global_load_lds(GLB(gsrc), LDSP(ldst), 16, 0, 0);
    }
    __syncthreads();

    short8 bfr[4];
#pragma unroll
    for (int j = 0; j < 4; ++j)
      bfr[j] = *(const short8*)(&Bs[(wn + j * 16 + r) * 32 + g * 8]);
#pragma unroll
    for (int i = 0; i < 4; ++i) {
      short8 af = *(const short8*)(&As[(wm + i * 16 + r) * 32 + g * 8]);
#pragma unroll
      for (int j = 0; j < 4; ++j)
        acc[i][j] = __builtin_amdgcn_mfma_f32_16x16x32_bf16(af, bfr[j], acc[i][j], 0, 0, 0);
    }
  }
  gemm_epilogue<EPI, 4, 4>(acc, Cout, bias, mods, gate_ofs, src, N, rowsPerB,
                           m0, n0, wm, wn, g, r);
}

// ---------------------------------------------------------------------------
// GEMM (pipelined 128x128): BK=64, 4 LDS bufs, depth-3, counted vmcnt.
// For the QKV GEMM (grid 768, 1 block/CU + 3-deep pipeline).
// EPI==4: fused-RoPE QKV epilogue (cs table passed via `bias`).
// NOTE (r8): do NOT use at grid 256 for the N=1024 GEMMs — 1 block/CU with
// no co-resident overlap loses ~23us vs gemm_p2's 512-block config.
// ---------------------------------------------------------------------------
template <int EPI>
__global__ __launch_bounds__(256) void gemm_pipe(
    const unsigned short* __restrict__ A, const unsigned short* __restrict__ Bt,
    void* __restrict__ Cout, const float* __restrict__ bias,
    const float* __restrict__ mods, int gate_ofs, const float* __restrict__ src,
    int M, int N, int K, int rowsPerB, int mshift) {
  __shared__ unsigned short lds[4 * 16384];
  const int tid = threadIdx.x;
  const int wave = tid >> 6, lane = tid & 63;
  const int g = lane >> 4, r = lane & 15;
  const int flat = blockIdx.x;
  const int xcd = flat & 7, idx = flat >> 3;
  const int mt = xcd * (1 << mshift) + (idx & ((1 << mshift) - 1));
  const int nt = idx >> mshift;
  const int m0 = mt * 128, n0 = nt * 128;
  const int wm = (wave >> 1) * 64, wn = (wave & 1) * 64;
  const int srow8 = lane >> 3;
  const int sck = (lane & 7) ^ srow8;

  f32x4 acc[4][4] = {};

  auto stage = [&](int t, int bufi) {
    const int k0 = t * 64;
#pragma unroll
    for (int i = 0; i < 8; ++i) {
      int u = wave * 8 + i;
      int isB = u >> 4;
      int uu = u & 15;
      int rl = uu * 8 + srow8;
      const unsigned short* gsrc =
          (isB ? (Bt + (size_t)(n0 + rl) * K) : (A + (size_t)(m0 + rl) * K)) +
          k0 + sck * 8;
      unsigned short* dst = (unsigned short*)lds + bufi * 16384 + isB * 8192 + uu * 512;
      __builtin_amdgcn_global_load_lds(GLB(gsrc), LDSP(dst), 16, 0, 0);
    }
  };

  const int nt_k = K / 64;
  stage(0, 0);
  stage(1, 1);
  stage(2, 2);

  for (int t = 0; t < nt_k; ++t) {
    int rem = nt_k - t;
    if (rem >= 3) {
      asm volatile("s_waitcnt vmcnt(16)" ::: "memory");
    } else if (rem == 2) {
      asm volatile("s_waitcnt vmcnt(8)" ::: "memory");
    } else {
      asm volatile("s_waitcnt vmcnt(0)" ::: "memory");
    }
    __builtin_amdgcn_sched_barrier(0);
    __builtin_amdgcn_s_barrier();
    __builtin_amdgcn_sched_barrier(0);
    if (t + 3 < nt_k) stage(t + 3, (t + 3) & 3);

    const unsigned short* Ab = (const unsigned short*)lds + (t & 3) * 16384;
    const unsigned short* Bb = Ab + 8192;
#pragma unroll
    for (int ks = 0; ks < 2; ++ks) {
      short8 bfr[4];
#pragma unroll
      for (int j = 0; j < 4; ++j) {
        int row = wn + j * 16 + r;
        bfr[j] = *(const short8*)&Bb[row * 64 + ((g + ks * 4) ^ (r & 7)) * 8];
      }
#pragma unroll
      for (int i = 0; i < 4; ++i) {
        int row = wm + i * 16 + r;
        short8 af = *(const short8*)&Ab[row * 64 + ((g + ks * 4) ^ (r & 7)) * 8];
#pragma unroll
        for (int j = 0; j < 4; ++j)
          acc[i][j] = __builtin_amdgcn_mfma_f32_16x16x32_bf16(af, bfr[j], acc[i][j], 0, 0, 0);
      }
    }
  }
  if constexpr (EPI == 4) {
    qkv_rope_epilogue(acc, (unsigned short*)Cout, (const float2*)bias,
                      m0, n0, wm, wn, g, r);
  } else {
    gemm_epilogue<EPI, 4, 4>(acc, Cout, bias, mods, gate_ofs, src, N, rowsPerB,
                             m0, n0, wm, wn, g, r);
  }
}

// ---------------------------------------------------------------------------
// GEMM (64x128 tile, 2-blocks/CU): 4 waves of 32x64, BK=64, 3 LDS bufs (72KB),
// depth-2 counted vmcnt(6).  Grid = (M/64)*(N/128); nt = flat % ntn puts one
// B-panel per XCD when ntn==8.  PROVEN best for the grid-512 N=1024 GEMMs
// (r8: 128^2 pipe at 1 block/CU is 23us slower across wo_s/wo_c/mlp2).
// ---------------------------------------------------------------------------
template <int EPI>
__global__ __launch_bounds__(256) void gemm_p2(
    const unsigned short* __restrict__ A, const unsigned short* __restrict__ Bt,
    void* __restrict__ Cout, const float* __restrict__ bias,
    const float* __restrict__ mods, int gate_ofs, const float* __restrict__ src,
    int M, int N, int K, int rowsPerB, int ntn) {
  __shared__ unsigned short lds[3 * 12288];  // per buf: A 64x64 (8KB) | B 128x64 (16KB)
  const int tid = threadIdx.x;
  const int wave = tid >> 6, lane = tid & 63;
  const int g = lane >> 4, r = lane & 15;
  const int flat = blockIdx.x;
  const int nt = flat % ntn, mt = flat / ntn;
  const int m0 = mt * 64, n0 = nt * 128;
  const int wm = (wave >> 1) * 32, wn = (wave & 1) * 64;
  const int srow8 = lane >> 3;
  const int sck = (lane & 7) ^ srow8;

  f32x4 acc[2][4] = {};

  auto stage = [&](int t, int bufi) {
    const int k0 = t * 64;
    unsigned short* base = (unsigned short*)lds + bufi * 12288;
#pragma unroll
    for (int i = 0; i < 2; ++i) {  // A units: 8 of 64 rows
      int u = wave * 2 + i;
      int rl = u * 8 + srow8;
      const unsigned short* gsrc = A + (size_t)(m0 + rl) * K + k0 + sck * 8;
      __builtin_amdgcn_global_load_lds(GLB(gsrc), LDSP(base + u * 512), 16, 0, 0);
    }
#pragma unroll
    for (int i = 0; i < 4; ++i) {  // B units: 16 of 128 rows
      int u = wave * 4 + i;
      int rl = u * 8 + srow8;
      const unsigned short* gsrc = Bt + (size_t)(n0 + rl) * K + k0 + sck * 8;
      __builtin_amdgcn_global_load_lds(GLB(gsrc), LDSP(base + 4096 + u * 512), 16, 0, 0);
    }
  };

  const int ntk = K / 64;
  stage(0, 0);
  stage(1, 1);
  int cbuf = 0, sbuf = 2;

  for (int t = 0; t < ntk; ++t) {
    if (t < ntk - 1) {
      asm volatile("s_waitcnt vmcnt(6)" ::: "memory");
    } else {
      asm volatile("s_waitcnt vmcnt(0)" ::: "memory");
    }
    __builtin_amdgcn_sched_barrier(0);
    __builtin_amdgcn_s_barrier();
    __builtin_amdgcn_sched_barrier(0);
    if (t + 2 < ntk) {
      stage(t + 2, sbuf);
      sbuf = (sbuf == 2) ? 0 : sbuf + 1;
    }

    const unsigned short* Ab = (const unsigned short*)lds + cbuf * 12288;
    const unsigned short* Bb = Ab + 4096;
#pragma unroll
    for (int ks = 0; ks < 2; ++ks) {
      short8 bfr[4];
#pragma unroll
      for (int j = 0; j < 4; ++j) {
        int row = wn + j * 16 + r;
        bfr[j] = *(const short8*)&Bb[row * 64 + ((g + ks * 4) ^ (r & 7)) * 8];
      }
#pragma unroll
      for (int i = 0; i < 2; ++i) {
        int row = wm + i * 16 + r;
        short8 af = *(const short8*)&Ab[row * 64 + ((g + ks * 4) ^ (r & 7)) * 8];
#pragma unroll
        for (int j = 0; j < 4; ++j)
          acc[i][j] = __builtin_amdgcn_mfma_f32_16x16x32_bf16(af, bfr[j], acc[i][j], 0, 0, 0);
      }
    }
    cbuf = (cbuf == 2) ? 0 : cbuf + 1;
  }
  gemm_epilogue<EPI, 2, 4>(acc, Cout, bias, mods, gate_ofs, src, N, rowsPerB,
                           m0, n0, wm, wn, g, r);
}

// ---------------------------------------------------------------------------
// gemm_cross: fused cross-attention Q-proj + KV-proj in ONE launch (768 blk).
//   blocks [0,512):   q = nx(4096x1024) @ wqcT,  N=1024, ntn=8  -> qb (bf16)
//   blocks [512,768): kv = ctxb(1024x1024) @ wkcT(+wvcT adj), N=2048, ntn=16
//                     -> kb/vb split-store (EPI3 layout)
// ---------------------------------------------------------------------------
__global__ __launch_bounds__(256) void gemm_cross(
    const unsigned short* __restrict__ Anx, const unsigned short* __restrict__ Bq,
    unsigned short* __restrict__ Oq,
    const unsigned short* __restrict__ Actx, const unsigned short* __restrict__ Bkv,
    unsigned short* __restrict__ Okv) {
  __shared__ unsigned short lds[3 * 12288];
  const int tid = threadIdx.x;
  const int wave = tid >> 6, lane = tid & 63;
  const int g = lane >> 4, r = lane & 15;
  const bool iskv = blockIdx.x >= 512;
  const int flat = iskv ? (blockIdx.x - 512) : blockIdx.x;
  const int ntn = iskv ? 16 : 8;
  const unsigned short* A = iskv ? Actx : Anx;
  const unsigned short* Bt = iskv ? Bkv : Bq;
  const int nt = flat % ntn, mt = flat / ntn;
  const int m0 = mt * 64, n0 = nt * 128;
  const int K = 1024;
  const int wm = (wave >> 1) * 32, wn = (wave & 1) * 64;
  const int srow8 = lane >> 3;
  const int sck = (lane & 7) ^ srow8;

  f32x4 acc[2][4] = {};

  auto stage = [&](int t, int bufi) {
    const int k0 = t * 64;
    unsigned short* base = (unsigned short*)lds + bufi * 12288;
#pragma unroll
    for (int i = 0; i < 2; ++i) {
      int u = wave * 2 + i;
      int rl = u * 8 + srow8;
      const unsigned short* gsrc = A + (size_t)(m0 + rl) * K + k0 + sck * 8;
      __builtin_amdgcn_global_load_lds(GLB(gsrc), LDSP(base + u * 512), 16, 0, 0);
    }
#pragma unroll
    for (int i = 0; i < 4; ++i) {
      int u = wave * 4 + i;
      int rl = u * 8 + srow8;
      const unsigned short* gsrc = Bt + (size_t)(n0 + rl) * K + k0 + sck * 8;
      __builtin_amdgcn_global_load_lds(GLB(gsrc), LDSP(base + 4096 + u * 512), 16, 0, 0);
    }
  };

  const int ntk = K / 64;
  stage(0, 0);
  stage(1, 1);
  int cbuf = 0, sbuf = 2;

  for (int t = 0; t < ntk; ++t) {
    if (t < ntk - 1) {
      asm volatile("s_waitcnt vmcnt(6)" ::: "memory");
    } else {
      asm volatile("s_waitcnt vmcnt(0)" ::: "memory");
    }
    __builtin_amdgcn_sched_barrier(0);
    __builtin_amdgcn_s_barrier();
    __builtin_amdgcn_sched_barrier(0);
    if (t + 2 < ntk) {
      stage(t + 2, sbuf);
      sbuf = (sbuf == 2) ? 0 : sbuf + 1;
    }

    const unsigned short* Ab = (const unsigned short*)lds + cbuf * 12288;
    const unsigned short* Bb = Ab + 4096;
#pragma unroll
    for (int ks = 0; ks < 2; ++ks) {
      short8 bfr[4];
#pragma unroll
      for (int j = 0; j < 4; ++j) {
        int row = wn + j * 16 + r;
        bfr[j] = *(const short8*)&Bb[row * 64 + ((g + ks * 4) ^ (r & 7)) * 8];
      }
#pragma unroll
      for (int i = 0; i < 2; ++i) {
        int row = wm + i * 16 + r;
        short8 af = *(const short8*)&Ab[row * 64 + ((g + ks * 4) ^ (r & 7)) * 8];
#pragma unroll
        for (int j = 0; j < 4; ++j)
          acc[i][j] = __builtin_amdgcn_mfma_f32_16x16x32_bf16(af, bfr[j], acc[i][j], 0, 0, 0);
      }
    }
    cbuf = (cbuf == 2) ? 0 : cbuf + 1;
  }

#pragma unroll
  for (int i = 0; i < 2; ++i) {
#pragma unroll
    for (int j = 0; j < 4; ++j) {
#pragma unroll
      for (int q = 0; q < 4; ++q) {
        size_t grow = (size_t)(m0 + wm + i * 16 + g * 4 + q);
        size_t gcol = (size_t)(n0 + wn + j * 16 + r);
        float v = acc[i][j][q];
        if (iskv) {
          size_t buf = gcol >> 10;
          Okv[buf * (4096ull * 1024) + grow * 1024 + (gcol & 1023)] = f2b(v);
        } else {
          Oq[grow * 1024 + gcol] = f2b(v);
        }
      }
    }
  }
}

// ---------------------------------------------------------------------------
// Flash attention v9 (converged): 128 q/block, T15 pipeline, cvt_pk, max3,
// fused-scale, perm V-pack, setprio(PV).  Blind VALU edits exhausted — frozen.
// ---------------------------------------------------------------------------
__global__ __launch_bounds__(256, 2) void flash2(
    const unsigned short* __restrict__ Q, const unsigned short* __restrict__ Kv,
    const unsigned short* __restrict__ Vv, unsigned short* __restrict__ O,
    int Lk) {
  __shared__ unsigned short lds[20480];  // 40KB: K 3x8KB @0 | V^T 2x8KB @12288
  const int tid = threadIdx.x, wave = tid >> 6, lane = tid & 63;
  const int hi = lane >> 5, lq = lane & 31;
  const int flat = blockIdx.x;
  const int xcd = flat & 7, rr = flat >> 3;
  const int gl = rr >> 4, qt = rr & 15;
  const int g = xcd * 4 + gl;
  const int h = g & 15, b = g >> 4;
  const int Lq = 2048, D = 1024;

  const unsigned short* Qbase =
      Q + ((size_t)b * Lq + qt * 128 + wave * 32 + lq) * D + h * 64;
  const unsigned short* Kbase = Kv + (size_t)b * Lk * D + h * 64;
  const unsigned short* Vbase = Vv + (size_t)b * Lk * D + h * 64;

  short8 qf[4];
#pragma unroll
  for (int kb = 0; kb < 4; ++kb)
    qf[kb] = *(const short8*)(Qbase + kb * 16 + hi * 8);

  const short8 ones = {0x3F80, 0x3F80, 0x3F80, 0x3F80, 0x3F80, 0x3F80, 0x3F80, 0x3F80};
  const f32x16 z16 = {};  // persistent zero C-operand

  const int kr0 = tid >> 3, kc0 = tid & 7;   // K stage: row, chunk
  const int kvp = tid >> 3, db = tid & 7;    // V stage: kv-pair, d-block
  const int kch0 = (kc0 ^ (kr0 & 7) ^ (kr0 >> 3)) & 7;
  const int kch1 = kch0 ^ 4;
  const int f0 = (lq & 7) ^ (lq >> 3);
  const int swz0 = f0 << 4, swz1 = swz0 ^ 64;

  // kt-invariant V^T write byte-offsets (per-thread constants, reg-resident)
  int vby[8];
#pragma unroll
  for (int e = 0; e < 8; ++e) {
    int d = db * 8 + e;
    vby[e] = d * 128 + ((kvp * 4) ^ (((e ^ db) & 7) << 4));
  }

  float m_run = -3.0e38f;
  f32x16 o0 = {}, o1 = {}, lacc = {};
  short8 vr0, vr1;
  short8 pbf[4];

  auto stageK = [&](int t, int bi) {
    const unsigned short* s0 = Kbase + (size_t)(t * 64 + kr0) * D + kch0 * 8;
    const unsigned short* s1 = Kbase + (size_t)(t * 64 + kr0 + 32) * D + kch1 * 8;
    __builtin_amdgcn_global_load_lds(GLB(s0), LDSP(&lds[bi * 4096 + wave * 512]), 16, 0, 0);
    __builtin_amdgcn_global_load_lds(GLB(s1), LDSP(&lds[bi * 4096 + 2048 + wave * 512]), 16, 0, 0);
  };
  auto loadV = [&](int t) {
    const unsigned short* v0 = Vbase + (size_t)(t * 64 + 2 * kvp) * D + db * 8;
    vr0 = *(const short8*)v0;
    vr1 = *(const short8*)(v0 + D);
  };
  auto writeV = [&](int t) {
    char* vt = (char*)&lds[12288 + (t & 1) * 4096];
    union { short8 s; unsigned int u[4]; } a, c;
    a.s = vr0; c.s = vr1;
#pragma unroll
    for (int k = 0; k < 4; ++k) {
      *(unsigned int*)(vt + vby[2 * k]) =
          __builtin_amdgcn_perm(c.u[k], a.u[k], 0x05040100u);
      *(unsigned int*)(vt + vby[2 * k + 1]) =
          __builtin_amdgcn_perm(c.u[k], a.u[k], 0x07060302u);
    }
  };
  auto qk = [&](int bi, f32x16& sa0, f32x16& sa1) {
    const unsigned short* K0 = &lds[bi * 4096];
    {
      int lo = hi * 16;
      short8 a0 = *(const short8*)&K0[lq * 64 + ((lo ^ swz0) >> 1)];
      short8 a1 = *(const short8*)&K0[(32 + lq) * 64 + ((lo ^ swz1) >> 1)];
      sa0 = __builtin_amdgcn_mfma_f32_32x32x16_bf16(a0, qf[0], z16, 0, 0, 0);
      sa1 = __builtin_amdgcn_mfma_f32_32x32x16_bf16(a1, qf[0], z16, 0, 0, 0);
    }
#pragma unroll
    for (int ks = 1; ks < 4; ++ks) {
      int lo = ks * 32 + hi * 16;
      short8 a0 = *(const short8*)&K0[lq * 64 + ((lo ^ swz0) >> 1)];
      short8 a1 = *(const short8*)&K0[(32 + lq) * 64 + ((lo ^ swz1) >> 1)];
      sa0 = __builtin_amdgcn_mfma_f32_32x32x16_bf16(a0, qf[ks], sa0, 0, 0, 0);
      sa1 = __builtin_amdgcn_mfma_f32_32x32x16_bf16(a1, qf[ks], sa1, 0, 0, 0);
    }
  };
  auto finish = [&](f32x16& s0a, f32x16& s1a) {
    float tm[8];
#pragma unroll
    for (int i = 0; i < 8; ++i)
      tm[i] = fmaxf(max3f(s0a[i], s0a[i + 8], s1a[i]), s1a[i + 8]);
    float x = max3f(tm[0], tm[1], tm[2]);
    float y = max3f(tm[3], tm[4], tm[5]);
    float pm = fmaxf(max3f(tm[6], tm[7], x), y);
    {
      unsigned int ua = __builtin_bit_cast(unsigned int, pm), ub = ua;
      vpsw(ua, ub);
      pm = fmaxf(__builtin_bit_cast(float, ua), __builtin_bit_cast(float, ub));
    }
    if (__any(pm - m_run > 8.0f)) {
      float mnew = fmaxf(m_run, pm);
      float alpha = exp2f(m_run - mnew);
      lacc[0] *= alpha;
#pragma unroll
      for (int i = 0; i < 16; ++i) { o0[i] *= alpha; o1[i] *= alpha; }
      m_run = mnew;
    }
    float mc = m_run;
#pragma unroll
    for (int i = 0; i < 16; ++i) s0a[i] = exp2f(s0a[i] - mc);
#pragma unroll
    for (int i = 0; i < 16; ++i) s1a[i] = exp2f(s1a[i] - mc);
#pragma unroll
    for (int kb = 0; kb < 4; ++kb) {
      int bb = (kb & 1) * 8;
      float p0, p1, p2, p3, p4, p5, p6, p7;
      if (kb < 2) {
        p0 = s0a[bb + 0]; p1 = s0a[bb + 1]; p2 = s0a[bb + 2]; p3 = s0a[bb + 3];
        p4 = s0a[bb + 4]; p5 = s0a[bb + 5]; p6 = s0a[bb + 6]; p7 = s0a[bb + 7];
      } else {
        p0 = s1a[bb + 0]; p1 = s1a[bb + 1]; p2 = s1a[bb + 2]; p3 = s1a[bb + 3];
        p4 = s1a[bb + 4]; p5 = s1a[bb + 5]; p6 = s1a[bb + 6]; p7 = s1a[bb + 7];
      }
      unsigned int u0 = pk2(p0, p1), u1 = pk2(p2, p3);
      unsigned int u2 = pk2(p4, p5), u3 = pk2(p6, p7);
      vpsw(u0, u2);
      vpsw(u1, u3);
      union { unsigned int u[4]; short8 s; } fr;
      fr.u[0] = u0; fr.u[1] = u1; fr.u[2] = u2; fr.u[3] = u3;
      pbf[kb] = fr.s;
    }
  };
  auto pv = [&](int t) {
    const unsigned short* V0 = &lds[12288 + (t & 1) * 4096];
    __builtin_amdgcn_s_setprio(1);
#pragma unroll
    for (int kb = 0; kb < 4; ++kb) {
      int lo = kb * 32 + hi * 16;
      short8 vf0 = *(const short8*)&V0[lq * 64 + ((lo ^ swz0) >> 1)];
      short8 vf1 = *(const short8*)&V0[(32 + lq) * 64 + ((lo ^ swz1) >> 1)];
      o0 = __builtin_amdgcn_mfma_f32_32x32x16_bf16(vf0, pbf[kb], o0, 0, 0, 0);
      o1 = __builtin_amdgcn_mfma_f32_32x32x16_bf16(vf1, pbf[kb], o1, 0, 0, 0);
      lacc = __builtin_amdgcn_mfma_f32_32x32x16_bf16(ones, pbf[kb], lacc, 0, 0, 0);
    }
    __builtin_amdgcn_s_setprio(0);
  };

  const int nkt = Lk / 64;  // even for both Lk=2048 (32) and Lk=512 (8)

  // prologue: K(0)->buf0, V(0)->Vbuf0, K(1)->buf1, then S(0)
  stageK(0, 0);
  loadV(0);
  writeV(0);
  stageK(1, 1);
  __syncthreads();

  f32x16 sA0, sA1, sB0, sB1;
  qk(0, sA0, sA1);

  // pipelined step: QK(t+1)->snew (MFMA) overlaps finish(sold) (VALU); PV(t)
  auto pstep = [&](int t, f32x16& n0, f32x16& n1, f32x16& p0, f32x16& p1) {
    const int tq = t + 1;
    if (tq < nkt) {
      loadV(tq);
      if (tq + 1 < nkt) stageK(tq + 1, (tq + 1) % 3);
      qk(tq % 3, n0, n1);
    }
    finish(p0, p1);
    if (tq < nkt) writeV(tq);
    pv(t);
    __syncthreads();
  };

  for (int t = 0; t < nkt; t += 2) {
    pstep(t, sB0, sB1, sA0, sA1);
    pstep(t + 1, sA0, sA1, sB0, sB1);
  }

  // ---- epilogue: normalize, bounce through LDS, coalesced store ----
  float rl = 1.0f / lacc[0];
  unsigned short* os = &lds[wave * 2048];
#pragma unroll
  for (int t = 0; t < 2; ++t) {
#pragma unroll
    for (int c = 0; c < 4; ++c) {
      int dbase = 32 * t + 8 * c + 4 * hi;
      float v0 = (t ? o1[4 * c + 0] : o0[4 * c + 0]) * rl;
      float v1 = (t ? o1[4 * c + 1] : o0[4 * c + 1]) * rl;
      float v2 = (t ? o1[4 * c + 2] : o0[4 * c + 2]) * rl;
      float v3 = (t ? o1[4 * c + 3] : o0[4 * c + 3]) * rl;
      int by0 = lq * 128 + ((dbase * 2) ^ ((lq & 7) << 4));
      int by1 = lq * 128 + (((dbase + 2) * 2) ^ ((lq & 7) << 4));
      *(unsigned int*)((char*)os + by0) = pk2(v0, v1);
      *(unsigned int*)((char*)os + by1) = pk2(v2, v3);
    }
  }
  int q2 = lane >> 1;
  unsigned short* orow =
      O + ((size_t)b * Lq + qt * 128 + wave * 32 + q2) * D + h * 64;
#pragma unroll
  for (int j = 0; j < 4; ++j) {
    int j2 = (lane & 1) * 4 + j;
    int byr = q2 * 128 + ((j2 * 16) ^ ((q2 & 7) << 4));
    short8 vv = *(const short8*)((char*)os + byr);
    *(short8*)(orow + j2 * 8) = vv;
  }
}

// ---------------------------------------------------------------------------
// Host orchestration
// ---------------------------------------------------------------------------
extern "C" void kernel_launch(void* const* d_in, const int* in_sizes, int n_in,
                              void* d_out, int out_size, void* d_ws, size_t ws_size,
                              hipStream_t stream) {
  (void)in_sizes; (void)n_in; (void)out_size; (void)ws_size;
  const float* x_in = (const float*)d_in[0];
  const float* te   = (const float*)d_in[1];
  const float* ctx  = (const float*)d_in[2];
  const float* rope = (const float*)d_in[3];
  const float* wmod = (const float*)d_in[4];
  const float* bmod = (const float*)d_in[5];
  const float* wqs  = (const float*)d_in[6];
  const float* wks  = (const float*)d_in[7];
  const float* wvs  = (const float*)d_in[8];
  const float* wos  = (const float*)d_in[9];
  const float* bos  = (const float*)d_in[10];
  const float* wqc  = (const float*)d_in[11];
  const float* wkc  = (const float*)d_in[12];
  const float* wvc  = (const float*)d_in[13];
  const float* woc  = (const float*)d_in[14];
  const float* boc  = (const float*)d_in[15];
  const float* w1   = (const float*)d_in[16];
  const float* b1   = (const float*)d_in[17];
  const float* w2   = (const float*)d_in[18];
  const float* b2   = (const float*)d_in[19];
  float* out = (float*)d_out;

  char* w = (char*)d_ws;
  size_t o = 0;
  auto alloc = [&](size_t bytes) {
    char* p = w + o;
    o = (o + bytes + 255) & ~(size_t)255;
    return p;
  };
  // wqsT/wksT/wvsT adjacent (fused QKV); wkcT/wvcT adjacent (fused cross-KV).
  unsigned short* wqsT  = (unsigned short*)alloc(1024ull * 1024 * 2);
  unsigned short* wksT  = (unsigned short*)alloc(1024ull * 1024 * 2);
  unsigned short* wvsT  = (unsigned short*)alloc(1024ull * 1024 * 2);
  unsigned short* wosT  = (unsigned short*)alloc(1024ull * 1024 * 2);
  unsigned short* wqcT  = (unsigned short*)alloc(1024ull * 1024 * 2);
  unsigned short* wkcT  = (unsigned short*)alloc(1024ull * 1024 * 2);
  unsigned short* wvcT  = (unsigned short*)alloc(1024ull * 1024 * 2);
  unsigned short* wocT  = (unsigned short*)alloc(1024ull * 1024 * 2);
  unsigned short* w1T   = (unsigned short*)alloc(4096ull * 1024 * 2);
  unsigned short* w2T   = (unsigned short*)alloc(1024ull * 4096 * 2);
  float* modsb = (float*)alloc(2ull * 6144 * 4);
  float2* csT  = (float2*)alloc(2048ull * 64 * 8);
  unsigned short* nx   = (unsigned short*)alloc(4096ull * 1024 * 2);
  unsigned short* ctxb = (unsigned short*)alloc(1024ull * 1024 * 2);
  // qb/kb/vb adjacent: EPI3/EPI4 buffer stride = 4096*1024 elems.
  unsigned short* qb = (unsigned short*)alloc(4096ull * 1024 * 2);
  unsigned short* kb = (unsigned short*)alloc(4096ull * 1024 * 2);
  unsigned short* vb = (unsigned short*)alloc(4096ull * 1024 * 2);
  unsigned short* ao = (unsigned short*)alloc(4096ull * 1024 * 2);
  float* xw = (float*)alloc(4096ull * 1024 * 4);
  unsigned short* hbuf = qb;  // reuse qb..ao contiguous 32MB for MLP hidden

  const float c1 = 0.125f * 1.4426950408889634f;  // scale * log2(e), folded into wqs/wkc

  PrepArgs pa;
  pa.wmod = wmod; pa.te = te; pa.bmod = bmod; pa.mods = modsb;
  pa.sq[0] = {wqs, wqsT, c1};
  pa.sq[1] = {wks, wksT, 1.0f};
  pa.sq[2] = {wvs, wvsT, 1.0f};
  pa.sq[3] = {wos, wosT, 1.0f};
  pa.sq[4] = {wqc, wqcT, 1.0f};
  pa.sq[5] = {wkc, wkcT, c1};
  pa.sq[6] = {wvc, wvcT, 1.0f};
  pa.sq[7] = {woc, wocT, 1.0f};
  pa.w1 = w1; pa.w1T = w1T;
  pa.w2 = w2; pa.w2T = w2T;
  pa.ctx = ctx; pa.ctxb = ctxb;
  pa.rope = rope; pa.cs = csT;
  prep<<<18968, 256, 0, stream>>>(pa);

  // --- self-attention (RoPE fused into QKV epilogue) ---
  ln_mod<<<4096, 256, 0, stream>>>(x_in, modsb, nx, 1024, 0);
  gemm_pipe<4><<<768, 256, 0, stream>>>(nx, wqsT, qb, (const float*)csT, nullptr, -1, nullptr, 4096, 3072, 1024, 2048, 2);
  flash2<<<512, 256, 0, stream>>>(qb, kb, vb, ao, 2048);
  gemm_p2<2><<<512, 256, 0, stream>>>(ao, wosT, xw, bos, modsb, 2048, x_in, 4096, 1024, 1024, 2048, 8);

  // --- cross-attention (Q-proj + KV-proj fused in one launch) ---
  ln_mod<<<4096, 256, 0, stream>>>(xw, modsb, nx, -1, -1);
  gemm_cross<<<768, 256, 0, stream>>>(nx, wqcT, qb, ctxb, wkcT, kb);
  flash2<<<512, 256, 0, stream>>>(qb, kb, vb, ao, 512);
  gemm_p2<2><<<512, 256, 0, stream>>>(ao, wocT, xw, boc, modsb, -1, xw, 4096, 1024, 1024, 2048, 8);

  // --- MLP ---
  ln_mod<<<4096, 256, 0, stream>>>(xw, modsb, nx, 4096, 3072);
  gemm_bt<1><<<dim3(32, 32), 256, 0, stream>>>(nx, w1T, hbuf, b1, nullptr, -1, nullptr, 4096, 4096, 1024, 2048);
  gemm_p2<2><<<512, 256, 0, stream>>>(hbuf, w2T, out, b2, modsb, 5120, xw, 4096, 1024, 4096, 2048, 8);
}

// Round 10
// 387.677 us; speedup vs baseline: 1.0562x; 1.0015x over previous
//
#include <hip/hip_runtime.h>
#include <hip/hip_bf16.h>

// ---------------------------------------------------------------------------
// CleanDITBlock: adaLN-modulated DiT block (self-attn w/ RoPE, cross-attn, MLP)
// B=2, L=2048, S=512, D=1024, H=16, HD=64, CTX=1024, HID=4096
// ---------------------------------------------------------------------------

typedef short short8 __attribute__((ext_vector_type(8)));
typedef float f32x4 __attribute__((ext_vector_type(4)));
typedef float f32x16 __attribute__((ext_vector_type(16)));

#define DEV __device__ __forceinline__

DEV unsigned short f2b(float f) {
  __hip_bfloat16 h = __float2bfloat16(f);
  return *reinterpret_cast<unsigned short*>(&h);
}
DEV float b2f(unsigned short u) {
  unsigned int x = ((unsigned int)u) << 16;
  return __builtin_bit_cast(float, x);
}
// single-instruction packed f32->bf16 pair (T12): D[15:0]=bf16(lo), D[31:16]=bf16(hi)
DEV unsigned int pk2(float lo, float hi) {
  unsigned int r;
  asm("v_cvt_pk_bf16_f32 %0, %1, %2" : "=v"(r) : "v"(lo), "v"(hi));
  return r;
}
// lane[i]<->lane[i+32] half-swap (VALU, no LDS)
DEV void vpsw(unsigned int& a, unsigned int& b) {
  asm("v_permlane32_swap_b32 %0, %1" : "+v"(a), "+v"(b));
}
// 3-input max (T17)
DEV float max3f(float a, float b, float c) {
  float r;
  asm("v_max3_f32 %0, %1, %2, %3" : "=v"(r) : "v"(a), "v"(b), "v"(c));
  return r;
}

#define GLB(p) ((const __attribute__((address_space(1))) void*)(p))
#define LDSP(p) ((__attribute__((address_space(3))) void*)(p))

// ---------------------------------------------------------------------------
// prep: ALL preprocessing in one launch (flattened grid, range decode).
//   [0,24)            mods = te @ wmod + bmod, computed DIRECTLY from f32 wmod
//   [24,8216)         8 square 1024^2 transposes (wq/wk/wv/wo self+cross)
//   [8216,12312)      w1 transpose (1024x4096 -> 4096x1024)
//   [12312,16408)     w2 transpose (4096x1024 -> 1024x4096)
//   [16408,18456)     ctx f32->bf16 cast, 2 elems/thread (packed cvt)
//   [18456,18968)     rope (cos,sin) table (131072 elems)
// ---------------------------------------------------------------------------
struct TCB { const float* in; unsigned short* out; float scale; };
struct PrepArgs {
  const float* wmod; const float* te; const float* bmod; float* mods;
  TCB sq[8];
  const float* w1; unsigned short* w1T;
  const float* w2; unsigned short* w2T;
  const float* ctx; unsigned short* ctxb;
  const float* rope; float2* cs;
};

__global__ __launch_bounds__(256) void prep(PrepArgs a) {
  __shared__ float t32[32][33];
  __shared__ float tes[2048];
  const int blk = blockIdx.x;
  const int tid = threadIdx.x;
  const int tx = tid & 31, ty = tid >> 5;
  if (blk < 24) {
    // ---- mods: j-chunk of 256 columns, both batches ----
    const int j = blk * 256 + tid;
    for (int u = tid; u < 2048; u += 256) tes[u] = a.te[u];
    __syncthreads();
    float a0 = 0.f, b0 = 0.f, a1 = 0.f, b1 = 0.f;
#pragma unroll 8
    for (int k = 0; k < 1024; k += 2) {
      float v0 = a.wmod[(size_t)k * 6144 + j];
      float v1 = a.wmod[(size_t)(k + 1) * 6144 + j];
      a0 += tes[k] * v0;
      b0 += tes[k + 1] * v1;
      a1 += tes[1024 + k] * v0;
      b1 += tes[1024 + k + 1] * v1;
    }
    float bm = a.bmod[j];
    a.mods[j] = a0 + b0 + bm;
    a.mods[6144 + j] = a1 + b1 + bm;
  } else if (blk < 16408) {
    const float* in;
    unsigned short* out;
    int R, C, gx, tile;
    float scale;
    if (blk < 8216) {
      int j = (blk - 24) >> 10;
      tile = (blk - 24) & 1023;
      in = a.sq[j].in; out = a.sq[j].out; scale = a.sq[j].scale;
      R = 1024; C = 1024; gx = 32;
    } else if (blk < 12312) {
      tile = blk - 8216;
      in = a.w1; out = a.w1T; R = 1024; C = 4096; gx = 128; scale = 1.f;
    } else {
      tile = blk - 12312;
      in = a.w2; out = a.w2T; R = 4096; C = 1024; gx = 32; scale = 1.f;
    }
    int bx = (tile % gx) * 32, by = (tile / gx) * 32;
#pragma unroll
    for (int i = ty; i < 32; i += 8)
      t32[i][tx] = in[(size_t)(by + i) * C + bx + tx];
    __syncthreads();
#pragma unroll
    for (int i = ty; i < 32; i += 8)
      out[(size_t)(bx + i) * R + by + tx] = f2b(t32[tx][i] * scale);
  } else if (blk < 18456) {
    int i = (blk - 16408) * 512 + tid * 2;
    float2 v = *(const float2*)&a.ctx[i];
    *(unsigned int*)&a.ctxb[i] = pk2(v.x, v.y);
  } else {
    int i = (blk - 18456) * 256 + tid;
    float v = a.rope[i];
    a.cs[i] = make_float2(cosf(v), sinf(v));
  }
}

// ---------------------------------------------------------------------------
// ln_mod: LayerNorm (+ optional adaLN scale/shift) -> bf16.
// BF16IN=1 reads a bf16 input stream (residual stored as bf16).
// ---------------------------------------------------------------------------
template <int BF16IN>
__global__ __launch_bounds__(256) void ln_mod(
    const void* __restrict__ xin, const float* __restrict__ mods,
    unsigned short* __restrict__ out, int scale_ofs, int shift_ofs) {
  int row = blockIdx.x;
  int b = row >> 11;
  int tid = threadIdx.x;
  float vv[4];
  if constexpr (BF16IN) {
    const unsigned short* xr = (const unsigned short*)xin + (size_t)row * 1024;
    ushort4 u = ((const ushort4*)xr)[tid];
    vv[0] = b2f(u.x); vv[1] = b2f(u.y); vv[2] = b2f(u.z); vv[3] = b2f(u.w);
  } else {
    const float* xr = (const float*)xin + (size_t)row * 1024;
    float4 v = ((const float4*)xr)[tid];
    vv[0] = v.x; vv[1] = v.y; vv[2] = v.z; vv[3] = v.w;
  }
  float s = vv[0] + vv[1] + vv[2] + vv[3];
  float ss = vv[0] * vv[0] + vv[1] * vv[1] + vv[2] * vv[2] + vv[3] * vv[3];
#pragma unroll
  for (int off = 32; off >= 1; off >>= 1) {
    s += __shfl_down(s, off);
    ss += __shfl_down(ss, off);
  }
  __shared__ float red[8];
  int wave = tid >> 6, lane = tid & 63;
  if (lane == 0) { red[wave] = s; red[4 + wave] = ss; }
  __syncthreads();
  if (tid == 0) {
    float S = red[0] + red[1] + red[2] + red[3];
    float SS = red[4] + red[5] + red[6] + red[7];
    float mu = S * (1.f / 1024.f);
    red[0] = mu;
    red[1] = SS * (1.f / 1024.f) - mu * mu;
  }
  __syncthreads();
  float mu = red[0];
  float rs = rsqrtf(red[1] + 1e-6f);
  unsigned short o[4];
#pragma unroll
  for (int c = 0; c < 4; ++c) {
    int col = tid * 4 + c;
    float nv = (vv[c] - mu) * rs;
    if (scale_ofs >= 0)
      nv = nv * (1.f + mods[(size_t)b * 6144 + scale_ofs + col]) +
           mods[(size_t)b * 6144 + shift_ofs + col];
    o[c] = f2b(nv);
  }
  *(ushort4*)(&out[(size_t)row * 1024 + tid * 4]) = *(const ushort4*)o;
}

// ---------------------------------------------------------------------------
// Shared GEMM epilogue.  EPI: 0 bf16; 1 bias+GELU bf16; 2 f32 residual
// src(f32) + gate*(acc+bias); 3 bf16 split-store; 5 bf16 residual out
// (src f32); 7 f32 residual out (src bf16).
// ---------------------------------------------------------------------------
template <int EPI, int MI, int NJ>
DEV void gemm_epilogue(f32x4 (&acc)[MI][NJ], void* Cout, const float* bias,
                       const float* mods, int gate_ofs, const float* src,
                       int N, int rowsPerB, int m0, int n0, int wm, int wn,
                       int g, int r) {
#pragma unroll
  for (int i = 0; i < MI; ++i) {
#pragma unroll
    for (int j = 0; j < NJ; ++j) {
#pragma unroll
      for (int q = 0; q < 4; ++q) {
        size_t grow = (size_t)(m0 + wm + i * 16 + g * 4 + q);
        size_t gcol = (size_t)(n0 + wn + j * 16 + r);
        float v = acc[i][j][q];
        if constexpr (EPI == 0) {
          ((unsigned short*)Cout)[grow * N + gcol] = f2b(v);
        } else if constexpr (EPI == 1) {
          v += bias[gcol];
          float ge = 0.5f * v * (1.0f + erff(v * 0.70710678f));
          ((unsigned short*)Cout)[grow * N + gcol] = f2b(ge);
        } else if constexpr (EPI == 3) {
          size_t buf = gcol >> 10;
          ((unsigned short*)Cout)[buf * (4096ull * 1024) + grow * 1024 + (gcol & 1023)] = f2b(v);
        } else if constexpr (EPI == 5) {
          // bf16 residual out, f32 src
          v += bias[gcol];
          float gate = 1.0f;
          if (gate_ofs >= 0)
            gate = mods[(grow / rowsPerB) * 6144 + gate_ofs + gcol];
          ((unsigned short*)Cout)[grow * N + gcol] =
              f2b(src[grow * N + gcol] + gate * v);
        } else if constexpr (EPI == 7) {
          // f32 residual out, bf16 src
          v += bias[gcol];
          float gate = 1.0f;
          if (gate_ofs >= 0)
            gate = mods[(grow / rowsPerB) * 6144 + gate_ofs + gcol];
          float sv = b2f(((const unsigned short*)src)[grow * N + gcol]);
          ((float*)Cout)[grow * N + gcol] = sv + gate * v;
        } else {
          v += bias[gcol];
          float gate = 1.0f;
          if (gate_ofs >= 0)
            gate = mods[(grow / rowsPerB) * 6144 + gate_ofs + gcol];
          ((float*)Cout)[grow * N + gcol] = src[grow * N + gcol] + gate * v;
        }
      }
    }
  }
}

// ---------------------------------------------------------------------------
// QKV epilogue with fused RoPE (EPI 4).  j-tiles are head-aligned: d=j*16+r,
// rotation pair (d,d+32) = (acc[i][j], acc[i][j+2]) in the SAME lane.  Applies
// rope to buffers 0 (q) and 1 (k); buffer 2 (v) stored plain.  cs = interleaved
// (cos,sin)[l][d].
// ---------------------------------------------------------------------------
DEV void qkv_rope_epilogue(f32x4 (&acc)[4][4], unsigned short* Cout,
                           const float2* cs, int m0, int n0, int wm, int wn,
                           int g, int r) {
  const int buf = (n0 + wn) >> 10;      // wave-uniform
  const int colbase = (n0 + wn) & 1023;
  unsigned short* base = Cout + (size_t)buf * (4096ull * 1024);
#pragma unroll
  for (int i = 0; i < 4; ++i) {
#pragma unroll
    for (int q = 0; q < 4; ++q) {
      size_t grow = (size_t)(m0 + wm + i * 16 + g * 4 + q);
      unsigned short* orow = base + grow * 1024 + colbase + r;
      if (buf < 2) {
        int l = (int)(grow & 2047);
#pragma unroll
        for (int j = 0; j < 2; ++j) {
          int d = j * 16 + r;
          float2 a = cs[l * 64 + d];
          float2 bb = cs[l * 64 + d + 32];
          float x1 = acc[i][j][q], x2 = acc[i][j + 2][q];
          orow[j * 16] = f2b(x1 * a.x - x2 * a.y);
          orow[(j + 2) * 16] = f2b(x2 * bb.x + x1 * bb.y);
        }
      } else {
#pragma unroll
        for (int j = 0; j < 4; ++j) orow[j * 16] = f2b(acc[i][j][q]);
      }
    }
  }
}

// ---------------------------------------------------------------------------
// GEMM (m97): 128x128, BK=32, implicit overlap.  For >=4 blocks/CU (mlp1).
// ---------------------------------------------------------------------------
template <int EPI>
__global__ __launch_bounds__(256, 2) void gemm_bt(
    const unsigned short* __restrict__ A, const unsigned short* __restrict__ Bt,
    void* __restrict__ Cout, const float* __restrict__ bias,
    const float* __restrict__ mods, int gate_ofs, const float* __restrict__ src,
    int M, int N, int K, int rowsPerB) {
  __shared__ unsigned short As[128 * 32];
  __shared__ unsigned short Bs[128 * 32];
  const int tid = threadIdx.x;
  const int wave = tid >> 6, lane = tid & 63;
  const int g = lane >> 4, r = lane & 15;
  const int m0 = blockIdx.y * 128, n0 = blockIdx.x * 128;
  const int wm = (wave >> 1) * 64, wn = (wave & 1) * 64;
  const int srow = lane >> 2;
  const int scol = (lane & 3) * 8;

  f32x4 acc[4][4] = {};

  for (int k0 = 0; k0 < K; k0 += 32) {
    __syncthreads();
#pragma unroll
    for (int cc = 0; cc < 4; ++cc) {
      int c = wave * 4 + cc;
      int isB = c >> 3;
      int cl = c & 7;
      int row = cl * 16 + srow;
      const unsigned short* gsrc =
          isB ? (Bt + (size_t)(n0 + row) * K + k0 + scol)
              : (A + (size_t)(m0 + row) * K + k0 + scol);
      unsigned short* ldst = (isB ? Bs : As) + cl * 512;
      __builtin_amdgcn_global_load_lds(GLB(gsrc), LDSP(ldst), 16, 0, 0);
    }
    __syncthreads();

    short8 bfr[4];
#pragma unroll
    for (int j = 0; j < 4; ++j)
      bfr[j] = *(const short8*)(&Bs[(wn + j * 16 + r) * 32 + g * 8]);
#pragma unroll
    for (int i = 0; i < 4; ++i) {
      short8 af = *(const short8*)(&As[(wm + i * 16 + r) * 32 + g * 8]);
#pragma unroll
      for (int j = 0; j < 4; ++j)
        acc[i][j] = __builtin_amdgcn_mfma_f32_16x16x32_bf16(af, bfr[j], acc[i][j], 0, 0, 0);
    }
  }
  gemm_epilogue<EPI, 4, 4>(acc, Cout, bias, mods, gate_ofs, src, N, rowsPerB,
                           m0, n0, wm, wn, g, r);
}

// ---------------------------------------------------------------------------
// GEMM (pipelined 128x128): BK=64, 4 LDS bufs, depth-3, counted vmcnt.
// For the QKV GEMM (grid 768, 1 block/CU + 3-deep pipeline).
// EPI==4: fused-RoPE QKV epilogue (cs table passed via `bias`).
// NOTE (r8): do NOT use at grid 256 for the N=1024 GEMMs — 1 block/CU with
// no co-resident overlap loses ~23us vs gemm_p2's 512-block config.
// ---------------------------------------------------------------------------
template <int EPI>
__global__ __launch_bounds__(256) void gemm_pipe(
    const unsigned short* __restrict__ A, const unsigned short* __restrict__ Bt,
    void* __restrict__ Cout, const float* __restrict__ bias,
    const float* __restrict__ mods, int gate_ofs, const float* __restrict__ src,
    int M, int N, int K, int rowsPerB, int mshift) {
  __shared__ unsigned short lds[4 * 16384];
  const int tid = threadIdx.x;
  const int wave = tid >> 6, lane = tid & 63;
  const int g = lane >> 4, r = lane & 15;
  const int flat = blockIdx.x;
  const int xcd = flat & 7, idx = flat >> 3;
  const int mt = xcd * (1 << mshift) + (idx & ((1 << mshift) - 1));
  const int nt = idx >> mshift;
  const int m0 = mt * 128, n0 = nt * 128;
  const int wm = (wave >> 1) * 64, wn = (wave & 1) * 64;
  const int srow8 = lane >> 3;
  const int sck = (lane & 7) ^ srow8;

  f32x4 acc[4][4] = {};

  auto stage = [&](int t, int bufi) {
    const int k0 = t * 64;
#pragma unroll
    for (int i = 0; i < 8; ++i) {
      int u = wave * 8 + i;
      int isB = u >> 4;
      int uu = u & 15;
      int rl = uu * 8 + srow8;
      const unsigned short* gsrc =
          (isB ? (Bt + (size_t)(n0 + rl) * K) : (A + (size_t)(m0 + rl) * K)) +
          k0 + sck * 8;
      unsigned short* dst = (unsigned short*)lds + bufi * 16384 + isB * 8192 + uu * 512;
      __builtin_amdgcn_global_load_lds(GLB(gsrc), LDSP(dst), 16, 0, 0);
    }
  };

  const int nt_k = K / 64;
  stage(0, 0);
  stage(1, 1);
  stage(2, 2);

  for (int t = 0; t < nt_k; ++t) {
    int rem = nt_k - t;
    if (rem >= 3) {
      asm volatile("s_waitcnt vmcnt(16)" ::: "memory");
    } else if (rem == 2) {
      asm volatile("s_waitcnt vmcnt(8)" ::: "memory");
    } else {
      asm volatile("s_waitcnt vmcnt(0)" ::: "memory");
    }
    __builtin_amdgcn_sched_barrier(0);
    __builtin_amdgcn_s_barrier();
    __builtin_amdgcn_sched_barrier(0);
    if (t + 3 < nt_k) stage(t + 3, (t + 3) & 3);

    const unsigned short* Ab = (const unsigned short*)lds + (t & 3) * 16384;
    const unsigned short* Bb = Ab + 8192;
#pragma unroll
    for (int ks = 0; ks < 2; ++ks) {
      short8 bfr[4];
#pragma unroll
      for (int j = 0; j < 4; ++j) {
        int row = wn + j * 16 + r;
        bfr[j] = *(const short8*)&Bb[row * 64 + ((g + ks * 4) ^ (r & 7)) * 8];
      }
#pragma unroll
      for (int i = 0; i < 4; ++i) {
        int row = wm + i * 16 + r;
        short8 af = *(const short8*)&Ab[row * 64 + ((g + ks * 4) ^ (r & 7)) * 8];
#pragma unroll
        for (int j = 0; j < 4; ++j)
          acc[i][j] = __builtin_amdgcn_mfma_f32_16x16x32_bf16(af, bfr[j], acc[i][j], 0, 0, 0);
      }
    }
  }
  if constexpr (EPI == 4) {
    qkv_rope_epilogue(acc, (unsigned short*)Cout, (const float2*)bias,
                      m0, n0, wm, wn, g, r);
  } else {
    gemm_epilogue<EPI, 4, 4>(acc, Cout, bias, mods, gate_ofs, src, N, rowsPerB,
                             m0, n0, wm, wn, g, r);
  }
}

// ---------------------------------------------------------------------------
// GEMM (64x128 tile, 2-blocks/CU): 4 waves of 32x64, BK=64, 3 LDS bufs (72KB),
// depth-2 counted vmcnt(6).  Grid = (M/64)*(N/128); nt = flat % ntn puts one
// B-panel per XCD when ntn==8.  PROVEN best for the grid-512 N=1024 GEMMs
// (r8: 128^2 pipe at 1 block/CU is 23us slower across wo_s/wo_c/mlp2).
// ---------------------------------------------------------------------------
template <int EPI>
__global__ __launch_bounds__(256) void gemm_p2(
    const unsigned short* __restrict__ A, const unsigned short* __restrict__ Bt,
    void* __restrict__ Cout, const float* __restrict__ bias,
    const float* __restrict__ mods, int gate_ofs, const float* __restrict__ src,
    int M, int N, int K, int rowsPerB, int ntn) {
  __shared__ unsigned short lds[3 * 12288];  // per buf: A 64x64 (8KB) | B 128x64 (16KB)
  const int tid = threadIdx.x;
  const int wave = tid >> 6, lane = tid & 63;
  const int g = lane >> 4, r = lane & 15;
  const int flat = blockIdx.x;
  const int nt = flat % ntn, mt = flat / ntn;
  const int m0 = mt * 64, n0 = nt * 128;
  const int wm = (wave >> 1) * 32, wn = (wave & 1) * 64;
  const int srow8 = lane >> 3;
  const int sck = (lane & 7) ^ srow8;

  f32x4 acc[2][4] = {};

  auto stage = [&](int t, int bufi) {
    const int k0 = t * 64;
    unsigned short* base = (unsigned short*)lds + bufi * 12288;
#pragma unroll
    for (int i = 0; i < 2; ++i) {  // A units: 8 of 64 rows
      int u = wave * 2 + i;
      int rl = u * 8 + srow8;
      const unsigned short* gsrc = A + (size_t)(m0 + rl) * K + k0 + sck * 8;
      __builtin_amdgcn_global_load_lds(GLB(gsrc), LDSP(base + u * 512), 16, 0, 0);
    }
#pragma unroll
    for (int i = 0; i < 4; ++i) {  // B units: 16 of 128 rows
      int u = wave * 4 + i;
      int rl = u * 8 + srow8;
      const unsigned short* gsrc = Bt + (size_t)(n0 + rl) * K + k0 + sck * 8;
      __builtin_amdgcn_global_load_lds(GLB(gsrc), LDSP(base + 4096 + u * 512), 16, 0, 0);
    }
  };

  const int ntk = K / 64;
  stage(0, 0);
  stage(1, 1);
  int cbuf = 0, sbuf = 2;

  for (int t = 0; t < ntk; ++t) {
    if (t < ntk - 1) {
      asm volatile("s_waitcnt vmcnt(6)" ::: "memory");
    } else {
      asm volatile("s_waitcnt vmcnt(0)" ::: "memory");
    }
    __builtin_amdgcn_sched_barrier(0);
    __builtin_amdgcn_s_barrier();
    __builtin_amdgcn_sched_barrier(0);
    if (t + 2 < ntk) {
      stage(t + 2, sbuf);
      sbuf = (sbuf == 2) ? 0 : sbuf + 1;
    }

    const unsigned short* Ab = (const unsigned short*)lds + cbuf * 12288;
    const unsigned short* Bb = Ab + 4096;
#pragma unroll
    for (int ks = 0; ks < 2; ++ks) {
      short8 bfr[4];
#pragma unroll
      for (int j = 0; j < 4; ++j) {
        int row = wn + j * 16 + r;
        bfr[j] = *(const short8*)&Bb[row * 64 + ((g + ks * 4) ^ (r & 7)) * 8];
      }
#pragma unroll
      for (int i = 0; i < 2; ++i) {
        int row = wm + i * 16 + r;
        short8 af = *(const short8*)&Ab[row * 64 + ((g + ks * 4) ^ (r & 7)) * 8];
#pragma unroll
        for (int j = 0; j < 4; ++j)
          acc[i][j] = __builtin_amdgcn_mfma_f32_16x16x32_bf16(af, bfr[j], acc[i][j], 0, 0, 0);
      }
    }
    cbuf = (cbuf == 2) ? 0 : cbuf + 1;
  }
  gemm_epilogue<EPI, 2, 4>(acc, Cout, bias, mods, gate_ofs, src, N, rowsPerB,
                           m0, n0, wm, wn, g, r);
}

// ---------------------------------------------------------------------------
// gemm_cross: fused cross-attention Q-proj + KV-proj in ONE launch (768 blk).
//   blocks [0,512):   q = nx(4096x1024) @ wqcT,  N=1024, ntn=8  -> qb (bf16)
//   blocks [512,768): kv = ctxb(1024x1024) @ wkcT(+wvcT adj), N=2048, ntn=16
//                     -> kb/vb split-store (EPI3 layout)
// ---------------------------------------------------------------------------
__global__ __launch_bounds__(256) void gemm_cross(
    const unsigned short* __restrict__ Anx, const unsigned short* __restrict__ Bq,
    unsigned short* __restrict__ Oq,
    const unsigned short* __restrict__ Actx, const unsigned short* __restrict__ Bkv,
    unsigned short* __restrict__ Okv) {
  __shared__ unsigned short lds[3 * 12288];
  const int tid = threadIdx.x;
  const int wave = tid >> 6, lane = tid & 63;
  const int g = lane >> 4, r = lane & 15;
  const bool iskv = blockIdx.x >= 512;
  const int flat = iskv ? (blockIdx.x - 512) : blockIdx.x;
  const int ntn = iskv ? 16 : 8;
  const unsigned short* A = iskv ? Actx : Anx;
  const unsigned short* Bt = iskv ? Bkv : Bq;
  const int nt = flat % ntn, mt = flat / ntn;
  const int m0 = mt * 64, n0 = nt * 128;
  const int K = 1024;
  const int wm = (wave >> 1) * 32, wn = (wave & 1) * 64;
  const int srow8 = lane >> 3;
  const int sck = (lane & 7) ^ srow8;

  f32x4 acc[2][4] = {};

  auto stage = [&](int t, int bufi) {
    const int k0 = t * 64;
    unsigned short* base = (unsigned short*)lds + bufi * 12288;
#pragma unroll
    for (int i = 0; i < 2; ++i) {
      int u = wave * 2 + i;
      int rl = u * 8 + srow8;
      const unsigned short* gsrc = A + (size_t)(m0 + rl) * K + k0 + sck * 8;
      __builtin_amdgcn_global_load_lds(GLB(gsrc), LDSP(base + u * 512), 16, 0, 0);
    }
#pragma unroll
    for (int i = 0; i < 4; ++i) {
      int u = wave * 4 + i;
      int rl = u * 8 + srow8;
      const unsigned short* gsrc = Bt + (size_t)(n0 + rl) * K + k0 + sck * 8;
      __builtin_amdgcn_global_load_lds(GLB(gsrc), LDSP(base + 4096 + u * 512), 16, 0, 0);
    }
  };

  const int ntk = K / 64;
  stage(0, 0);
  stage(1, 1);
  int cbuf = 0, sbuf = 2;

  for (int t = 0; t < ntk; ++t) {
    if (t < ntk - 1) {
      asm volatile("s_waitcnt vmcnt(6)" ::: "memory");
    } else {
      asm volatile("s_waitcnt vmcnt(0)" ::: "memory");
    }
    __builtin_amdgcn_sched_barrier(0);
    __builtin_amdgcn_s_barrier();
    __builtin_amdgcn_sched_barrier(0);
    if (t + 2 < ntk) {
      stage(t + 2, sbuf);
      sbuf = (sbuf == 2) ? 0 : sbuf + 1;
    }

    const unsigned short* Ab = (const unsigned short*)lds + cbuf * 12288;
    const unsigned short* Bb = Ab + 4096;
#pragma unroll
    for (int ks = 0; ks < 2; ++ks) {
      short8 bfr[4];
#pragma unroll
      for (int j = 0; j < 4; ++j) {
        int row = wn + j * 16 + r;
        bfr[j] = *(const short8*)&Bb[row * 64 + ((g + ks * 4) ^ (r & 7)) * 8];
      }
#pragma unroll
      for (int i = 0; i < 2; ++i) {
        int row = wm + i * 16 + r;
        short8 af = *(const short8*)&Ab[row * 64 + ((g + ks * 4) ^ (r & 7)) * 8];
#pragma unroll
        for (int j = 0; j < 4; ++j)
          acc[i][j] = __builtin_amdgcn_mfma_f32_16x16x32_bf16(af, bfr[j], acc[i][j], 0, 0, 0);
      }
    }
    cbuf = (cbuf == 2) ? 0 : cbuf + 1;
  }

#pragma unroll
  for (int i = 0; i < 2; ++i) {
#pragma unroll
    for (int j = 0; j < 4; ++j) {
#pragma unroll
      for (int q = 0; q < 4; ++q) {
        size_t grow = (size_t)(m0 + wm + i * 16 + g * 4 + q);
        size_t gcol = (size_t)(n0 + wn + j * 16 + r);
        float v = acc[i][j][q];
        if (iskv) {
          size_t buf = gcol >> 10;
          Okv[buf * (4096ull * 1024) + grow * 1024 + (gcol & 1023)] = f2b(v);
        } else {
          Oq[grow * 1024 + gcol] = f2b(v);
        }
      }
    }
  }
}

// ---------------------------------------------------------------------------
// Flash attention v9 (converged): 128 q/block, T15 pipeline, cvt_pk, max3,
// fused-scale, perm V-pack, setprio(PV).  Blind VALU edits exhausted — frozen.
// ---------------------------------------------------------------------------
__global__ __launch_bounds__(256, 2) void flash2(
    const unsigned short* __restrict__ Q, const unsigned short* __restrict__ Kv,
    const unsigned short* __restrict__ Vv, unsigned short* __restrict__ O,
    int Lk) {
  __shared__ unsigned short lds[20480];  // 40KB: K 3x8KB @0 | V^T 2x8KB @12288
  const int tid = threadIdx.x, wave = tid >> 6, lane = tid & 63;
  const int hi = lane >> 5, lq = lane & 31;
  const int flat = blockIdx.x;
  const int xcd = flat & 7, rr = flat >> 3;
  const int gl = rr >> 4, qt = rr & 15;
  const int g = xcd * 4 + gl;
  const int h = g & 15, b = g >> 4;
  const int Lq = 2048, D = 1024;

  const unsigned short* Qbase =
      Q + ((size_t)b * Lq + qt * 128 + wave * 32 + lq) * D + h * 64;
  const unsigned short* Kbase = Kv + (size_t)b * Lk * D + h * 64;
  const unsigned short* Vbase = Vv + (size_t)b * Lk * D + h * 64;

  short8 qf[4];
#pragma unroll
  for (int kb = 0; kb < 4; ++kb)
    qf[kb] = *(const short8*)(Qbase + kb * 16 + hi * 8);

  const short8 ones = {0x3F80, 0x3F80, 0x3F80, 0x3F80, 0x3F80, 0x3F80, 0x3F80, 0x3F80};
  const f32x16 z16 = {};  // persistent zero C-operand

  const int kr0 = tid >> 3, kc0 = tid & 7;   // K stage: row, chunk
  const int kvp = tid >> 3, db = tid & 7;    // V stage: kv-pair, d-block
  const int kch0 = (kc0 ^ (kr0 & 7) ^ (kr0 >> 3)) & 7;
  const int kch1 = kch0 ^ 4;
  const int f0 = (lq & 7) ^ (lq >> 3);
  const int swz0 = f0 << 4, swz1 = swz0 ^ 64;

  // kt-invariant V^T write byte-offsets (per-thread constants, reg-resident)
  int vby[8];
#pragma unroll
  for (int e = 0; e < 8; ++e) {
    int d = db * 8 + e;
    vby[e] = d * 128 + ((kvp * 4) ^ (((e ^ db) & 7) << 4));
  }

  float m_run = -3.0e38f;
  f32x16 o0 = {}, o1 = {}, lacc = {};
  short8 vr0, vr1;
  short8 pbf[4];

  auto stageK = [&](int t, int bi) {
    const unsigned short* s0 = Kbase + (size_t)(t * 64 + kr0) * D + kch0 * 8;
    const unsigned short* s1 = Kbase + (size_t)(t * 64 + kr0 + 32) * D + kch1 * 8;
    __builtin_amdgcn_global_load_lds(GLB(s0), LDSP(&lds[bi * 4096 + wave * 512]), 16, 0, 0);
    __builtin_amdgcn_global_load_lds(GLB(s1), LDSP(&lds[bi * 4096 + 2048 + wave * 512]), 16, 0, 0);
  };
  auto loadV = [&](int t) {
    const unsigned short* v0 = Vbase + (size_t)(t * 64 + 2 * kvp) * D + db * 8;
    vr0 = *(const short8*)v0;
    vr1 = *(const short8*)(v0 + D);
  };
  auto writeV = [&](int t) {
    char* vt = (char*)&lds[12288 + (t & 1) * 4096];
    union { short8 s; unsigned int u[4]; } a, c;
    a.s = vr0; c.s = vr1;
#pragma unroll
    for (int k = 0; k < 4; ++k) {
      *(unsigned int*)(vt + vby[2 * k]) =
          __builtin_amdgcn_perm(c.u[k], a.u[k], 0x05040100u);
      *(unsigned int*)(vt + vby[2 * k + 1]) =
          __builtin_amdgcn_perm(c.u[k], a.u[k], 0x07060302u);
    }
  };
  auto qk = [&](int bi, f32x16& sa0, f32x16& sa1) {
    const unsigned short* K0 = &lds[bi * 4096];
    {
      int lo = hi * 16;
      short8 a0 = *(const short8*)&K0[lq * 64 + ((lo ^ swz0) >> 1)];
      short8 a1 = *(const short8*)&K0[(32 + lq) * 64 + ((lo ^ swz1) >> 1)];
      sa0 = __builtin_amdgcn_mfma_f32_32x32x16_bf16(a0, qf[0], z16, 0, 0, 0);
      sa1 = __builtin_amdgcn_mfma_f32_32x32x16_bf16(a1, qf[0], z16, 0, 0, 0);
    }
#pragma unroll
    for (int ks = 1; ks < 4; ++ks) {
      int lo = ks * 32 + hi * 16;
      short8 a0 = *(const short8*)&K0[lq * 64 + ((lo ^ swz0) >> 1)];
      short8 a1 = *(const short8*)&K0[(32 + lq) * 64 + ((lo ^ swz1) >> 1)];
      sa0 = __builtin_amdgcn_mfma_f32_32x32x16_bf16(a0, qf[ks], sa0, 0, 0, 0);
      sa1 = __builtin_amdgcn_mfma_f32_32x32x16_bf16(a1, qf[ks], sa1, 0, 0, 0);
    }
  };
  auto finish = [&](f32x16& s0a, f32x16& s1a) {
    float tm[8];
#pragma unroll
    for (int i = 0; i < 8; ++i)
      tm[i] = fmaxf(max3f(s0a[i], s0a[i + 8], s1a[i]), s1a[i + 8]);
    float x = max3f(tm[0], tm[1], tm[2]);
    float y = max3f(tm[3], tm[4], tm[5]);
    float pm = fmaxf(max3f(tm[6], tm[7], x), y);
    {
      unsigned int ua = __builtin_bit_cast(unsigned int, pm), ub = ua;
      vpsw(ua, ub);
      pm = fmaxf(__builtin_bit_cast(float, ua), __builtin_bit_cast(float, ub));
    }
    if (__any(pm - m_run > 8.0f)) {
      float mnew = fmaxf(m_run, pm);
      float alpha = exp2f(m_run - mnew);
      lacc[0] *= alpha;
#pragma unroll
      for (int i = 0; i < 16; ++i) { o0[i] *= alpha; o1[i] *= alpha; }
      m_run = mnew;
    }
    float mc = m_run;
#pragma unroll
    for (int i = 0; i < 16; ++i) s0a[i] = exp2f(s0a[i] - mc);
#pragma unroll
    for (int i = 0; i < 16; ++i) s1a[i] = exp2f(s1a[i] - mc);
#pragma unroll
    for (int kb = 0; kb < 4; ++kb) {
      int bb = (kb & 1) * 8;
      float p0, p1, p2, p3, p4, p5, p6, p7;
      if (kb < 2) {
        p0 = s0a[bb + 0]; p1 = s0a[bb + 1]; p2 = s0a[bb + 2]; p3 = s0a[bb + 3];
        p4 = s0a[bb + 4]; p5 = s0a[bb + 5]; p6 = s0a[bb + 6]; p7 = s0a[bb + 7];
      } else {
        p0 = s1a[bb + 0]; p1 = s1a[bb + 1]; p2 = s1a[bb + 2]; p3 = s1a[bb + 3];
        p4 = s1a[bb + 4]; p5 = s1a[bb + 5]; p6 = s1a[bb + 6]; p7 = s1a[bb + 7];
      }
      unsigned int u0 = pk2(p0, p1), u1 = pk2(p2, p3);
      unsigned int u2 = pk2(p4, p5), u3 = pk2(p6, p7);
      vpsw(u0, u2);
      vpsw(u1, u3);
      union { unsigned int u[4]; short8 s; } fr;
      fr.u[0] = u0; fr.u[1] = u1; fr.u[2] = u2; fr.u[3] = u3;
      pbf[kb] = fr.s;
    }
  };
  auto pv = [&](int t) {
    const unsigned short* V0 = &lds[12288 + (t & 1) * 4096];
    __builtin_amdgcn_s_setprio(1);
#pragma unroll
    for (int kb = 0; kb < 4; ++kb) {
      int lo = kb * 32 + hi * 16;
      short8 vf0 = *(const short8*)&V0[lq * 64 + ((lo ^ swz0) >> 1)];
      short8 vf1 = *(const short8*)&V0[(32 + lq) * 64 + ((lo ^ swz1) >> 1)];
      o0 = __builtin_amdgcn_mfma_f32_32x32x16_bf16(vf0, pbf[kb], o0, 0, 0, 0);
      o1 = __builtin_amdgcn_mfma_f32_32x32x16_bf16(vf1, pbf[kb], o1, 0, 0, 0);
      lacc = __builtin_amdgcn_mfma_f32_32x32x16_bf16(ones, pbf[kb], lacc, 0, 0, 0);
    }
    __builtin_amdgcn_s_setprio(0);
  };

  const int nkt = Lk / 64;  // even for both Lk=2048 (32) and Lk=512 (8)

  // prologue: K(0)->buf0, V(0)->Vbuf0, K(1)->buf1, then S(0)
  stageK(0, 0);
  loadV(0);
  writeV(0);
  stageK(1, 1);
  __syncthreads();

  f32x16 sA0, sA1, sB0, sB1;
  qk(0, sA0, sA1);

  // pipelined step: QK(t+1)->snew (MFMA) overlaps finish(sold) (VALU); PV(t)
  auto pstep = [&](int t, f32x16& n0, f32x16& n1, f32x16& p0, f32x16& p1) {
    const int tq = t + 1;
    if (tq < nkt) {
      loadV(tq);
      if (tq + 1 < nkt) stageK(tq + 1, (tq + 1) % 3);
      qk(tq % 3, n0, n1);
    }
    finish(p0, p1);
    if (tq < nkt) writeV(tq);
    pv(t);
    __syncthreads();
  };

  for (int t = 0; t < nkt; t += 2) {
    pstep(t, sB0, sB1, sA0, sA1);
    pstep(t + 1, sA0, sA1, sB0, sB1);
  }

  // ---- epilogue: normalize, bounce through LDS, coalesced store ----
  float rl = 1.0f / lacc[0];
  unsigned short* os = &lds[wave * 2048];
#pragma unroll
  for (int t = 0; t < 2; ++t) {
#pragma unroll
    for (int c = 0; c < 4; ++c) {
      int dbase = 32 * t + 8 * c + 4 * hi;
      float v0 = (t ? o1[4 * c + 0] : o0[4 * c + 0]) * rl;
      float v1 = (t ? o1[4 * c + 1] : o0[4 * c + 1]) * rl;
      float v2 = (t ? o1[4 * c + 2] : o0[4 * c + 2]) * rl;
      float v3 = (t ? o1[4 * c + 3] : o0[4 * c + 3]) * rl;
      int by0 = lq * 128 + ((dbase * 2) ^ ((lq & 7) << 4));
      int by1 = lq * 128 + (((dbase + 2) * 2) ^ ((lq & 7) << 4));
      *(unsigned int*)((char*)os + by0) = pk2(v0, v1);
      *(unsigned int*)((char*)os + by1) = pk2(v2, v3);
    }
  }
  int q2 = lane >> 1;
  unsigned short* orow =
      O + ((size_t)b * Lq + qt * 128 + wave * 32 + q2) * D + h * 64;
#pragma unroll
  for (int j = 0; j < 4; ++j) {
    int j2 = (lane & 1) * 4 + j;
    int byr = q2 * 128 + ((j2 * 16) ^ ((q2 & 7) << 4));
    short8 vv = *(const short8*)((char*)os + byr);
    *(short8*)(orow + j2 * 8) = vv;
  }
}

// ---------------------------------------------------------------------------
// Host orchestration
// ---------------------------------------------------------------------------
extern "C" void kernel_launch(void* const* d_in, const int* in_sizes, int n_in,
                              void* d_out, int out_size, void* d_ws, size_t ws_size,
                              hipStream_t stream) {
  (void)in_sizes; (void)n_in; (void)out_size; (void)ws_size;
  const float* x_in = (const float*)d_in[0];
  const float* te   = (const float*)d_in[1];
  const float* ctx  = (const float*)d_in[2];
  const float* rope = (const float*)d_in[3];
  const float* wmod = (const float*)d_in[4];
  const float* bmod = (const float*)d_in[5];
  const float* wqs  = (const float*)d_in[6];
  const float* wks  = (const float*)d_in[7];
  const float* wvs  = (const float*)d_in[8];
  const float* wos  = (const float*)d_in[9];
  const float* bos  = (const float*)d_in[10];
  const float* wqc  = (const float*)d_in[11];
  const float* wkc  = (const float*)d_in[12];
  const float* wvc  = (const float*)d_in[13];
  const float* woc  = (const float*)d_in[14];
  const float* boc  = (const float*)d_in[15];
  const float* w1   = (const float*)d_in[16];
  const float* b1   = (const float*)d_in[17];
  const float* w2   = (const float*)d_in[18];
  const float* b2   = (const float*)d_in[19];
  float* out = (float*)d_out;

  char* w = (char*)d_ws;
  size_t o = 0;
  auto alloc = [&](size_t bytes) {
    char* p = w + o;
    o = (o + bytes + 255) & ~(size_t)255;
    return p;
  };
  // wqsT/wksT/wvsT adjacent (fused QKV); wkcT/wvcT adjacent (fused cross-KV).
  unsigned short* wqsT  = (unsigned short*)alloc(1024ull * 1024 * 2);
  unsigned short* wksT  = (unsigned short*)alloc(1024ull * 1024 * 2);
  unsigned short* wvsT  = (unsigned short*)alloc(1024ull * 1024 * 2);
  unsigned short* wosT  = (unsigned short*)alloc(1024ull * 1024 * 2);
  unsigned short* wqcT  = (unsigned short*)alloc(1024ull * 1024 * 2);
  unsigned short* wkcT  = (unsigned short*)alloc(1024ull * 1024 * 2);
  unsigned short* wvcT  = (unsigned short*)alloc(1024ull * 1024 * 2);
  unsigned short* wocT  = (unsigned short*)alloc(1024ull * 1024 * 2);
  unsigned short* w1T   = (unsigned short*)alloc(4096ull * 1024 * 2);
  unsigned short* w2T   = (unsigned short*)alloc(1024ull * 4096 * 2);
  float* modsb = (float*)alloc(2ull * 6144 * 4);
  float2* csT  = (float2*)alloc(2048ull * 64 * 8);
  unsigned short* nx   = (unsigned short*)alloc(4096ull * 1024 * 2);
  unsigned short* ctxb = (unsigned short*)alloc(1024ull * 1024 * 2);
  // qb/kb/vb adjacent: EPI3/EPI4 buffer stride = 4096*1024 elems.
  unsigned short* qb = (unsigned short*)alloc(4096ull * 1024 * 2);
  unsigned short* kb = (unsigned short*)alloc(4096ull * 1024 * 2);
  unsigned short* vb = (unsigned short*)alloc(4096ull * 1024 * 2);
  unsigned short* ao = (unsigned short*)alloc(4096ull * 1024 * 2);
  unsigned short* xwb = (unsigned short*)alloc(4096ull * 1024 * 2);  // residual after self-attn (bf16)
  float* xw = (float*)alloc(4096ull * 1024 * 4);                     // residual after cross-attn (f32)
  unsigned short* hbuf = qb;  // reuse qb..ao contiguous 32MB for MLP hidden

  const float c1 = 0.125f * 1.4426950408889634f;  // scale * log2(e), folded into wqs/wkc

  PrepArgs pa;
  pa.wmod = wmod; pa.te = te; pa.bmod = bmod; pa.mods = modsb;
  pa.sq[0] = {wqs, wqsT, c1};
  pa.sq[1] = {wks, wksT, 1.0f};
  pa.sq[2] = {wvs, wvsT, 1.0f};
  pa.sq[3] = {wos, wosT, 1.0f};
  pa.sq[4] = {wqc, wqcT, 1.0f};
  pa.sq[5] = {wkc, wkcT, c1};
  pa.sq[6] = {wvc, wvcT, 1.0f};
  pa.sq[7] = {woc, wocT, 1.0f};
  pa.w1 = w1; pa.w1T = w1T;
  pa.w2 = w2; pa.w2T = w2T;
  pa.ctx = ctx; pa.ctxb = ctxb;
  pa.rope = rope; pa.cs = csT;
  prep<<<18968, 256, 0, stream>>>(pa);

  // --- self-attention (RoPE fused into QKV epilogue) ---
  ln_mod<0><<<4096, 256, 0, stream>>>(x_in, modsb, nx, 1024, 0);
  gemm_pipe<4><<<768, 256, 0, stream>>>(nx, wqsT, qb, (const float*)csT, nullptr, -1, nullptr, 4096, 3072, 1024, 2048, 2);
  flash2<<<512, 256, 0, stream>>>(qb, kb, vb, ao, 2048);
  // xw1 = x + gate_msa*sa, stored bf16 (EPI5: bf16 out, f32 src)
  gemm_p2<5><<<512, 256, 0, stream>>>(ao, wosT, xwb, bos, modsb, 2048, x_in, 4096, 1024, 1024, 2048, 8);

  // --- cross-attention (Q-proj + KV-proj fused in one launch) ---
  ln_mod<1><<<4096, 256, 0, stream>>>(xwb, modsb, nx, -1, -1);
  gemm_cross<<<768, 256, 0, stream>>>(nx, wqcT, qb, ctxb, wkcT, kb);
  flash2<<<512, 256, 0, stream>>>(qb, kb, vb, ao, 512);
  // xw2 = xw1 + ca, f32 out from bf16 src (EPI7)
  gemm_p2<7><<<512, 256, 0, stream>>>(ao, wocT, xw, boc, modsb, -1, (const float*)xwb, 4096, 1024, 1024, 2048, 8);

  // --- MLP ---
  ln_mod<0><<<4096, 256, 0, stream>>>(xw, modsb, nx, 4096, 3072);
  gemm_bt<1><<<dim3(32, 32), 256, 0, stream>>>(nx, w1T, hbuf, b1, nullptr, -1, nullptr, 4096, 4096, 1024, 2048);
  gemm_p2<2><<<512, 256, 0, stream>>>(hbuf, w2T, out, b2, modsb, 5120, xw, 4096, 1024, 4096, 2048, 8);
}

// Round 11
// 387.579 us; speedup vs baseline: 1.0565x; 1.0003x over previous
//
#include <hip/hip_runtime.h>
#include <hip/hip_bf16.h>

// ---------------------------------------------------------------------------
// CleanDITBlock: adaLN-modulated DiT block (self-attn w/ RoPE, cross-attn, MLP)
// B=2, L=2048, S=512, D=1024, H=16, HD=64, CTX=1024, HID=4096
// ---------------------------------------------------------------------------

typedef short short8 __attribute__((ext_vector_type(8)));
typedef float f32x4 __attribute__((ext_vector_type(4)));
typedef float f32x16 __attribute__((ext_vector_type(16)));

#define DEV __device__ __forceinline__

DEV unsigned short f2b(float f) {
  __hip_bfloat16 h = __float2bfloat16(f);
  return *reinterpret_cast<unsigned short*>(&h);
}
DEV float b2f(unsigned short u) {
  unsigned int x = ((unsigned int)u) << 16;
  return __builtin_bit_cast(float, x);
}
// single-instruction packed f32->bf16 pair (T12): D[15:0]=bf16(lo), D[31:16]=bf16(hi)
DEV unsigned int pk2(float lo, float hi) {
  unsigned int r;
  asm("v_cvt_pk_bf16_f32 %0, %1, %2" : "=v"(r) : "v"(lo), "v"(hi));
  return r;
}
// lane[i]<->lane[i+32] half-swap (VALU, no LDS)
DEV void vpsw(unsigned int& a, unsigned int& b) {
  asm("v_permlane32_swap_b32 %0, %1" : "+v"(a), "+v"(b));
}
// 3-input max (T17)
DEV float max3f(float a, float b, float c) {
  float r;
  asm("v_max3_f32 %0, %1, %2, %3" : "=v"(r) : "v"(a), "v"(b), "v"(c));
  return r;
}

#define GLB(p) ((const __attribute__((address_space(1))) void*)(p))
#define LDSP(p) ((__attribute__((address_space(3))) void*)(p))

// ---------------------------------------------------------------------------
// prep: ALL preprocessing in one launch (flattened grid, range decode).
//   [0,24)            mods = te @ wmod + bmod, computed DIRECTLY from f32 wmod
//   [24,8216)         8 square 1024^2 transposes (wq/wk/wv/wo self+cross)
//   [8216,12312)      w1 transpose (1024x4096 -> 4096x1024)
//   [12312,16408)     w2 transpose (4096x1024 -> 1024x4096)
//   [16408,18456)     ctx f32->bf16 cast, 2 elems/thread (packed cvt)
//   [18456,18968)     rope (cos,sin) table (131072 elems)
// ---------------------------------------------------------------------------
struct TCB { const float* in; unsigned short* out; float scale; };
struct PrepArgs {
  const float* wmod; const float* te; const float* bmod; float* mods;
  TCB sq[8];
  const float* w1; unsigned short* w1T;
  const float* w2; unsigned short* w2T;
  const float* ctx; unsigned short* ctxb;
  const float* rope; float2* cs;
};

__global__ __launch_bounds__(256) void prep(PrepArgs a) {
  __shared__ float t32[32][33];
  __shared__ float tes[2048];
  const int blk = blockIdx.x;
  const int tid = threadIdx.x;
  const int tx = tid & 31, ty = tid >> 5;
  if (blk < 24) {
    // ---- mods: j-chunk of 256 columns, both batches ----
    const int j = blk * 256 + tid;
    for (int u = tid; u < 2048; u += 256) tes[u] = a.te[u];
    __syncthreads();
    float a0 = 0.f, b0 = 0.f, a1 = 0.f, b1 = 0.f;
#pragma unroll 8
    for (int k = 0; k < 1024; k += 2) {
      float v0 = a.wmod[(size_t)k * 6144 + j];
      float v1 = a.wmod[(size_t)(k + 1) * 6144 + j];
      a0 += tes[k] * v0;
      b0 += tes[k + 1] * v1;
      a1 += tes[1024 + k] * v0;
      b1 += tes[1024 + k + 1] * v1;
    }
    float bm = a.bmod[j];
    a.mods[j] = a0 + b0 + bm;
    a.mods[6144 + j] = a1 + b1 + bm;
  } else if (blk < 16408) {
    const float* in;
    unsigned short* out;
    int R, C, gx, tile;
    float scale;
    if (blk < 8216) {
      int j = (blk - 24) >> 10;
      tile = (blk - 24) & 1023;
      in = a.sq[j].in; out = a.sq[j].out; scale = a.sq[j].scale;
      R = 1024; C = 1024; gx = 32;
    } else if (blk < 12312) {
      tile = blk - 8216;
      in = a.w1; out = a.w1T; R = 1024; C = 4096; gx = 128; scale = 1.f;
    } else {
      tile = blk - 12312;
      in = a.w2; out = a.w2T; R = 4096; C = 1024; gx = 32; scale = 1.f;
    }
    int bx = (tile % gx) * 32, by = (tile / gx) * 32;
#pragma unroll
    for (int i = ty; i < 32; i += 8)
      t32[i][tx] = in[(size_t)(by + i) * C + bx + tx];
    __syncthreads();
#pragma unroll
    for (int i = ty; i < 32; i += 8)
      out[(size_t)(bx + i) * R + by + tx] = f2b(t32[tx][i] * scale);
  } else if (blk < 18456) {
    int i = (blk - 16408) * 512 + tid * 2;
    float2 v = *(const float2*)&a.ctx[i];
    *(unsigned int*)&a.ctxb[i] = pk2(v.x, v.y);
  } else {
    int i = (blk - 18456) * 256 + tid;
    float v = a.rope[i];
    a.cs[i] = make_float2(cosf(v), sinf(v));
  }
}

// ---------------------------------------------------------------------------
// ln_mod: LayerNorm (+ optional adaLN scale/shift) -> bf16.
// BF16IN=1 reads a bf16 input stream (residual stored as bf16).
// ---------------------------------------------------------------------------
template <int BF16IN>
__global__ __launch_bounds__(256) void ln_mod(
    const void* __restrict__ xin, const float* __restrict__ mods,
    unsigned short* __restrict__ out, int scale_ofs, int shift_ofs) {
  int row = blockIdx.x;
  int b = row >> 11;
  int tid = threadIdx.x;
  float vv[4];
  if constexpr (BF16IN) {
    const unsigned short* xr = (const unsigned short*)xin + (size_t)row * 1024;
    ushort4 u = ((const ushort4*)xr)[tid];
    vv[0] = b2f(u.x); vv[1] = b2f(u.y); vv[2] = b2f(u.z); vv[3] = b2f(u.w);
  } else {
    const float* xr = (const float*)xin + (size_t)row * 1024;
    float4 v = ((const float4*)xr)[tid];
    vv[0] = v.x; vv[1] = v.y; vv[2] = v.z; vv[3] = v.w;
  }
  float s = vv[0] + vv[1] + vv[2] + vv[3];
  float ss = vv[0] * vv[0] + vv[1] * vv[1] + vv[2] * vv[2] + vv[3] * vv[3];
#pragma unroll
  for (int off = 32; off >= 1; off >>= 1) {
    s += __shfl_down(s, off);
    ss += __shfl_down(ss, off);
  }
  __shared__ float red[8];
  int wave = tid >> 6, lane = tid & 63;
  if (lane == 0) { red[wave] = s; red[4 + wave] = ss; }
  __syncthreads();
  if (tid == 0) {
    float S = red[0] + red[1] + red[2] + red[3];
    float SS = red[4] + red[5] + red[6] + red[7];
    float mu = S * (1.f / 1024.f);
    red[0] = mu;
    red[1] = SS * (1.f / 1024.f) - mu * mu;
  }
  __syncthreads();
  float mu = red[0];
  float rs = rsqrtf(red[1] + 1e-6f);
  unsigned short o[4];
#pragma unroll
  for (int c = 0; c < 4; ++c) {
    int col = tid * 4 + c;
    float nv = (vv[c] - mu) * rs;
    if (scale_ofs >= 0)
      nv = nv * (1.f + mods[(size_t)b * 6144 + scale_ofs + col]) +
           mods[(size_t)b * 6144 + shift_ofs + col];
    o[c] = f2b(nv);
  }
  *(ushort4*)(&out[(size_t)row * 1024 + tid * 4]) = *(const ushort4*)o;
}

// ---------------------------------------------------------------------------
// Shared GEMM epilogue.  EPI: 0 bf16; 1 bias+GELU bf16; 2 f32 residual
// src(f32) + gate*(acc+bias); 3 bf16 split-store; 5 bf16 residual out
// (src f32); 7 f32 residual out (src bf16).
// ---------------------------------------------------------------------------
template <int EPI, int MI, int NJ>
DEV void gemm_epilogue(f32x4 (&acc)[MI][NJ], void* Cout, const float* bias,
                       const float* mods, int gate_ofs, const float* src,
                       int N, int rowsPerB, int m0, int n0, int wm, int wn,
                       int g, int r) {
#pragma unroll
  for (int i = 0; i < MI; ++i) {
#pragma unroll
    for (int j = 0; j < NJ; ++j) {
#pragma unroll
      for (int q = 0; q < 4; ++q) {
        size_t grow = (size_t)(m0 + wm + i * 16 + g * 4 + q);
        size_t gcol = (size_t)(n0 + wn + j * 16 + r);
        float v = acc[i][j][q];
        if constexpr (EPI == 0) {
          ((unsigned short*)Cout)[grow * N + gcol] = f2b(v);
        } else if constexpr (EPI == 1) {
          v += bias[gcol];
          float ge = 0.5f * v * (1.0f + erff(v * 0.70710678f));
          ((unsigned short*)Cout)[grow * N + gcol] = f2b(ge);
        } else if constexpr (EPI == 3) {
          size_t buf = gcol >> 10;
          ((unsigned short*)Cout)[buf * (4096ull * 1024) + grow * 1024 + (gcol & 1023)] = f2b(v);
        } else if constexpr (EPI == 5) {
          // bf16 residual out, f32 src
          v += bias[gcol];
          float gate = 1.0f;
          if (gate_ofs >= 0)
            gate = mods[(grow / rowsPerB) * 6144 + gate_ofs + gcol];
          ((unsigned short*)Cout)[grow * N + gcol] =
              f2b(src[grow * N + gcol] + gate * v);
        } else if constexpr (EPI == 7) {
          // f32 residual out, bf16 src
          v += bias[gcol];
          float gate = 1.0f;
          if (gate_ofs >= 0)
            gate = mods[(grow / rowsPerB) * 6144 + gate_ofs + gcol];
          float sv = b2f(((const unsigned short*)src)[grow * N + gcol]);
          ((float*)Cout)[grow * N + gcol] = sv + gate * v;
        } else {
          v += bias[gcol];
          float gate = 1.0f;
          if (gate_ofs >= 0)
            gate = mods[(grow / rowsPerB) * 6144 + gate_ofs + gcol];
          ((float*)Cout)[grow * N + gcol] = src[grow * N + gcol] + gate * v;
        }
      }
    }
  }
}

// ---------------------------------------------------------------------------
// QKV epilogue with fused RoPE (EPI 4).  j-tiles are head-aligned: d=j*16+r,
// rotation pair (d,d+32) = (acc[i][j], acc[i][j+2]) in the SAME lane.  Applies
// rope to buffers 0 (q) and 1 (k); buffer 2 (v) stored plain.  cs = interleaved
// (cos,sin)[l][d].
// ---------------------------------------------------------------------------
DEV void qkv_rope_epilogue(f32x4 (&acc)[4][4], unsigned short* Cout,
                           const float2* cs, int m0, int n0, int wm, int wn,
                           int g, int r) {
  const int buf = (n0 + wn) >> 10;      // wave-uniform
  const int colbase = (n0 + wn) & 1023;
  unsigned short* base = Cout + (size_t)buf * (4096ull * 1024);
#pragma unroll
  for (int i = 0; i < 4; ++i) {
#pragma unroll
    for (int q = 0; q < 4; ++q) {
      size_t grow = (size_t)(m0 + wm + i * 16 + g * 4 + q);
      unsigned short* orow = base + grow * 1024 + colbase + r;
      if (buf < 2) {
        int l = (int)(grow & 2047);
#pragma unroll
        for (int j = 0; j < 2; ++j) {
          int d = j * 16 + r;
          float2 a = cs[l * 64 + d];
          float2 bb = cs[l * 64 + d + 32];
          float x1 = acc[i][j][q], x2 = acc[i][j + 2][q];
          orow[j * 16] = f2b(x1 * a.x - x2 * a.y);
          orow[(j + 2) * 16] = f2b(x2 * bb.x + x1 * bb.y);
        }
      } else {
#pragma unroll
        for (int j = 0; j < 4; ++j) orow[j * 16] = f2b(acc[i][j][q]);
      }
    }
  }
}

// ---------------------------------------------------------------------------
// GEMM (m97): 128x128, BK=32, implicit overlap.  For >=4 blocks/CU (mlp1).
// ---------------------------------------------------------------------------
template <int EPI>
__global__ __launch_bounds__(256, 2) void gemm_bt(
    const unsigned short* __restrict__ A, const unsigned short* __restrict__ Bt,
    void* __restrict__ Cout, const float* __restrict__ bias,
    const float* __restrict__ mods, int gate_ofs, const float* __restrict__ src,
    int M, int N, int K, int rowsPerB) {
  __shared__ unsigned short As[128 * 32];
  __shared__ unsigned short Bs[128 * 32];
  const int tid = threadIdx.x;
  const int wave = tid >> 6, lane = tid & 63;
  const int g = lane >> 4, r = lane & 15;
  const int m0 = blockIdx.y * 128, n0 = blockIdx.x * 128;
  const int wm = (wave >> 1) * 64, wn = (wave & 1) * 64;
  const int srow = lane >> 2;
  const int scol = (lane & 3) * 8;

  f32x4 acc[4][4] = {};

  for (int k0 = 0; k0 < K; k0 += 32) {
    __syncthreads();
#pragma unroll
    for (int cc = 0; cc < 4; ++cc) {
      int c = wave * 4 + cc;
      int isB = c >> 3;
      int cl = c & 7;
      int row = cl * 16 + srow;
      const unsigned short* gsrc =
          isB ? (Bt + (size_t)(n0 + row) * K + k0 + scol)
              : (A + (size_t)(m0 + row) * K + k0 + scol);
      unsigned short* ldst = (isB ? Bs : As) + cl * 512;
      __builtin_amdgcn_global_load_lds(GLB(gsrc), LDSP(ldst), 16, 0, 0);
    }
    __syncthreads();

    short8 bfr[4];
#pragma unroll
    for (int j = 0; j < 4; ++j)
      bfr[j] = *(const short8*)(&Bs[(wn + j * 16 + r) * 32 + g * 8]);
#pragma unroll
    for (int i = 0; i < 4; ++i) {
      short8 af = *(const short8*)(&As[(wm + i * 16 + r) * 32 + g * 8]);
#pragma unroll
      for (int j = 0; j < 4; ++j)
        acc[i][j] = __builtin_amdgcn_mfma_f32_16x16x32_bf16(af, bfr[j], acc[i][j], 0, 0, 0);
    }
  }
  gemm_epilogue<EPI, 4, 4>(acc, Cout, bias, mods, gate_ofs, src, N, rowsPerB,
                           m0, n0, wm, wn, g, r);
}

// ---------------------------------------------------------------------------
// GEMM (pipelined 128x128): BK=64, 4 LDS bufs, depth-3, counted vmcnt.
// For the QKV GEMM (grid 768, 1 block/CU + 3-deep pipeline).
// EPI==4: fused-RoPE QKV epilogue (cs table passed via `bias`).
// NOTE (r8): do NOT use at grid 256 for the N=1024 GEMMs — 1 block/CU with
// no co-resident overlap loses ~23us vs gemm_p2's 512-block config.
// ---------------------------------------------------------------------------
template <int EPI>
__global__ __launch_bounds__(256) void gemm_pipe(
    const unsigned short* __restrict__ A, const unsigned short* __restrict__ Bt,
    void* __restrict__ Cout, const float* __restrict__ bias,
    const float* __restrict__ mods, int gate_ofs, const float* __restrict__ src,
    int M, int N, int K, int rowsPerB, int mshift) {
  __shared__ unsigned short lds[4 * 16384];
  const int tid = threadIdx.x;
  const int wave = tid >> 6, lane = tid & 63;
  const int g = lane >> 4, r = lane & 15;
  const int flat = blockIdx.x;
  const int xcd = flat & 7, idx = flat >> 3;
  const int mt = xcd * (1 << mshift) + (idx & ((1 << mshift) - 1));
  const int nt = idx >> mshift;
  const int m0 = mt * 128, n0 = nt * 128;
  const int wm = (wave >> 1) * 64, wn = (wave & 1) * 64;
  const int srow8 = lane >> 3;
  const int sck = (lane & 7) ^ srow8;

  f32x4 acc[4][4] = {};

  auto stage = [&](int t, int bufi) {
    const int k0 = t * 64;
#pragma unroll
    for (int i = 0; i < 8; ++i) {
      int u = wave * 8 + i;
      int isB = u >> 4;
      int uu = u & 15;
      int rl = uu * 8 + srow8;
      const unsigned short* gsrc =
          (isB ? (Bt + (size_t)(n0 + rl) * K) : (A + (size_t)(m0 + rl) * K)) +
          k0 + sck * 8;
      unsigned short* dst = (unsigned short*)lds + bufi * 16384 + isB * 8192 + uu * 512;
      __builtin_amdgcn_global_load_lds(GLB(gsrc), LDSP(dst), 16, 0, 0);
    }
  };

  const int nt_k = K / 64;
  stage(0, 0);
  stage(1, 1);
  stage(2, 2);

  for (int t = 0; t < nt_k; ++t) {
    int rem = nt_k - t;
    if (rem >= 3) {
      asm volatile("s_waitcnt vmcnt(16)" ::: "memory");
    } else if (rem == 2) {
      asm volatile("s_waitcnt vmcnt(8)" ::: "memory");
    } else {
      asm volatile("s_waitcnt vmcnt(0)" ::: "memory");
    }
    __builtin_amdgcn_sched_barrier(0);
    __builtin_amdgcn_s_barrier();
    __builtin_amdgcn_sched_barrier(0);
    if (t + 3 < nt_k) stage(t + 3, (t + 3) & 3);

    const unsigned short* Ab = (const unsigned short*)lds + (t & 3) * 16384;
    const unsigned short* Bb = Ab + 8192;
#pragma unroll
    for (int ks = 0; ks < 2; ++ks) {
      short8 bfr[4];
#pragma unroll
      for (int j = 0; j < 4; ++j) {
        int row = wn + j * 16 + r;
        bfr[j] = *(const short8*)&Bb[row * 64 + ((g + ks * 4) ^ (r & 7)) * 8];
      }
#pragma unroll
      for (int i = 0; i < 4; ++i) {
        int row = wm + i * 16 + r;
        short8 af = *(const short8*)&Ab[row * 64 + ((g + ks * 4) ^ (r & 7)) * 8];
#pragma unroll
        for (int j = 0; j < 4; ++j)
          acc[i][j] = __builtin_amdgcn_mfma_f32_16x16x32_bf16(af, bfr[j], acc[i][j], 0, 0, 0);
      }
    }
  }
  if constexpr (EPI == 4) {
    qkv_rope_epilogue(acc, (unsigned short*)Cout, (const float2*)bias,
                      m0, n0, wm, wn, g, r);
  } else {
    gemm_epilogue<EPI, 4, 4>(acc, Cout, bias, mods, gate_ofs, src, N, rowsPerB,
                             m0, n0, wm, wn, g, r);
  }
}

// ---------------------------------------------------------------------------
// GEMM (64x128 tile, 2-blocks/CU): 4 waves of 32x64, BK=64, 3 LDS bufs (72KB),
// depth-2 counted vmcnt(6).  Grid = (M/64)*(N/128); nt = flat % ntn puts one
// B-panel per XCD when ntn==8.  PROVEN best for the grid-512 N=1024 GEMMs
// (r8: 128^2 pipe at 1 block/CU is 23us slower across wo_s/wo_c/mlp2).
// ---------------------------------------------------------------------------
template <int EPI>
__global__ __launch_bounds__(256) void gemm_p2(
    const unsigned short* __restrict__ A, const unsigned short* __restrict__ Bt,
    void* __restrict__ Cout, const float* __restrict__ bias,
    const float* __restrict__ mods, int gate_ofs, const float* __restrict__ src,
    int M, int N, int K, int rowsPerB, int ntn) {
  __shared__ unsigned short lds[3 * 12288];  // per buf: A 64x64 (8KB) | B 128x64 (16KB)
  const int tid = threadIdx.x;
  const int wave = tid >> 6, lane = tid & 63;
  const int g = lane >> 4, r = lane & 15;
  const int flat = blockIdx.x;
  const int nt = flat % ntn, mt = flat / ntn;
  const int m0 = mt * 64, n0 = nt * 128;
  const int wm = (wave >> 1) * 32, wn = (wave & 1) * 64;
  const int srow8 = lane >> 3;
  const int sck = (lane & 7) ^ srow8;

  f32x4 acc[2][4] = {};

  auto stage = [&](int t, int bufi) {
    const int k0 = t * 64;
    unsigned short* base = (unsigned short*)lds + bufi * 12288;
#pragma unroll
    for (int i = 0; i < 2; ++i) {  // A units: 8 of 64 rows
      int u = wave * 2 + i;
      int rl = u * 8 + srow8;
      const unsigned short* gsrc = A + (size_t)(m0 + rl) * K + k0 + sck * 8;
      __builtin_amdgcn_global_load_lds(GLB(gsrc), LDSP(base + u * 512), 16, 0, 0);
    }
#pragma unroll
    for (int i = 0; i < 4; ++i) {  // B units: 16 of 128 rows
      int u = wave * 4 + i;
      int rl = u * 8 + srow8;
      const unsigned short* gsrc = Bt + (size_t)(n0 + rl) * K + k0 + sck * 8;
      __builtin_amdgcn_global_load_lds(GLB(gsrc), LDSP(base + 4096 + u * 512), 16, 0, 0);
    }
  };

  const int ntk = K / 64;
  stage(0, 0);
  stage(1, 1);
  int cbuf = 0, sbuf = 2;

  for (int t = 0; t < ntk; ++t) {
    if (t < ntk - 1) {
      asm volatile("s_waitcnt vmcnt(6)" ::: "memory");
    } else {
      asm volatile("s_waitcnt vmcnt(0)" ::: "memory");
    }
    __builtin_amdgcn_sched_barrier(0);
    __builtin_amdgcn_s_barrier();
    __builtin_amdgcn_sched_barrier(0);
    if (t + 2 < ntk) {
      stage(t + 2, sbuf);
      sbuf = (sbuf == 2) ? 0 : sbuf + 1;
    }

    const unsigned short* Ab = (const unsigned short*)lds + cbuf * 12288;
    const unsigned short* Bb = Ab + 4096;
#pragma unroll
    for (int ks = 0; ks < 2; ++ks) {
      short8 bfr[4];
#pragma unroll
      for (int j = 0; j < 4; ++j) {
        int row = wn + j * 16 + r;
        bfr[j] = *(const short8*)&Bb[row * 64 + ((g + ks * 4) ^ (r & 7)) * 8];
      }
#pragma unroll
      for (int i = 0; i < 2; ++i) {
        int row = wm + i * 16 + r;
        short8 af = *(const short8*)&Ab[row * 64 + ((g + ks * 4) ^ (r & 7)) * 8];
#pragma unroll
        for (int j = 0; j < 4; ++j)
          acc[i][j] = __builtin_amdgcn_mfma_f32_16x16x32_bf16(af, bfr[j], acc[i][j], 0, 0, 0);
      }
    }
    cbuf = (cbuf == 2) ? 0 : cbuf + 1;
  }
  gemm_epilogue<EPI, 2, 4>(acc, Cout, bias, mods, gate_ofs, src, N, rowsPerB,
                           m0, n0, wm, wn, g, r);
}

// ---------------------------------------------------------------------------
// Flash attention v10: v9 flash body + HIDDEN cross-KV GEMM.
// Blocks [0,512): flash (128 q/block, T15 pipeline, 40KB LDS, 4 blk/CU cap).
// Blocks [512,640): cross-KV projection ctxb(1024x1024) @ wkcT/wvcT(2048) ->
//   kcb/vcb (gemm_bt 128x128/BK=32 body, 16KB LDS <= flash's 40KB so the
//   combined kernel keeps the 4-blk/CU resource cap and ALL 640 blocks are
//   co-resident: the KV GEMM runs in CU slots flash leaves idle at grid 512).
// KV inputs (ctxb, wkcT) are ready after prep; output kcb/vcb is first read
// two launches later by flash-cross.  No aliasing with kb/vb (separate bufs).
// ---------------------------------------------------------------------------
__global__ __launch_bounds__(256, 2) void flash2(
    const unsigned short* __restrict__ Q, const unsigned short* __restrict__ Kv,
    const unsigned short* __restrict__ Vv, unsigned short* __restrict__ O,
    int Lk,
    const unsigned short* __restrict__ Actx,
    const unsigned short* __restrict__ Bkv,
    unsigned short* __restrict__ Okv) {
  __shared__ unsigned short lds[20480];  // 40KB: K 3x8KB @0 | V^T 2x8KB @12288
  const int tid = threadIdx.x, wave = tid >> 6, lane = tid & 63;

  if (blockIdx.x >= 512) {
    // ---- cross-KV GEMM (m97 body): M=1024, N=2048, K=1024, 128 blocks ----
    const int gblk = blockIdx.x - 512;
    const int m0 = (gblk >> 4) * 128, n0 = (gblk & 15) * 128;
    const int g = lane >> 4, r = lane & 15;
    const int wm = (wave >> 1) * 64, wn = (wave & 1) * 64;
    const int srow = lane >> 2;
    const int scol = (lane & 3) * 8;
    unsigned short* As = lds;           // 128x32
    unsigned short* Bs = lds + 4096;    // 128x32
    f32x4 acc[4][4] = {};
    for (int k0 = 0; k0 < 1024; k0 += 32) {
      __syncthreads();
#pragma unroll
      for (int cc = 0; cc < 4; ++cc) {
        int c = wave * 4 + cc;
        int isB = c >> 3;
        int cl = c & 7;
        int row = cl * 16 + srow;
        const unsigned short* gsrc =
            isB ? (Bkv + (size_t)(n0 + row) * 1024 + k0 + scol)
                : (Actx + (size_t)(m0 + row) * 1024 + k0 + scol);
        unsigned short* ldst = (isB ? Bs : As) + cl * 512;
        __builtin_amdgcn_global_load_lds(GLB(gsrc), LDSP(ldst), 16, 0, 0);
      }
      __syncthreads();
      short8 bfr[4];
#pragma unroll
      for (int j = 0; j < 4; ++j)
        bfr[j] = *(const short8*)(&Bs[(wn + j * 16 + r) * 32 + g * 8]);
#pragma unroll
      for (int i = 0; i < 4; ++i) {
        short8 af = *(const short8*)(&As[(wm + i * 16 + r) * 32 + g * 8]);
#pragma unroll
        for (int j = 0; j < 4; ++j)
          acc[i][j] = __builtin_amdgcn_mfma_f32_16x16x32_bf16(af, bfr[j], acc[i][j], 0, 0, 0);
      }
    }
    // split-store: buf = gcol>>10, kcb/vcb adjacent with stride 1024*1024 elems
#pragma unroll
    for (int i = 0; i < 4; ++i) {
#pragma unroll
      for (int j = 0; j < 4; ++j) {
#pragma unroll
        for (int q = 0; q < 4; ++q) {
          size_t grow = (size_t)(m0 + wm + i * 16 + g * 4 + q);
          size_t gcol = (size_t)(n0 + wn + j * 16 + r);
          size_t buf = gcol >> 10;
          Okv[buf * (1024ull * 1024) + grow * 1024 + (gcol & 1023)] =
              f2b(acc[i][j][q]);
        }
      }
    }
    return;
  }

  const int hi = lane >> 5, lq = lane & 31;
  const int flat = blockIdx.x;
  const int xcd = flat & 7, rr = flat >> 3;
  const int gl = rr >> 4, qt = rr & 15;
  const int g = xcd * 4 + gl;
  const int h = g & 15, b = g >> 4;
  const int Lq = 2048, D = 1024;

  const unsigned short* Qbase =
      Q + ((size_t)b * Lq + qt * 128 + wave * 32 + lq) * D + h * 64;
  const unsigned short* Kbase = Kv + (size_t)b * Lk * D + h * 64;
  const unsigned short* Vbase = Vv + (size_t)b * Lk * D + h * 64;

  short8 qf[4];
#pragma unroll
  for (int kb = 0; kb < 4; ++kb)
    qf[kb] = *(const short8*)(Qbase + kb * 16 + hi * 8);

  const short8 ones = {0x3F80, 0x3F80, 0x3F80, 0x3F80, 0x3F80, 0x3F80, 0x3F80, 0x3F80};
  const f32x16 z16 = {};  // persistent zero C-operand

  const int kr0 = tid >> 3, kc0 = tid & 7;   // K stage: row, chunk
  const int kvp = tid >> 3, db = tid & 7;    // V stage: kv-pair, d-block
  const int kch0 = (kc0 ^ (kr0 & 7) ^ (kr0 >> 3)) & 7;
  const int kch1 = kch0 ^ 4;
  const int f0 = (lq & 7) ^ (lq >> 3);
  const int swz0 = f0 << 4, swz1 = swz0 ^ 64;

  // kt-invariant V^T write byte-offsets (per-thread constants, reg-resident)
  int vby[8];
#pragma unroll
  for (int e = 0; e < 8; ++e) {
    int d = db * 8 + e;
    vby[e] = d * 128 + ((kvp * 4) ^ (((e ^ db) & 7) << 4));
  }

  float m_run = -3.0e38f;
  f32x16 o0 = {}, o1 = {}, lacc = {};
  short8 vr0, vr1;
  short8 pbf[4];

  auto stageK = [&](int t, int bi) {
    const unsigned short* s0 = Kbase + (size_t)(t * 64 + kr0) * D + kch0 * 8;
    const unsigned short* s1 = Kbase + (size_t)(t * 64 + kr0 + 32) * D + kch1 * 8;
    __builtin_amdgcn_global_load_lds(GLB(s0), LDSP(&lds[bi * 4096 + wave * 512]), 16, 0, 0);
    __builtin_amdgcn_global_load_lds(GLB(s1), LDSP(&lds[bi * 4096 + 2048 + wave * 512]), 16, 0, 0);
  };
  auto loadV = [&](int t) {
    const unsigned short* v0 = Vbase + (size_t)(t * 64 + 2 * kvp) * D + db * 8;
    vr0 = *(const short8*)v0;
    vr1 = *(const short8*)(v0 + D);
  };
  auto writeV = [&](int t) {
    char* vt = (char*)&lds[12288 + (t & 1) * 4096];
    union { short8 s; unsigned int u[4]; } a, c;
    a.s = vr0; c.s = vr1;
#pragma unroll
    for (int k = 0; k < 4; ++k) {
      *(unsigned int*)(vt + vby[2 * k]) =
          __builtin_amdgcn_perm(c.u[k], a.u[k], 0x05040100u);
      *(unsigned int*)(vt + vby[2 * k + 1]) =
          __builtin_amdgcn_perm(c.u[k], a.u[k], 0x07060302u);
    }
  };
  auto qk = [&](int bi, f32x16& sa0, f32x16& sa1) {
    const unsigned short* K0 = &lds[bi * 4096];
    {
      int lo = hi * 16;
      short8 a0 = *(const short8*)&K0[lq * 64 + ((lo ^ swz0) >> 1)];
      short8 a1 = *(const short8*)&K0[(32 + lq) * 64 + ((lo ^ swz1) >> 1)];
      sa0 = __builtin_amdgcn_mfma_f32_32x32x16_bf16(a0, qf[0], z16, 0, 0, 0);
      sa1 = __builtin_amdgcn_mfma_f32_32x32x16_bf16(a1, qf[0], z16, 0, 0, 0);
    }
#pragma unroll
    for (int ks = 1; ks < 4; ++ks) {
      int lo = ks * 32 + hi * 16;
      short8 a0 = *(const short8*)&K0[lq * 64 + ((lo ^ swz0) >> 1)];
      short8 a1 = *(const short8*)&K0[(32 + lq) * 64 + ((lo ^ swz1) >> 1)];
      sa0 = __builtin_amdgcn_mfma_f32_32x32x16_bf16(a0, qf[ks], sa0, 0, 0, 0);
      sa1 = __builtin_amdgcn_mfma_f32_32x32x16_bf16(a1, qf[ks], sa1, 0, 0, 0);
    }
  };
  auto finish = [&](f32x16& s0a, f32x16& s1a) {
    float tm[8];
#pragma unroll
    for (int i = 0; i < 8; ++i)
      tm[i] = fmaxf(max3f(s0a[i], s0a[i + 8], s1a[i]), s1a[i + 8]);
    float x = max3f(tm[0], tm[1], tm[2]);
    float y = max3f(tm[3], tm[4], tm[5]);
    float pm = fmaxf(max3f(tm[6], tm[7], x), y);
    {
      unsigned int ua = __builtin_bit_cast(unsigned int, pm), ub = ua;
      vpsw(ua, ub);
      pm = fmaxf(__builtin_bit_cast(float, ua), __builtin_bit_cast(float, ub));
    }
    if (__any(pm - m_run > 8.0f)) {
      float mnew = fmaxf(m_run, pm);
      float alpha = exp2f(m_run - mnew);
      lacc[0] *= alpha;
#pragma unroll
      for (int i = 0; i < 16; ++i) { o0[i] *= alpha; o1[i] *= alpha; }
      m_run = mnew;
    }
    float mc = m_run;
#pragma unroll
    for (int i = 0; i < 16; ++i) s0a[i] = exp2f(s0a[i] - mc);
#pragma unroll
    for (int i = 0; i < 16; ++i) s1a[i] = exp2f(s1a[i] - mc);
#pragma unroll
    for (int kb = 0; kb < 4; ++kb) {
      int bb = (kb & 1) * 8;
      float p0, p1, p2, p3, p4, p5, p6, p7;
      if (kb < 2) {
        p0 = s0a[bb + 0]; p1 = s0a[bb + 1]; p2 = s0a[bb + 2]; p3 = s0a[bb + 3];
        p4 = s0a[bb + 4]; p5 = s0a[bb + 5]; p6 = s0a[bb + 6]; p7 = s0a[bb + 7];
      } else {
        p0 = s1a[bb + 0]; p1 = s1a[bb + 1]; p2 = s1a[bb + 2]; p3 = s1a[bb + 3];
        p4 = s1a[bb + 4]; p5 = s1a[bb + 5]; p6 = s1a[bb + 6]; p7 = s1a[bb + 7];
      }
      unsigned int u0 = pk2(p0, p1), u1 = pk2(p2, p3);
      unsigned int u2 = pk2(p4, p5), u3 = pk2(p6, p7);
      vpsw(u0, u2);
      vpsw(u1, u3);
      union { unsigned int u[4]; short8 s; } fr;
      fr.u[0] = u0; fr.u[1] = u1; fr.u[2] = u2; fr.u[3] = u3;
      pbf[kb] = fr.s;
    }
  };
  auto pv = [&](int t) {
    const unsigned short* V0 = &lds[12288 + (t & 1) * 4096];
    __builtin_amdgcn_s_setprio(1);
#pragma unroll
    for (int kb = 0; kb < 4; ++kb) {
      int lo = kb * 32 + hi * 16;
      short8 vf0 = *(const short8*)&V0[lq * 64 + ((lo ^ swz0) >> 1)];
      short8 vf1 = *(const short8*)&V0[(32 + lq) * 64 + ((lo ^ swz1) >> 1)];
      o0 = __builtin_amdgcn_mfma_f32_32x32x16_bf16(vf0, pbf[kb], o0, 0, 0, 0);
      o1 = __builtin_amdgcn_mfma_f32_32x32x16_bf16(vf1, pbf[kb], o1, 0, 0, 0);
      lacc = __builtin_amdgcn_mfma_f32_32x32x16_bf16(ones, pbf[kb], lacc, 0, 0, 0);
    }
    __builtin_amdgcn_s_setprio(0);
  };

  const int nkt = Lk / 64;  // even for both Lk=2048 (32) and Lk=512 (8)

  // prologue: K(0)->buf0, V(0)->Vbuf0, K(1)->buf1, then S(0)
  stageK(0, 0);
  loadV(0);
  writeV(0);
  stageK(1, 1);
  __syncthreads();

  f32x16 sA0, sA1, sB0, sB1;
  qk(0, sA0, sA1);

  // pipelined step: QK(t+1)->snew (MFMA) overlaps finish(sold) (VALU); PV(t)
  auto pstep = [&](int t, f32x16& n0, f32x16& n1, f32x16& p0, f32x16& p1) {
    const int tq = t + 1;
    if (tq < nkt) {
      loadV(tq);
      if (tq + 1 < nkt) stageK(tq + 1, (tq + 1) % 3);
      qk(tq % 3, n0, n1);
    }
    finish(p0, p1);
    if (tq < nkt) writeV(tq);
    pv(t);
    __syncthreads();
  };

  for (int t = 0; t < nkt; t += 2) {
    pstep(t, sB0, sB1, sA0, sA1);
    pstep(t + 1, sA0, sA1, sB0, sB1);
  }

  // ---- epilogue: normalize, bounce through LDS, coalesced store ----
  float rl = 1.0f / lacc[0];
  unsigned short* os = &lds[wave * 2048];
#pragma unroll
  for (int t = 0; t < 2; ++t) {
#pragma unroll
    for (int c = 0; c < 4; ++c) {
      int dbase = 32 * t + 8 * c + 4 * hi;
      float v0 = (t ? o1[4 * c + 0] : o0[4 * c + 0]) * rl;
      float v1 = (t ? o1[4 * c + 1] : o0[4 * c + 1]) * rl;
      float v2 = (t ? o1[4 * c + 2] : o0[4 * c + 2]) * rl;
      float v3 = (t ? o1[4 * c + 3] : o0[4 * c + 3]) * rl;
      int by0 = lq * 128 + ((dbase * 2) ^ ((lq & 7) << 4));
      int by1 = lq * 128 + (((dbase + 2) * 2) ^ ((lq & 7) << 4));
      *(unsigned int*)((char*)os + by0) = pk2(v0, v1);
      *(unsigned int*)((char*)os + by1) = pk2(v2, v3);
    }
  }
  int q2 = lane >> 1;
  unsigned short* orow =
      O + ((size_t)b * Lq + qt * 128 + wave * 32 + q2) * D + h * 64;
#pragma unroll
  for (int j = 0; j < 4; ++j) {
    int j2 = (lane & 1) * 4 + j;
    int byr = q2 * 128 + ((j2 * 16) ^ ((q2 & 7) << 4));
    short8 vv = *(const short8*)((char*)os + byr);
    *(short8*)(orow + j2 * 8) = vv;
  }
}

// ---------------------------------------------------------------------------
// Host orchestration
// ---------------------------------------------------------------------------
extern "C" void kernel_launch(void* const* d_in, const int* in_sizes, int n_in,
                              void* d_out, int out_size, void* d_ws, size_t ws_size,
                              hipStream_t stream) {
  (void)in_sizes; (void)n_in; (void)out_size; (void)ws_size;
  const float* x_in = (const float*)d_in[0];
  const float* te   = (const float*)d_in[1];
  const float* ctx  = (const float*)d_in[2];
  const float* rope = (const float*)d_in[3];
  const float* wmod = (const float*)d_in[4];
  const float* bmod = (const float*)d_in[5];
  const float* wqs  = (const float*)d_in[6];
  const float* wks  = (const float*)d_in[7];
  const float* wvs  = (const float*)d_in[8];
  const float* wos  = (const float*)d_in[9];
  const float* bos  = (const float*)d_in[10];
  const float* wqc  = (const float*)d_in[11];
  const float* wkc  = (const float*)d_in[12];
  const float* wvc  = (const float*)d_in[13];
  const float* woc  = (const float*)d_in[14];
  const float* boc  = (const float*)d_in[15];
  const float* w1   = (const float*)d_in[16];
  const float* b1   = (const float*)d_in[17];
  const float* w2   = (const float*)d_in[18];
  const float* b2   = (const float*)d_in[19];
  float* out = (float*)d_out;

  char* w = (char*)d_ws;
  size_t o = 0;
  auto alloc = [&](size_t bytes) {
    char* p = w + o;
    o = (o + bytes + 255) & ~(size_t)255;
    return p;
  };
  // wqsT/wksT/wvsT adjacent (fused QKV); wkcT/wvcT adjacent (fused cross-KV).
  unsigned short* wqsT  = (unsigned short*)alloc(1024ull * 1024 * 2);
  unsigned short* wksT  = (unsigned short*)alloc(1024ull * 1024 * 2);
  unsigned short* wvsT  = (unsigned short*)alloc(1024ull * 1024 * 2);
  unsigned short* wosT  = (unsigned short*)alloc(1024ull * 1024 * 2);
  unsigned short* wqcT  = (unsigned short*)alloc(1024ull * 1024 * 2);
  unsigned short* wkcT  = (unsigned short*)alloc(1024ull * 1024 * 2);
  unsigned short* wvcT  = (unsigned short*)alloc(1024ull * 1024 * 2);
  unsigned short* wocT  = (unsigned short*)alloc(1024ull * 1024 * 2);
  unsigned short* w1T   = (unsigned short*)alloc(4096ull * 1024 * 2);
  unsigned short* w2T   = (unsigned short*)alloc(1024ull * 4096 * 2);
  float* modsb = (float*)alloc(2ull * 6144 * 4);
  float2* csT  = (float2*)alloc(2048ull * 64 * 8);
  unsigned short* nx   = (unsigned short*)alloc(4096ull * 1024 * 2);
  unsigned short* ctxb = (unsigned short*)alloc(1024ull * 1024 * 2);
  // qb/kb/vb adjacent: EPI3/EPI4 buffer stride = 4096*1024 elems.
  unsigned short* qb = (unsigned short*)alloc(4096ull * 1024 * 2);
  unsigned short* kb = (unsigned short*)alloc(4096ull * 1024 * 2);
  unsigned short* vb = (unsigned short*)alloc(4096ull * 1024 * 2);
  unsigned short* ao = (unsigned short*)alloc(4096ull * 1024 * 2);
  // cross K/V (written concurrently with flash-self; must NOT alias kb/vb).
  // kcb/vcb adjacent: hidden-KV split-store stride = 1024*1024 elems.
  unsigned short* kcb = (unsigned short*)alloc(1024ull * 1024 * 2);
  unsigned short* vcb = (unsigned short*)alloc(1024ull * 1024 * 2);
  unsigned short* xwb = (unsigned short*)alloc(4096ull * 1024 * 2);  // residual after self-attn (bf16)
  float* xw = (float*)alloc(4096ull * 1024 * 4);                     // residual after cross-attn (f32)
  unsigned short* hbuf = qb;  // reuse qb..ao contiguous 32MB for MLP hidden

  const float c1 = 0.125f * 1.4426950408889634f;  // scale * log2(e), folded into wqs/wkc

  PrepArgs pa;
  pa.wmod = wmod; pa.te = te; pa.bmod = bmod; pa.mods = modsb;
  pa.sq[0] = {wqs, wqsT, c1};
  pa.sq[1] = {wks, wksT, 1.0f};
  pa.sq[2] = {wvs, wvsT, 1.0f};
  pa.sq[3] = {wos, wosT, 1.0f};
  pa.sq[4] = {wqc, wqcT, 1.0f};
  pa.sq[5] = {wkc, wkcT, c1};
  pa.sq[6] = {wvc, wvcT, 1.0f};
  pa.sq[7] = {woc, wocT, 1.0f};
  pa.w1 = w1; pa.w1T = w1T;
  pa.w2 = w2; pa.w2T = w2T;
  pa.ctx = ctx; pa.ctxb = ctxb;
  pa.rope = rope; pa.cs = csT;
  prep<<<18968, 256, 0, stream>>>(pa);

  // --- self-attention (RoPE fused into QKV epilogue) ---
  ln_mod<0><<<4096, 256, 0, stream>>>(x_in, modsb, nx, 1024, 0);
  gemm_pipe<4><<<768, 256, 0, stream>>>(nx, wqsT, qb, (const float*)csT, nullptr, -1, nullptr, 4096, 3072, 1024, 2048, 2);
  // flash-self (512 blk) + hidden cross-KV projection (128 blk) in one launch
  flash2<<<640, 256, 0, stream>>>(qb, kb, vb, ao, 2048, ctxb, wkcT, kcb);
  // xw1 = x + gate_msa*sa, stored bf16 (EPI5: bf16 out, f32 src)
  gemm_p2<5><<<512, 256, 0, stream>>>(ao, wosT, xwb, bos, modsb, 2048, x_in, 4096, 1024, 1024, 2048, 8);

  // --- cross-attention (KV already computed under flash-self) ---
  ln_mod<1><<<4096, 256, 0, stream>>>(xwb, modsb, nx, -1, -1);
  gemm_p2<0><<<512, 256, 0, stream>>>(nx, wqcT, qb, nullptr, nullptr, -1, nullptr, 4096, 1024, 1024, 2048, 8);
  flash2<<<512, 256, 0, stream>>>(qb, kcb, vcb, ao, 512, nullptr, nullptr, nullptr);
  // xw2 = xw1 + ca, f32 out from bf16 src (EPI7)
  gemm_p2<7><<<512, 256, 0, stream>>>(ao, wocT, xw, boc, modsb, -1, (const float*)xwb, 4096, 1024, 1024, 2048, 8);

  // --- MLP ---
  ln_mod<0><<<4096, 256, 0, stream>>>(xw, modsb, nx, 4096, 3072);
  gemm_bt<1><<<dim3(32, 32), 256, 0, stream>>>(nx, w1T, hbuf, b1, nullptr, -1, nullptr, 4096, 4096, 1024, 2048);
  gemm_p2<2><<<512, 256, 0, stream>>>(hbuf, w2T, out, b2, modsb, 5120, xw, 4096, 1024, 4096, 2048, 8);
}

// Round 12
// 386.708 us; speedup vs baseline: 1.0589x; 1.0023x over previous
//
#include <hip/hip_runtime.h>
#include <hip/hip_bf16.h>

// ---------------------------------------------------------------------------
// CleanDITBlock: adaLN-modulated DiT block (self-attn w/ RoPE, cross-attn, MLP)
// B=2, L=2048, S=512, D=1024, H=16, HD=64, CTX=1024, HID=4096
// ---------------------------------------------------------------------------

typedef short short8 __attribute__((ext_vector_type(8)));
typedef float f32x4 __attribute__((ext_vector_type(4)));
typedef float f32x16 __attribute__((ext_vector_type(16)));

#define DEV __device__ __forceinline__

DEV unsigned short f2b(float f) {
  __hip_bfloat16 h = __float2bfloat16(f);
  return *reinterpret_cast<unsigned short*>(&h);
}
DEV float b2f(unsigned short u) {
  unsigned int x = ((unsigned int)u) << 16;
  return __builtin_bit_cast(float, x);
}
// single-instruction packed f32->bf16 pair (T12): D[15:0]=bf16(lo), D[31:16]=bf16(hi)
DEV unsigned int pk2(float lo, float hi) {
  unsigned int r;
  asm("v_cvt_pk_bf16_f32 %0, %1, %2" : "=v"(r) : "v"(lo), "v"(hi));
  return r;
}
// lane[i]<->lane[i+32] half-swap (VALU, no LDS)
DEV void vpsw(unsigned int& a, unsigned int& b) {
  asm("v_permlane32_swap_b32 %0, %1" : "+v"(a), "+v"(b));
}
// 3-input max (T17)
DEV float max3f(float a, float b, float c) {
  float r;
  asm("v_max3_f32 %0, %1, %2, %3" : "=v"(r) : "v"(a), "v"(b), "v"(c));
  return r;
}

#define GLB(p) ((const __attribute__((address_space(1))) void*)(p))
#define LDSP(p) ((__attribute__((address_space(3))) void*)(p))

// ---------------------------------------------------------------------------
// prep: ALL preprocessing in one launch (flattened grid, range decode).
//   [0,24)            mods = te @ wmod + bmod, computed DIRECTLY from f32 wmod
//   [24,8216)         8 square 1024^2 transposes (wq/wk/wv/wo self+cross)
//   [8216,12312)      w1 transpose (1024x4096 -> 4096x1024)
//   [12312,16408)     w2 transpose (4096x1024 -> 1024x4096)
//   [16408,18456)     ctx f32->bf16 cast, 2 elems/thread (packed cvt)
//   [18456,18968)     rope (cos,sin) table (131072 elems)
// ---------------------------------------------------------------------------
struct TCB { const float* in; unsigned short* out; float scale; };
struct PrepArgs {
  const float* wmod; const float* te; const float* bmod; float* mods;
  TCB sq[8];
  const float* w1; unsigned short* w1T;
  const float* w2; unsigned short* w2T;
  const float* ctx; unsigned short* ctxb;
  const float* rope; float2* cs;
};

__global__ __launch_bounds__(256) void prep(PrepArgs a) {
  __shared__ float t32[32][33];
  __shared__ float tes[2048];
  const int blk = blockIdx.x;
  const int tid = threadIdx.x;
  const int tx = tid & 31, ty = tid >> 5;
  if (blk < 24) {
    // ---- mods: j-chunk of 256 columns, both batches ----
    const int j = blk * 256 + tid;
    for (int u = tid; u < 2048; u += 256) tes[u] = a.te[u];
    __syncthreads();
    float a0 = 0.f, b0 = 0.f, a1 = 0.f, b1 = 0.f;
#pragma unroll 8
    for (int k = 0; k < 1024; k += 2) {
      float v0 = a.wmod[(size_t)k * 6144 + j];
      float v1 = a.wmod[(size_t)(k + 1) * 6144 + j];
      a0 += tes[k] * v0;
      b0 += tes[k + 1] * v1;
      a1 += tes[1024 + k] * v0;
      b1 += tes[1024 + k + 1] * v1;
    }
    float bm = a.bmod[j];
    a.mods[j] = a0 + b0 + bm;
    a.mods[6144 + j] = a1 + b1 + bm;
  } else if (blk < 16408) {
    const float* in;
    unsigned short* out;
    int R, C, gx, tile;
    float scale;
    if (blk < 8216) {
      int j = (blk - 24) >> 10;
      tile = (blk - 24) & 1023;
      in = a.sq[j].in; out = a.sq[j].out; scale = a.sq[j].scale;
      R = 1024; C = 1024; gx = 32;
    } else if (blk < 12312) {
      tile = blk - 8216;
      in = a.w1; out = a.w1T; R = 1024; C = 4096; gx = 128; scale = 1.f;
    } else {
      tile = blk - 12312;
      in = a.w2; out = a.w2T; R = 4096; C = 1024; gx = 32; scale = 1.f;
    }
    int bx = (tile % gx) * 32, by = (tile / gx) * 32;
#pragma unroll
    for (int i = ty; i < 32; i += 8)
      t32[i][tx] = in[(size_t)(by + i) * C + bx + tx];
    __syncthreads();
#pragma unroll
    for (int i = ty; i < 32; i += 8)
      out[(size_t)(bx + i) * R + by + tx] = f2b(t32[tx][i] * scale);
  } else if (blk < 18456) {
    int i = (blk - 16408) * 512 + tid * 2;
    float2 v = *(const float2*)&a.ctx[i];
    *(unsigned int*)&a.ctxb[i] = pk2(v.x, v.y);
  } else {
    int i = (blk - 18456) * 256 + tid;
    float v = a.rope[i];
    a.cs[i] = make_float2(cosf(v), sinf(v));
  }
}

// ---------------------------------------------------------------------------
// ln_mod: LayerNorm (+ optional adaLN scale/shift) -> bf16.
// BF16IN=1 reads a bf16 input stream (residual stored as bf16).
// ---------------------------------------------------------------------------
template <int BF16IN>
__global__ __launch_bounds__(256) void ln_mod(
    const void* __restrict__ xin, const float* __restrict__ mods,
    unsigned short* __restrict__ out, int scale_ofs, int shift_ofs) {
  int row = blockIdx.x;
  int b = row >> 11;
  int tid = threadIdx.x;
  float vv[4];
  if constexpr (BF16IN) {
    const unsigned short* xr = (const unsigned short*)xin + (size_t)row * 1024;
    ushort4 u = ((const ushort4*)xr)[tid];
    vv[0] = b2f(u.x); vv[1] = b2f(u.y); vv[2] = b2f(u.z); vv[3] = b2f(u.w);
  } else {
    const float* xr = (const float*)xin + (size_t)row * 1024;
    float4 v = ((const float4*)xr)[tid];
    vv[0] = v.x; vv[1] = v.y; vv[2] = v.z; vv[3] = v.w;
  }
  float s = vv[0] + vv[1] + vv[2] + vv[3];
  float ss = vv[0] * vv[0] + vv[1] * vv[1] + vv[2] * vv[2] + vv[3] * vv[3];
#pragma unroll
  for (int off = 32; off >= 1; off >>= 1) {
    s += __shfl_down(s, off);
    ss += __shfl_down(ss, off);
  }
  __shared__ float red[8];
  int wave = tid >> 6, lane = tid & 63;
  if (lane == 0) { red[wave] = s; red[4 + wave] = ss; }
  __syncthreads();
  if (tid == 0) {
    float S = red[0] + red[1] + red[2] + red[3];
    float SS = red[4] + red[5] + red[6] + red[7];
    float mu = S * (1.f / 1024.f);
    red[0] = mu;
    red[1] = SS * (1.f / 1024.f) - mu * mu;
  }
  __syncthreads();
  float mu = red[0];
  float rs = rsqrtf(red[1] + 1e-6f);
  unsigned short o[4];
#pragma unroll
  for (int c = 0; c < 4; ++c) {
    int col = tid * 4 + c;
    float nv = (vv[c] - mu) * rs;
    if (scale_ofs >= 0)
      nv = nv * (1.f + mods[(size_t)b * 6144 + scale_ofs + col]) +
           mods[(size_t)b * 6144 + shift_ofs + col];
    o[c] = f2b(nv);
  }
  *(ushort4*)(&out[(size_t)row * 1024 + tid * 4]) = *(const ushort4*)o;
}

// ---------------------------------------------------------------------------
// Shared GEMM epilogue.  EPI: 0 bf16; 1 bias+GELU bf16; 2 f32 residual
// src(f32) + gate*(acc+bias); 3 bf16 split-store; 5 bf16 residual out
// (src f32); 7 f32 residual out (src bf16).
// ---------------------------------------------------------------------------
template <int EPI, int MI, int NJ>
DEV void gemm_epilogue(f32x4 (&acc)[MI][NJ], void* Cout, const float* bias,
                       const float* mods, int gate_ofs, const float* src,
                       int N, int rowsPerB, int m0, int n0, int wm, int wn,
                       int g, int r) {
#pragma unroll
  for (int i = 0; i < MI; ++i) {
#pragma unroll
    for (int j = 0; j < NJ; ++j) {
#pragma unroll
      for (int q = 0; q < 4; ++q) {
        size_t grow = (size_t)(m0 + wm + i * 16 + g * 4 + q);
        size_t gcol = (size_t)(n0 + wn + j * 16 + r);
        float v = acc[i][j][q];
        if constexpr (EPI == 0) {
          ((unsigned short*)Cout)[grow * N + gcol] = f2b(v);
        } else if constexpr (EPI == 1) {
          v += bias[gcol];
          float ge = 0.5f * v * (1.0f + erff(v * 0.70710678f));
          ((unsigned short*)Cout)[grow * N + gcol] = f2b(ge);
        } else if constexpr (EPI == 3) {
          size_t buf = gcol >> 10;
          ((unsigned short*)Cout)[buf * (4096ull * 1024) + grow * 1024 + (gcol & 1023)] = f2b(v);
        } else if constexpr (EPI == 5) {
          // bf16 residual out, f32 src
          v += bias[gcol];
          float gate = 1.0f;
          if (gate_ofs >= 0)
            gate = mods[(grow / rowsPerB) * 6144 + gate_ofs + gcol];
          ((unsigned short*)Cout)[grow * N + gcol] =
              f2b(src[grow * N + gcol] + gate * v);
        } else if constexpr (EPI == 7) {
          // f32 residual out, bf16 src
          v += bias[gcol];
          float gate = 1.0f;
          if (gate_ofs >= 0)
            gate = mods[(grow / rowsPerB) * 6144 + gate_ofs + gcol];
          float sv = b2f(((const unsigned short*)src)[grow * N + gcol]);
          ((float*)Cout)[grow * N + gcol] = sv + gate * v;
        } else {
          v += bias[gcol];
          float gate = 1.0f;
          if (gate_ofs >= 0)
            gate = mods[(grow / rowsPerB) * 6144 + gate_ofs + gcol];
          ((float*)Cout)[grow * N + gcol] = src[grow * N + gcol] + gate * v;
        }
      }
    }
  }
}

// ---------------------------------------------------------------------------
// QKV epilogue with fused RoPE (EPI 4).  j-tiles are head-aligned: d=j*16+r,
// rotation pair (d,d+32) = (acc[i][j], acc[i][j+2]) in the SAME lane.  Applies
// rope to buffers 0 (q) and 1 (k); buffer 2 (v) stored plain.  cs = interleaved
// (cos,sin)[l][d].
// ---------------------------------------------------------------------------
DEV void qkv_rope_epilogue(f32x4 (&acc)[4][4], unsigned short* Cout,
                           const float2* cs, int m0, int n0, int wm, int wn,
                           int g, int r) {
  const int buf = (n0 + wn) >> 10;      // wave-uniform
  const int colbase = (n0 + wn) & 1023;
  unsigned short* base = Cout + (size_t)buf * (4096ull * 1024);
#pragma unroll
  for (int i = 0; i < 4; ++i) {
#pragma unroll
    for (int q = 0; q < 4; ++q) {
      size_t grow = (size_t)(m0 + wm + i * 16 + g * 4 + q);
      unsigned short* orow = base + grow * 1024 + colbase + r;
      if (buf < 2) {
        int l = (int)(grow & 2047);
#pragma unroll
        for (int j = 0; j < 2; ++j) {
          int d = j * 16 + r;
          float2 a = cs[l * 64 + d];
          float2 bb = cs[l * 64 + d + 32];
          float x1 = acc[i][j][q], x2 = acc[i][j + 2][q];
          orow[j * 16] = f2b(x1 * a.x - x2 * a.y);
          orow[(j + 2) * 16] = f2b(x2 * bb.x + x1 * bb.y);
        }
      } else {
#pragma unroll
        for (int j = 0; j < 4; ++j) orow[j * 16] = f2b(acc[i][j][q]);
      }
    }
  }
}

// ---------------------------------------------------------------------------
// GEMM (m97): 128x128, BK=32, implicit overlap.  For >=4 blocks/CU (mlp1).
// ---------------------------------------------------------------------------
template <int EPI>
__global__ __launch_bounds__(256, 2) void gemm_bt(
    const unsigned short* __restrict__ A, const unsigned short* __restrict__ Bt,
    void* __restrict__ Cout, const float* __restrict__ bias,
    const float* __restrict__ mods, int gate_ofs, const float* __restrict__ src,
    int M, int N, int K, int rowsPerB) {
  __shared__ unsigned short As[128 * 32];
  __shared__ unsigned short Bs[128 * 32];
  const int tid = threadIdx.x;
  const int wave = tid >> 6, lane = tid & 63;
  const int g = lane >> 4, r = lane & 15;
  const int m0 = blockIdx.y * 128, n0 = blockIdx.x * 128;
  const int wm = (wave >> 1) * 64, wn = (wave & 1) * 64;
  const int srow = lane >> 2;
  const int scol = (lane & 3) * 8;

  f32x4 acc[4][4] = {};

  for (int k0 = 0; k0 < K; k0 += 32) {
    __syncthreads();
#pragma unroll
    for (int cc = 0; cc < 4; ++cc) {
      int c = wave * 4 + cc;
      int isB = c >> 3;
      int cl = c & 7;
      int row = cl * 16 + srow;
      const unsigned short* gsrc =
          isB ? (Bt + (size_t)(n0 + row) * K + k0 + scol)
              : (A + (size_t)(m0 + row) * K + k0 + scol);
      unsigned short* ldst = (isB ? Bs : As) + cl * 512;
      __builtin_amdgcn_global_load_lds(GLB(gsrc), LDSP(ldst), 16, 0, 0);
    }
    __syncthreads();

    short8 bfr[4];
#pragma unroll
    for (int j = 0; j < 4; ++j)
      bfr[j] = *(const short8*)(&Bs[(wn + j * 16 + r) * 32 + g * 8]);
#pragma unroll
    for (int i = 0; i < 4; ++i) {
      short8 af = *(const short8*)(&As[(wm + i * 16 + r) * 32 + g * 8]);
#pragma unroll
      for (int j = 0; j < 4; ++j)
        acc[i][j] = __builtin_amdgcn_mfma_f32_16x16x32_bf16(af, bfr[j], acc[i][j], 0, 0, 0);
    }
  }
  gemm_epilogue<EPI, 4, 4>(acc, Cout, bias, mods, gate_ofs, src, N, rowsPerB,
                           m0, n0, wm, wn, g, r);
}

// ---------------------------------------------------------------------------
// GEMM (pipelined 128x128): BK=64, 4 LDS bufs, depth-3, counted vmcnt.
// For the QKV GEMM (grid 768, 1 block/CU + 3-deep pipeline).
// EPI==4: fused-RoPE QKV epilogue (cs table passed via `bias`).
// NOTE (r8): do NOT use at grid 256 for the N=1024 GEMMs — 1 block/CU with
// no co-resident overlap loses ~23us vs gemm_p2's 512-block config.
// ---------------------------------------------------------------------------
template <int EPI>
__global__ __launch_bounds__(256) void gemm_pipe(
    const unsigned short* __restrict__ A, const unsigned short* __restrict__ Bt,
    void* __restrict__ Cout, const float* __restrict__ bias,
    const float* __restrict__ mods, int gate_ofs, const float* __restrict__ src,
    int M, int N, int K, int rowsPerB, int mshift) {
  __shared__ unsigned short lds[4 * 16384];
  const int tid = threadIdx.x;
  const int wave = tid >> 6, lane = tid & 63;
  const int g = lane >> 4, r = lane & 15;
  const int flat = blockIdx.x;
  const int xcd = flat & 7, idx = flat >> 3;
  const int mt = xcd * (1 << mshift) + (idx & ((1 << mshift) - 1));
  const int nt = idx >> mshift;
  const int m0 = mt * 128, n0 = nt * 128;
  const int wm = (wave >> 1) * 64, wn = (wave & 1) * 64;
  const int srow8 = lane >> 3;
  const int sck = (lane & 7) ^ srow8;

  f32x4 acc[4][4] = {};

  auto stage = [&](int t, int bufi) {
    const int k0 = t * 64;
#pragma unroll
    for (int i = 0; i < 8; ++i) {
      int u = wave * 8 + i;
      int isB = u >> 4;
      int uu = u & 15;
      int rl = uu * 8 + srow8;
      const unsigned short* gsrc =
          (isB ? (Bt + (size_t)(n0 + rl) * K) : (A + (size_t)(m0 + rl) * K)) +
          k0 + sck * 8;
      unsigned short* dst = (unsigned short*)lds + bufi * 16384 + isB * 8192 + uu * 512;
      __builtin_amdgcn_global_load_lds(GLB(gsrc), LDSP(dst), 16, 0, 0);
    }
  };

  const int nt_k = K / 64;
  stage(0, 0);
  stage(1, 1);
  stage(2, 2);

  for (int t = 0; t < nt_k; ++t) {
    int rem = nt_k - t;
    if (rem >= 3) {
      asm volatile("s_waitcnt vmcnt(16)" ::: "memory");
    } else if (rem == 2) {
      asm volatile("s_waitcnt vmcnt(8)" ::: "memory");
    } else {
      asm volatile("s_waitcnt vmcnt(0)" ::: "memory");
    }
    __builtin_amdgcn_sched_barrier(0);
    __builtin_amdgcn_s_barrier();
    __builtin_amdgcn_sched_barrier(0);
    if (t + 3 < nt_k) stage(t + 3, (t + 3) & 3);

    const unsigned short* Ab = (const unsigned short*)lds + (t & 3) * 16384;
    const unsigned short* Bb = Ab + 8192;
#pragma unroll
    for (int ks = 0; ks < 2; ++ks) {
      short8 bfr[4];
#pragma unroll
      for (int j = 0; j < 4; ++j) {
        int row = wn + j * 16 + r;
        bfr[j] = *(const short8*)&Bb[row * 64 + ((g + ks * 4) ^ (r & 7)) * 8];
      }
#pragma unroll
      for (int i = 0; i < 4; ++i) {
        int row = wm + i * 16 + r;
        short8 af = *(const short8*)&Ab[row * 64 + ((g + ks * 4) ^ (r & 7)) * 8];
#pragma unroll
        for (int j = 0; j < 4; ++j)
          acc[i][j] = __builtin_amdgcn_mfma_f32_16x16x32_bf16(af, bfr[j], acc[i][j], 0, 0, 0);
      }
    }
  }
  if constexpr (EPI == 4) {
    qkv_rope_epilogue(acc, (unsigned short*)Cout, (const float2*)bias,
                      m0, n0, wm, wn, g, r);
  } else {
    gemm_epilogue<EPI, 4, 4>(acc, Cout, bias, mods, gate_ofs, src, N, rowsPerB,
                             m0, n0, wm, wn, g, r);
  }
}

// ---------------------------------------------------------------------------
// GEMM (64x128 tile, 2-blocks/CU): 4 waves of 32x64, BK=64, 3 LDS bufs (72KB),
// depth-2 counted vmcnt(6).  Grid = (M/64)*(N/128); nt = flat % ntn puts one
// B-panel per XCD when ntn==8.  PROVEN best for the grid-512 N=1024 GEMMs
// (r8: 128^2 pipe at 1 block/CU is 23us slower across wo_s/wo_c/mlp2).
// ---------------------------------------------------------------------------
template <int EPI>
__global__ __launch_bounds__(256) void gemm_p2(
    const unsigned short* __restrict__ A, const unsigned short* __restrict__ Bt,
    void* __restrict__ Cout, const float* __restrict__ bias,
    const float* __restrict__ mods, int gate_ofs, const float* __restrict__ src,
    int M, int N, int K, int rowsPerB, int ntn) {
  __shared__ unsigned short lds[3 * 12288];  // per buf: A 64x64 (8KB) | B 128x64 (16KB)
  const int tid = threadIdx.x;
  const int wave = tid >> 6, lane = tid & 63;
  const int g = lane >> 4, r = lane & 15;
  const int flat = blockIdx.x;
  const int nt = flat % ntn, mt = flat / ntn;
  const int m0 = mt * 64, n0 = nt * 128;
  const int wm = (wave >> 1) * 32, wn = (wave & 1) * 64;
  const int srow8 = lane >> 3;
  const int sck = (lane & 7) ^ srow8;

  f32x4 acc[2][4] = {};

  auto stage = [&](int t, int bufi) {
    const int k0 = t * 64;
    unsigned short* base = (unsigned short*)lds + bufi * 12288;
#pragma unroll
    for (int i = 0; i < 2; ++i) {  // A units: 8 of 64 rows
      int u = wave * 2 + i;
      int rl = u * 8 + srow8;
      const unsigned short* gsrc = A + (size_t)(m0 + rl) * K + k0 + sck * 8;
      __builtin_amdgcn_global_load_lds(GLB(gsrc), LDSP(base + u * 512), 16, 0, 0);
    }
#pragma unroll
    for (int i = 0; i < 4; ++i) {  // B units: 16 of 128 rows
      int u = wave * 4 + i;
      int rl = u * 8 + srow8;
      const unsigned short* gsrc = Bt + (size_t)(n0 + rl) * K + k0 + sck * 8;
      __builtin_amdgcn_global_load_lds(GLB(gsrc), LDSP(base + 4096 + u * 512), 16, 0, 0);
    }
  };

  const int ntk = K / 64;
  stage(0, 0);
  stage(1, 1);
  int cbuf = 0, sbuf = 2;

  for (int t = 0; t < ntk; ++t) {
    if (t < ntk - 1) {
      asm volatile("s_waitcnt vmcnt(6)" ::: "memory");
    } else {
      asm volatile("s_waitcnt vmcnt(0)" ::: "memory");
    }
    __builtin_amdgcn_sched_barrier(0);
    __builtin_amdgcn_s_barrier();
    __builtin_amdgcn_sched_barrier(0);
    if (t + 2 < ntk) {
      stage(t + 2, sbuf);
      sbuf = (sbuf == 2) ? 0 : sbuf + 1;
    }

    const unsigned short* Ab = (const unsigned short*)lds + cbuf * 12288;
    const unsigned short* Bb = Ab + 4096;
#pragma unroll
    for (int ks = 0; ks < 2; ++ks) {
      short8 bfr[4];
#pragma unroll
      for (int j = 0; j < 4; ++j) {
        int row = wn + j * 16 + r;
        bfr[j] = *(const short8*)&Bb[row * 64 + ((g + ks * 4) ^ (r & 7)) * 8];
      }
#pragma unroll
      for (int i = 0; i < 2; ++i) {
        int row = wm + i * 16 + r;
        short8 af = *(const short8*)&Ab[row * 64 + ((g + ks * 4) ^ (r & 7)) * 8];
#pragma unroll
        for (int j = 0; j < 4; ++j)
          acc[i][j] = __builtin_amdgcn_mfma_f32_16x16x32_bf16(af, bfr[j], acc[i][j], 0, 0, 0);
      }
    }
    cbuf = (cbuf == 2) ? 0 : cbuf + 1;
  }
  gemm_epilogue<EPI, 2, 4>(acc, Cout, bias, mods, gate_ofs, src, N, rowsPerB,
                           m0, n0, wm, wn, g, r);
}

// ---------------------------------------------------------------------------
// gemm_cross: fused cross-attention Q-proj + KV-proj in ONE launch (768 blk).
//   blocks [0,512):   q = nx(4096x1024) @ wqcT,  N=1024, ntn=8  -> qb (bf16)
//   blocks [512,768): kv = ctxb(1024x1024) @ wkcT(+wvcT adj), N=2048, ntn=16
//                     -> kb/vb split-store (EPI3 layout)
// ---------------------------------------------------------------------------
__global__ __launch_bounds__(256) void gemm_cross(
    const unsigned short* __restrict__ Anx, const unsigned short* __restrict__ Bq,
    unsigned short* __restrict__ Oq,
    const unsigned short* __restrict__ Actx, const unsigned short* __restrict__ Bkv,
    unsigned short* __restrict__ Okv) {
  __shared__ unsigned short lds[3 * 12288];
  const int tid = threadIdx.x;
  const int wave = tid >> 6, lane = tid & 63;
  const int g = lane >> 4, r = lane & 15;
  const bool iskv = blockIdx.x >= 512;
  const int flat = iskv ? (blockIdx.x - 512) : blockIdx.x;
  const int ntn = iskv ? 16 : 8;
  const unsigned short* A = iskv ? Actx : Anx;
  const unsigned short* Bt = iskv ? Bkv : Bq;
  const int nt = flat % ntn, mt = flat / ntn;
  const int m0 = mt * 64, n0 = nt * 128;
  const int K = 1024;
  const int wm = (wave >> 1) * 32, wn = (wave & 1) * 64;
  const int srow8 = lane >> 3;
  const int sck = (lane & 7) ^ srow8;

  f32x4 acc[2][4] = {};

  auto stage = [&](int t, int bufi) {
    const int k0 = t * 64;
    unsigned short* base = (unsigned short*)lds + bufi * 12288;
#pragma unroll
    for (int i = 0; i < 2; ++i) {
      int u = wave * 2 + i;
      int rl = u * 8 + srow8;
      const unsigned short* gsrc = A + (size_t)(m0 + rl) * K + k0 + sck * 8;
      __builtin_amdgcn_global_load_lds(GLB(gsrc), LDSP(base + u * 512), 16, 0, 0);
    }
#pragma unroll
    for (int i = 0; i < 4; ++i) {
      int u = wave * 4 + i;
      int rl = u * 8 + srow8;
      const unsigned short* gsrc = Bt + (size_t)(n0 + rl) * K + k0 + sck * 8;
      __builtin_amdgcn_global_load_lds(GLB(gsrc), LDSP(base + 4096 + u * 512), 16, 0, 0);
    }
  };

  const int ntk = K / 64;
  stage(0, 0);
  stage(1, 1);
  int cbuf = 0, sbuf = 2;

  for (int t = 0; t < ntk; ++t) {
    if (t < ntk - 1) {
      asm volatile("s_waitcnt vmcnt(6)" ::: "memory");
    } else {
      asm volatile("s_waitcnt vmcnt(0)" ::: "memory");
    }
    __builtin_amdgcn_sched_barrier(0);
    __builtin_amdgcn_s_barrier();
    __builtin_amdgcn_sched_barrier(0);
    if (t + 2 < ntk) {
      stage(t + 2, sbuf);
      sbuf = (sbuf == 2) ? 0 : sbuf + 1;
    }

    const unsigned short* Ab = (const unsigned short*)lds + cbuf * 12288;
    const unsigned short* Bb = Ab + 4096;
#pragma unroll
    for (int ks = 0; ks < 2; ++ks) {
      short8 bfr[4];
#pragma unroll
      for (int j = 0; j < 4; ++j) {
        int row = wn + j * 16 + r;
        bfr[j] = *(const short8*)&Bb[row * 64 + ((g + ks * 4) ^ (r & 7)) * 8];
      }
#pragma unroll
      for (int i = 0; i < 2; ++i) {
        int row = wm + i * 16 + r;
        short8 af = *(const short8*)&Ab[row * 64 + ((g + ks * 4) ^ (r & 7)) * 8];
#pragma unroll
        for (int j = 0; j < 4; ++j)
          acc[i][j] = __builtin_amdgcn_mfma_f32_16x16x32_bf16(af, bfr[j], acc[i][j], 0, 0, 0);
      }
    }
    cbuf = (cbuf == 2) ? 0 : cbuf + 1;
  }

#pragma unroll
  for (int i = 0; i < 2; ++i) {
#pragma unroll
    for (int j = 0; j < 4; ++j) {
#pragma unroll
      for (int q = 0; q < 4; ++q) {
        size_t grow = (size_t)(m0 + wm + i * 16 + g * 4 + q);
        size_t gcol = (size_t)(n0 + wn + j * 16 + r);
        float v = acc[i][j][q];
        if (iskv) {
          size_t buf = gcol >> 10;
          Okv[buf * (4096ull * 1024) + grow * 1024 + (gcol & 1023)] = f2b(v);
        } else {
          Oq[grow * 1024 + gcol] = f2b(v);
        }
      }
    }
  }
}

// ---------------------------------------------------------------------------
// Flash attention v9 (converged): 128 q/block, T15 pipeline, cvt_pk, max3,
// fused-scale, perm V-pack, setprio(PV).  Blind VALU edits exhausted — frozen.
// (r11 hidden-KV fusion was break-even with 3x bank conflicts: reverted.)
// ---------------------------------------------------------------------------
__global__ __launch_bounds__(256, 2) void flash2(
    const unsigned short* __restrict__ Q, const unsigned short* __restrict__ Kv,
    const unsigned short* __restrict__ Vv, unsigned short* __restrict__ O,
    int Lk) {
  __shared__ unsigned short lds[20480];  // 40KB: K 3x8KB @0 | V^T 2x8KB @12288
  const int tid = threadIdx.x, wave = tid >> 6, lane = tid & 63;
  const int hi = lane >> 5, lq = lane & 31;
  const int flat = blockIdx.x;
  const int xcd = flat & 7, rr = flat >> 3;
  const int gl = rr >> 4, qt = rr & 15;
  const int g = xcd * 4 + gl;
  const int h = g & 15, b = g >> 4;
  const int Lq = 2048, D = 1024;

  const unsigned short* Qbase =
      Q + ((size_t)b * Lq + qt * 128 + wave * 32 + lq) * D + h * 64;
  const unsigned short* Kbase = Kv + (size_t)b * Lk * D + h * 64;
  const unsigned short* Vbase = Vv + (size_t)b * Lk * D + h * 64;

  short8 qf[4];
#pragma unroll
  for (int kb = 0; kb < 4; ++kb)
    qf[kb] = *(const short8*)(Qbase + kb * 16 + hi * 8);

  const short8 ones = {0x3F80, 0x3F80, 0x3F80, 0x3F80, 0x3F80, 0x3F80, 0x3F80, 0x3F80};
  const f32x16 z16 = {};  // persistent zero C-operand

  const int kr0 = tid >> 3, kc0 = tid & 7;   // K stage: row, chunk
  const int kvp = tid >> 3, db = tid & 7;    // V stage: kv-pair, d-block
  const int kch0 = (kc0 ^ (kr0 & 7) ^ (kr0 >> 3)) & 7;
  const int kch1 = kch0 ^ 4;
  const int f0 = (lq & 7) ^ (lq >> 3);
  const int swz0 = f0 << 4, swz1 = swz0 ^ 64;

  // kt-invariant V^T write byte-offsets (per-thread constants, reg-resident)
  int vby[8];
#pragma unroll
  for (int e = 0; e < 8; ++e) {
    int d = db * 8 + e;
    vby[e] = d * 128 + ((kvp * 4) ^ (((e ^ db) & 7) << 4));
  }

  float m_run = -3.0e38f;
  f32x16 o0 = {}, o1 = {}, lacc = {};
  short8 vr0, vr1;
  short8 pbf[4];

  auto stageK = [&](int t, int bi) {
    const unsigned short* s0 = Kbase + (size_t)(t * 64 + kr0) * D + kch0 * 8;
    const unsigned short* s1 = Kbase + (size_t)(t * 64 + kr0 + 32) * D + kch1 * 8;
    __builtin_amdgcn_global_load_lds(GLB(s0), LDSP(&lds[bi * 4096 + wave * 512]), 16, 0, 0);
    __builtin_amdgcn_global_load_lds(GLB(s1), LDSP(&lds[bi * 4096 + 2048 + wave * 512]), 16, 0, 0);
  };
  auto loadV = [&](int t) {
    const unsigned short* v0 = Vbase + (size_t)(t * 64 + 2 * kvp) * D + db * 8;
    vr0 = *(const short8*)v0;
    vr1 = *(const short8*)(v0 + D);
  };
  auto writeV = [&](int t) {
    char* vt = (char*)&lds[12288 + (t & 1) * 4096];
    union { short8 s; unsigned int u[4]; } a, c;
    a.s = vr0; c.s = vr1;
#pragma unroll
    for (int k = 0; k < 4; ++k) {
      *(unsigned int*)(vt + vby[2 * k]) =
          __builtin_amdgcn_perm(c.u[k], a.u[k], 0x05040100u);
      *(unsigned int*)(vt + vby[2 * k + 1]) =
          __builtin_amdgcn_perm(c.u[k], a.u[k], 0x07060302u);
    }
  };
  auto qk = [&](int bi, f32x16& sa0, f32x16& sa1) {
    const unsigned short* K0 = &lds[bi * 4096];
    {
      int lo = hi * 16;
      short8 a0 = *(const short8*)&K0[lq * 64 + ((lo ^ swz0) >> 1)];
      short8 a1 = *(const short8*)&K0[(32 + lq) * 64 + ((lo ^ swz1) >> 1)];
      sa0 = __builtin_amdgcn_mfma_f32_32x32x16_bf16(a0, qf[0], z16, 0, 0, 0);
      sa1 = __builtin_amdgcn_mfma_f32_32x32x16_bf16(a1, qf[0], z16, 0, 0, 0);
    }
#pragma unroll
    for (int ks = 1; ks < 4; ++ks) {
      int lo = ks * 32 + hi * 16;
      short8 a0 = *(const short8*)&K0[lq * 64 + ((lo ^ swz0) >> 1)];
      short8 a1 = *(const short8*)&K0[(32 + lq) * 64 + ((lo ^ swz1) >> 1)];
      sa0 = __builtin_amdgcn_mfma_f32_32x32x16_bf16(a0, qf[ks], sa0, 0, 0, 0);
      sa1 = __builtin_amdgcn_mfma_f32_32x32x16_bf16(a1, qf[ks], sa1, 0, 0, 0);
    }
  };
  auto finish = [&](f32x16& s0a, f32x16& s1a) {
    float tm[8];
#pragma unroll
    for (int i = 0; i < 8; ++i)
      tm[i] = fmaxf(max3f(s0a[i], s0a[i + 8], s1a[i]), s1a[i + 8]);
    float x = max3f(tm[0], tm[1], tm[2]);
    float y = max3f(tm[3], tm[4], tm[5]);
    float pm = fmaxf(max3f(tm[6], tm[7], x), y);
    {
      unsigned int ua = __builtin_bit_cast(unsigned int, pm), ub = ua;
      vpsw(ua, ub);
      pm = fmaxf(__builtin_bit_cast(float, ua), __builtin_bit_cast(float, ub));
    }
    if (__any(pm - m_run > 8.0f)) {
      float mnew = fmaxf(m_run, pm);
      float alpha = exp2f(m_run - mnew);
      lacc[0] *= alpha;
#pragma unroll
      for (int i = 0; i < 16; ++i) { o0[i] *= alpha; o1[i] *= alpha; }
      m_run = mnew;
    }
    float mc = m_run;
#pragma unroll
    for (int i = 0; i < 16; ++i) s0a[i] = exp2f(s0a[i] - mc);
#pragma unroll
    for (int i = 0; i < 16; ++i) s1a[i] = exp2f(s1a[i] - mc);
#pragma unroll
    for (int kb = 0; kb < 4; ++kb) {
      int bb = (kb & 1) * 8;
      float p0, p1, p2, p3, p4, p5, p6, p7;
      if (kb < 2) {
        p0 = s0a[bb + 0]; p1 = s0a[bb + 1]; p2 = s0a[bb + 2]; p3 = s0a[bb + 3];
        p4 = s0a[bb + 4]; p5 = s0a[bb + 5]; p6 = s0a[bb + 6]; p7 = s0a[bb + 7];
      } else {
        p0 = s1a[bb + 0]; p1 = s1a[bb + 1]; p2 = s1a[bb + 2]; p3 = s1a[bb + 3];
        p4 = s1a[bb + 4]; p5 = s1a[bb + 5]; p6 = s1a[bb + 6]; p7 = s1a[bb + 7];
      }
      unsigned int u0 = pk2(p0, p1), u1 = pk2(p2, p3);
      unsigned int u2 = pk2(p4, p5), u3 = pk2(p6, p7);
      vpsw(u0, u2);
      vpsw(u1, u3);
      union { unsigned int u[4]; short8 s; } fr;
      fr.u[0] = u0; fr.u[1] = u1; fr.u[2] = u2; fr.u[3] = u3;
      pbf[kb] = fr.s;
    }
  };
  auto pv = [&](int t) {
    const unsigned short* V0 = &lds[12288 + (t & 1) * 4096];
    __builtin_amdgcn_s_setprio(1);
#pragma unroll
    for (int kb = 0; kb < 4; ++kb) {
      int lo = kb * 32 + hi * 16;
      short8 vf0 = *(const short8*)&V0[lq * 64 + ((lo ^ swz0) >> 1)];
      short8 vf1 = *(const short8*)&V0[(32 + lq) * 64 + ((lo ^ swz1) >> 1)];
      o0 = __builtin_amdgcn_mfma_f32_32x32x16_bf16(vf0, pbf[kb], o0, 0, 0, 0);
      o1 = __builtin_amdgcn_mfma_f32_32x32x16_bf16(vf1, pbf[kb], o1, 0, 0, 0);
      lacc = __builtin_amdgcn_mfma_f32_32x32x16_bf16(ones, pbf[kb], lacc, 0, 0, 0);
    }
    __builtin_amdgcn_s_setprio(0);
  };

  const int nkt = Lk / 64;  // even for both Lk=2048 (32) and Lk=512 (8)

  // prologue: K(0)->buf0, V(0)->Vbuf0, K(1)->buf1, then S(0)
  stageK(0, 0);
  loadV(0);
  writeV(0);
  stageK(1, 1);
  __syncthreads();

  f32x16 sA0, sA1, sB0, sB1;
  qk(0, sA0, sA1);

  // pipelined step: QK(t+1)->snew (MFMA) overlaps finish(sold) (VALU); PV(t)
  auto pstep = [&](int t, f32x16& n0, f32x16& n1, f32x16& p0, f32x16& p1) {
    const int tq = t + 1;
    if (tq < nkt) {
      loadV(tq);
      if (tq + 1 < nkt) stageK(tq + 1, (tq + 1) % 3);
      qk(tq % 3, n0, n1);
    }
    finish(p0, p1);
    if (tq < nkt) writeV(tq);
    pv(t);
    __syncthreads();
  };

  for (int t = 0; t < nkt; t += 2) {
    pstep(t, sB0, sB1, sA0, sA1);
    pstep(t + 1, sA0, sA1, sB0, sB1);
  }

  // ---- epilogue: normalize, bounce through LDS, coalesced store ----
  float rl = 1.0f / lacc[0];
  unsigned short* os = &lds[wave * 2048];
#pragma unroll
  for (int t = 0; t < 2; ++t) {
#pragma unroll
    for (int c = 0; c < 4; ++c) {
      int dbase = 32 * t + 8 * c + 4 * hi;
      float v0 = (t ? o1[4 * c + 0] : o0[4 * c + 0]) * rl;
      float v1 = (t ? o1[4 * c + 1] : o0[4 * c + 1]) * rl;
      float v2 = (t ? o1[4 * c + 2] : o0[4 * c + 2]) * rl;
      float v3 = (t ? o1[4 * c + 3] : o0[4 * c + 3]) * rl;
      int by0 = lq * 128 + ((dbase * 2) ^ ((lq & 7) << 4));
      int by1 = lq * 128 + (((dbase + 2) * 2) ^ ((lq & 7) << 4));
      *(unsigned int*)((char*)os + by0) = pk2(v0, v1);
      *(unsigned int*)((char*)os + by1) = pk2(v2, v3);
    }
  }
  int q2 = lane >> 1;
  unsigned short* orow =
      O + ((size_t)b * Lq + qt * 128 + wave * 32 + q2) * D + h * 64;
#pragma unroll
  for (int j = 0; j < 4; ++j) {
    int j2 = (lane & 1) * 4 + j;
    int byr = q2 * 128 + ((j2 * 16) ^ ((q2 & 7) << 4));
    short8 vv = *(const short8*)((char*)os + byr);
    *(short8*)(orow + j2 * 8) = vv;
  }
}

// ---------------------------------------------------------------------------
// Host orchestration
// ---------------------------------------------------------------------------
extern "C" void kernel_launch(void* const* d_in, const int* in_sizes, int n_in,
                              void* d_out, int out_size, void* d_ws, size_t ws_size,
                              hipStream_t stream) {
  (void)in_sizes; (void)n_in; (void)out_size; (void)ws_size;
  const float* x_in = (const float*)d_in[0];
  const float* te   = (const float*)d_in[1];
  const float* ctx  = (const float*)d_in[2];
  const float* rope = (const float*)d_in[3];
  const float* wmod = (const float*)d_in[4];
  const float* bmod = (const float*)d_in[5];
  const float* wqs  = (const float*)d_in[6];
  const float* wks  = (const float*)d_in[7];
  const float* wvs  = (const float*)d_in[8];
  const float* wos  = (const float*)d_in[9];
  const float* bos  = (const float*)d_in[10];
  const float* wqc  = (const float*)d_in[11];
  const float* wkc  = (const float*)d_in[12];
  const float* wvc  = (const float*)d_in[13];
  const float* woc  = (const float*)d_in[14];
  const float* boc  = (const float*)d_in[15];
  const float* w1   = (const float*)d_in[16];
  const float* b1   = (const float*)d_in[17];
  const float* w2   = (const float*)d_in[18];
  const float* b2   = (const float*)d_in[19];
  float* out = (float*)d_out;

  char* w = (char*)d_ws;
  size_t o = 0;
  auto alloc = [&](size_t bytes) {
    char* p = w + o;
    o = (o + bytes + 255) & ~(size_t)255;
    return p;
  };
  // wqsT/wksT/wvsT adjacent (fused QKV); wkcT/wvcT adjacent (fused cross-KV).
  unsigned short* wqsT  = (unsigned short*)alloc(1024ull * 1024 * 2);
  unsigned short* wksT  = (unsigned short*)alloc(1024ull * 1024 * 2);
  unsigned short* wvsT  = (unsigned short*)alloc(1024ull * 1024 * 2);
  unsigned short* wosT  = (unsigned short*)alloc(1024ull * 1024 * 2);
  unsigned short* wqcT  = (unsigned short*)alloc(1024ull * 1024 * 2);
  unsigned short* wkcT  = (unsigned short*)alloc(1024ull * 1024 * 2);
  unsigned short* wvcT  = (unsigned short*)alloc(1024ull * 1024 * 2);
  unsigned short* wocT  = (unsigned short*)alloc(1024ull * 1024 * 2);
  unsigned short* w1T   = (unsigned short*)alloc(4096ull * 1024 * 2);
  unsigned short* w2T   = (unsigned short*)alloc(1024ull * 4096 * 2);
  float* modsb = (float*)alloc(2ull * 6144 * 4);
  float2* csT  = (float2*)alloc(2048ull * 64 * 8);
  unsigned short* nx   = (unsigned short*)alloc(4096ull * 1024 * 2);
  unsigned short* ctxb = (unsigned short*)alloc(1024ull * 1024 * 2);
  // qb/kb/vb adjacent: EPI3/EPI4 buffer stride = 4096*1024 elems.
  unsigned short* qb = (unsigned short*)alloc(4096ull * 1024 * 2);
  unsigned short* kb = (unsigned short*)alloc(4096ull * 1024 * 2);
  unsigned short* vb = (unsigned short*)alloc(4096ull * 1024 * 2);
  unsigned short* ao = (unsigned short*)alloc(4096ull * 1024 * 2);
  unsigned short* xwb = (unsigned short*)alloc(4096ull * 1024 * 2);  // residual after self-attn (bf16)
  float* xw = (float*)alloc(4096ull * 1024 * 4);                     // residual after cross-attn (f32)
  unsigned short* hbuf = qb;  // reuse qb..ao contiguous 32MB for MLP hidden

  const float c1 = 0.125f * 1.4426950408889634f;  // scale * log2(e), folded into wqs/wkc

  PrepArgs pa;
  pa.wmod = wmod; pa.te = te; pa.bmod = bmod; pa.mods = modsb;
  pa.sq[0] = {wqs, wqsT, c1};
  pa.sq[1] = {wks, wksT, 1.0f};
  pa.sq[2] = {wvs, wvsT, 1.0f};
  pa.sq[3] = {wos, wosT, 1.0f};
  pa.sq[4] = {wqc, wqcT, 1.0f};
  pa.sq[5] = {wkc, wkcT, c1};
  pa.sq[6] = {wvc, wvcT, 1.0f};
  pa.sq[7] = {woc, wocT, 1.0f};
  pa.w1 = w1; pa.w1T = w1T;
  pa.w2 = w2; pa.w2T = w2T;
  pa.ctx = ctx; pa.ctxb = ctxb;
  pa.rope = rope; pa.cs = csT;
  prep<<<18968, 256, 0, stream>>>(pa);

  // --- self-attention (RoPE fused into QKV epilogue) ---
  ln_mod<0><<<4096, 256, 0, stream>>>(x_in, modsb, nx, 1024, 0);
  gemm_pipe<4><<<768, 256, 0, stream>>>(nx, wqsT, qb, (const float*)csT, nullptr, -1, nullptr, 4096, 3072, 1024, 2048, 2);
  flash2<<<512, 256, 0, stream>>>(qb, kb, vb, ao, 2048);
  // xw1 = x + gate_msa*sa, stored bf16 (EPI5: bf16 out, f32 src)
  gemm_p2<5><<<512, 256, 0, stream>>>(ao, wosT, xwb, bos, modsb, 2048, x_in, 4096, 1024, 1024, 2048, 8);

  // --- cross-attention (Q-proj + KV-proj fused in one launch) ---
  ln_mod<1><<<4096, 256, 0, stream>>>(xwb, modsb, nx, -1, -1);
  gemm_cross<<<768, 256, 0, stream>>>(nx, wqcT, qb, ctxb, wkcT, kb);
  flash2<<<512, 256, 0, stream>>>(qb, kb, vb, ao, 512);
  // xw2 = xw1 + ca, f32 out from bf16 src (EPI7)
  gemm_p2<7><<<512, 256, 0, stream>>>(ao, wocT, xw, boc, modsb, -1, (const float*)xwb, 4096, 1024, 1024, 2048, 8);

  // --- MLP ---
  ln_mod<0><<<4096, 256, 0, stream>>>(xw, modsb, nx, 4096, 3072);
  gemm_bt<1><<<dim3(32, 32), 256, 0, stream>>>(nx, w1T, hbuf, b1, nullptr, -1, nullptr, 4096, 4096, 1024, 2048);
  gemm_p2<2><<<512, 256, 0, stream>>>(hbuf, w2T, out, b2, modsb, 5120, xw, 4096, 1024, 4096, 2048, 8);
}